// Round 1
// baseline (859.498 us; speedup 1.0000x reference)
//
#include <hip/hip_runtime.h>
#include <math.h>

#define PIX 16384   // H*W = 128*128
#define EPSF 1e-5f

__device__ __forceinline__ float sigmoidf_(float v) { return 1.f / (1.f + expf(-v)); }

// ---------- weight transpose: dst[c][r] = src[r][c] ----------
__global__ void k_transpose(const float* __restrict__ src, float* __restrict__ dst,
                            int R, int C) {
  int idx = blockIdx.x * 256 + threadIdx.x;
  if (idx < R * C) {
    int r = idx / C, c = idx % C;
    dst[(size_t)c * R + r] = src[idx];
  }
}

// ---------- K1: proj[b,o,p] = sum_i Wproj[o,i]*concat(x,h)[b,i,p] + bproj ----------
__global__ __launch_bounds__(256) void k_proj(
    const float* __restrict__ x, const float* __restrict__ h,
    const float* __restrict__ WT,   // [192][128]
    const float* __restrict__ bias, // [128]
    float* __restrict__ out)        // [B][128][PIX]
{
  __shared__ __align__(16) float sIn[192 * 64];
  int b = blockIdx.y;
  int p0 = blockIdx.x * 64;
  int t = threadIdx.x;
  const float* xb = x + (size_t)b * 64 * PIX + p0;
  const float* hb = h + (size_t)b * 128 * PIX + p0;
  for (int idx = t; idx < 64 * 64; idx += 256) {
    int ch = idx >> 6, px = idx & 63;
    sIn[ch * 64 + px] = xb[(size_t)ch * PIX + px];
  }
  for (int idx = t; idx < 128 * 64; idx += 256) {
    int ch = idx >> 6, px = idx & 63;
    sIn[(64 + ch) * 64 + px] = hb[(size_t)ch * PIX + px];
  }
  __syncthreads();
  int og = t & 31;      // out channels og*4 .. og*4+3
  int pxg = t >> 5;     // pixels pxg*8 .. pxg*8+7
  float acc[4][8];
  #pragma unroll
  for (int i = 0; i < 4; i++)
    #pragma unroll
    for (int j = 0; j < 8; j++) acc[i][j] = 0.f;
  for (int k = 0; k < 192; k++) {
    float4 wv = *reinterpret_cast<const float4*>(&WT[k * 128 + og * 4]);
    float4 a0 = *reinterpret_cast<const float4*>(&sIn[k * 64 + pxg * 8]);
    float4 a1 = *reinterpret_cast<const float4*>(&sIn[k * 64 + pxg * 8 + 4]);
    float w[4] = {wv.x, wv.y, wv.z, wv.w};
    float in[8] = {a0.x, a0.y, a0.z, a0.w, a1.x, a1.y, a1.z, a1.w};
    #pragma unroll
    for (int i = 0; i < 4; i++)
      #pragma unroll
      for (int j = 0; j < 8; j++) acc[i][j] = fmaf(w[i], in[j], acc[i][j]);
  }
  __syncthreads();
  // bounce through LDS (pad 66) for coalesced global writes
  #pragma unroll
  for (int i = 0; i < 4; i++) {
    int o = og * 4 + i;
    float bv = bias[o];
    #pragma unroll
    for (int j = 0; j < 8; j++) sIn[o * 66 + pxg * 8 + j] = acc[i][j] + bv;
  }
  __syncthreads();
  float* ob = out + (size_t)b * 128 * PIX + p0;
  for (int idx = t; idx < 128 * 64; idx += 256) {
    int ch = idx >> 6, px = idx & 63;
    ob[(size_t)ch * PIX + px] = sIn[ch * 66 + px];
  }
}

// ---------- K2: fused per-window LN -> QKV -> MHSA -> Wo ----------
__global__ __launch_bounds__(256) void k_attn(
    const float* __restrict__ proj,   // [B][128][PIX]
    const float* __restrict__ ln_g, const float* __restrict__ ln_b,
    const float* __restrict__ WqkvT,  // [128][384]
    const float* __restrict__ bqkv,   // [384]
    const float* __restrict__ WoT,    // [128][128]
    const float* __restrict__ bo,     // [128]
    float* __restrict__ attn_map)     // [B][128][PIX]
{
  __shared__ __align__(16) float sX[128 * 20];   // xn [ch][px]; later O [ch][px]
  __shared__ __align__(16) float sQKV[16 * 392]; // [px][o0..383]
  __shared__ float sS[4][16][17];                // scores per head
  __shared__ __align__(16) float sOut[16 * 132]; // attn out [px][co]

  int t = threadIdx.x;
  int w = blockIdx.x;
  int b = w >> 10, wh = (w >> 5) & 31, ww = w & 31;
  const float* pb = proj + (size_t)b * 128 * PIX + (size_t)(wh * 4) * 128 + ww * 4;

  // load window (16 px x 128 ch)
  for (int idx = t; idx < 2048; idx += 256) {
    int ch = idx >> 4, px = idx & 15;
    sX[ch * 20 + px] = pb[(size_t)ch * PIX + (px >> 2) * 128 + (px & 3)];
  }
  __syncthreads();

  // LayerNorm per token: 16 groups of 16 lanes
  {
    int tok = t >> 4, li = t & 15;
    float s = 0.f, s2 = 0.f;
    #pragma unroll
    for (int j = 0; j < 8; j++) {
      float v = sX[(li + 16 * j) * 20 + tok];
      s += v; s2 += v * v;
    }
    #pragma unroll
    for (int m = 8; m >= 1; m >>= 1) {
      s  += __shfl_xor(s, m, 16);
      s2 += __shfl_xor(s2, m, 16);
    }
    float mu = s * (1.f / 128.f);
    float var = s2 * (1.f / 128.f) - mu * mu;
    float rstd = rsqrtf(var + EPSF);
    #pragma unroll
    for (int j = 0; j < 8; j++) {
      int ch = li + 16 * j;
      float v = sX[ch * 20 + tok];
      sX[ch * 20 + tok] = (v - mu) * rstd * ln_g[ch] + ln_b[ch];
    }
  }
  __syncthreads();

  // QKV: thread owns o = (t&127)+128j (j<3), px = pxh..pxh+7
  {
    int oc = t & 127;
    int pxh = (t >> 7) * 8;
    float acc[3][8];
    #pragma unroll
    for (int j = 0; j < 3; j++)
      #pragma unroll
      for (int i = 0; i < 8; i++) acc[j][i] = 0.f;
    for (int k = 0; k < 128; k++) {
      float4 a0 = *reinterpret_cast<const float4*>(&sX[k * 20 + pxh]);
      float4 a1 = *reinterpret_cast<const float4*>(&sX[k * 20 + pxh + 4]);
      float in[8] = {a0.x, a0.y, a0.z, a0.w, a1.x, a1.y, a1.z, a1.w};
      const float* wrow = WqkvT + k * 384 + oc;
      float w0 = wrow[0], w1 = wrow[128], w2 = wrow[256];
      #pragma unroll
      for (int i = 0; i < 8; i++) {
        acc[0][i] = fmaf(w0, in[i], acc[0][i]);
        acc[1][i] = fmaf(w1, in[i], acc[1][i]);
        acc[2][i] = fmaf(w2, in[i], acc[2][i]);
      }
    }
    #pragma unroll
    for (int j = 0; j < 3; j++) {
      float bv = bqkv[oc + 128 * j];
      #pragma unroll
      for (int i = 0; i < 8; i++)
        sQKV[(pxh + i) * 392 + oc + 128 * j] = acc[j][i] + bv;
    }
  }
  __syncthreads();

  // scores: wave wv handles head wv; lane computes S[r][cg..cg+3]
  {
    int wv = t >> 6, l = t & 63;
    int r = l & 15, cg = (l >> 4) * 4;
    int qo = wv * 32, ko = 128 + wv * 32;
    float s[4] = {0.f, 0.f, 0.f, 0.f};
    for (int d = 0; d < 32; d += 4) {
      float4 q4 = *reinterpret_cast<const float4*>(&sQKV[r * 392 + qo + d]);
      #pragma unroll
      for (int cb = 0; cb < 4; cb++) {
        float4 k4 = *reinterpret_cast<const float4*>(&sQKV[(cg + cb) * 392 + ko + d]);
        s[cb] += q4.x * k4.x + q4.y * k4.y + q4.z * k4.z + q4.w * k4.w;
      }
    }
    const float scale = 0.17677669529663687f; // 32^-0.5
    #pragma unroll
    for (int cb = 0; cb < 4; cb++) sS[wv][r][cg + cb] = s[cb] * scale;
  }
  __syncthreads();

  // softmax per row (4 lanes per row do it redundantly, same values)
  {
    int wv = t >> 6, r = t & 15;
    float mx = -1e30f;
    #pragma unroll
    for (int cc = 0; cc < 16; cc++) mx = fmaxf(mx, sS[wv][r][cc]);
    float e[16], sum = 0.f;
    #pragma unroll
    for (int cc = 0; cc < 16; cc++) { e[cc] = expf(sS[wv][r][cc] - mx); sum += e[cc]; }
    float inv = 1.f / sum;
    #pragma unroll
    for (int cc = 0; cc < 16; cc++) sS[wv][r][cc] = e[cc] * inv;
  }
  __syncthreads();

  // PV: out[r][head*32+dg..+7], store as [ch][px] into sX (xn is dead)
  {
    int wv = t >> 6, l = t & 63;
    int r = l & 15, dg = (l >> 4) * 8;
    int vo = 256 + wv * 32 + dg;
    float o_[8];
    #pragma unroll
    for (int i = 0; i < 8; i++) o_[i] = 0.f;
    #pragma unroll
    for (int cc = 0; cc < 16; cc++) {
      float p = sS[wv][r][cc];
      float4 v0 = *reinterpret_cast<const float4*>(&sQKV[cc * 392 + vo]);
      float4 v1 = *reinterpret_cast<const float4*>(&sQKV[cc * 392 + vo + 4]);
      o_[0] = fmaf(p, v0.x, o_[0]); o_[1] = fmaf(p, v0.y, o_[1]);
      o_[2] = fmaf(p, v0.z, o_[2]); o_[3] = fmaf(p, v0.w, o_[3]);
      o_[4] = fmaf(p, v1.x, o_[4]); o_[5] = fmaf(p, v1.y, o_[5]);
      o_[6] = fmaf(p, v1.z, o_[6]); o_[7] = fmaf(p, v1.w, o_[7]);
    }
    #pragma unroll
    for (int i = 0; i < 8; i++) sX[(wv * 32 + dg + i) * 20 + r] = o_[i];
  }
  __syncthreads();

  // Wo: out[px][co] = sum_k O[px][k]*Wo[co][k] + bo
  {
    int co = t & 127;
    int pxh = (t >> 7) * 8;
    float acc[8];
    #pragma unroll
    for (int i = 0; i < 8; i++) acc[i] = 0.f;
    for (int k = 0; k < 128; k++) {
      float wv = WoT[k * 128 + co];
      float4 a0 = *reinterpret_cast<const float4*>(&sX[k * 20 + pxh]);
      float4 a1 = *reinterpret_cast<const float4*>(&sX[k * 20 + pxh + 4]);
      float in[8] = {a0.x, a0.y, a0.z, a0.w, a1.x, a1.y, a1.z, a1.w};
      #pragma unroll
      for (int i = 0; i < 8; i++) acc[i] = fmaf(wv, in[i], acc[i]);
    }
    float bv = bo[co];
    #pragma unroll
    for (int i = 0; i < 8; i++) sOut[(pxh + i) * 132 + co] = acc[i] + bv;
  }
  __syncthreads();

  float* ob = attn_map + (size_t)b * 128 * PIX + (size_t)(wh * 4) * 128 + ww * 4;
  for (int idx = t; idx < 2048; idx += 256) {
    int ch = idx >> 4, px = idx & 15;
    ob[(size_t)ch * PIX + (px >> 2) * 128 + (px & 3)] = sOut[px * 132 + ch];
  }
}

// ---------- group stats: partial sum/sumsq per (b,group) ----------
__global__ __launch_bounds__(256) void k_stats(const float* __restrict__ src,
                                               float* __restrict__ raw) { // [64][2]
  int blk = blockIdx.x;
  int slab = blk >> 2, q = blk & 3;          // 64 slabs x 4 quarters
  const float* base = src + (size_t)slab * 262144 + (size_t)q * 65536;
  int t = threadIdx.x;
  float s = 0.f, s2 = 0.f;
  for (int i = t * 4; i < 65536; i += 1024) {
    float4 v = *reinterpret_cast<const float4*>(&base[i]);
    s  += v.x + v.y + v.z + v.w;
    s2 += v.x * v.x + v.y * v.y + v.z * v.z + v.w * v.w;
  }
  #pragma unroll
  for (int m = 32; m >= 1; m >>= 1) {
    s  += __shfl_xor(s, m, 64);
    s2 += __shfl_xor(s2, m, 64);
  }
  __shared__ float red[8];
  int wv = t >> 6, l = t & 63;
  if (l == 0) { red[wv] = s; red[4 + wv] = s2; }
  __syncthreads();
  if (t == 0) {
    float S = red[0] + red[1] + red[2] + red[3];
    float S2 = red[4] + red[5] + red[6] + red[7];
    atomicAdd(&raw[slab * 2], S);
    atomicAdd(&raw[slab * 2 + 1], S2);
  }
}

__global__ void k_stats_fin(const float* __restrict__ raw, float* __restrict__ fin) {
  int i = threadIdx.x;
  if (i < 64) {
    const float invN = 1.f / 262144.f;
    float mu = raw[i * 2] * invN;
    float var = raw[i * 2 + 1] * invN - mu * mu;
    fin[i * 2] = mu;
    fin[i * 2 + 1] = rsqrtf(var + EPSF);
  }
}

// ---------- K4: GN(attn_map) -> gates GEMM -> LSTM update ----------
__global__ __launch_bounds__(256) void k_gates(
    const float* __restrict__ attn_map,  // [B][128][PIX]
    const float* __restrict__ statsA,    // [64][2] mu,rstd
    const float* __restrict__ gn_g, const float* __restrict__ gn_b,
    const float* __restrict__ WT,        // [128][512]
    const float* __restrict__ bias,      // [512]
    const float* __restrict__ c,
    float* __restrict__ cnext,           // d_out second half
    float* __restrict__ tbuf)            // o*tanh(cnext)
{
  __shared__ __align__(16) float sIn[128 * 20];
  __shared__ float sG[512 * 21];
  int bp = blockIdx.x;
  int b = bp >> 10;
  int p0 = (bp & 1023) * 16;
  int t = threadIdx.x;
  const float* ab = attn_map + (size_t)b * 128 * PIX + p0;
  for (int idx = t; idx < 2048; idx += 256) {
    int ch = idx >> 4, px = idx & 15;
    int g = ch >> 4;
    float mu = statsA[(b * 8 + g) * 2], rstd = statsA[(b * 8 + g) * 2 + 1];
    float v = ab[(size_t)ch * PIX + px];
    sIn[ch * 20 + px] = (v - mu) * rstd * gn_g[ch] + gn_b[ch];
  }
  __syncthreads();
  {
    float acc[2][16];
    #pragma unroll
    for (int j = 0; j < 2; j++)
      #pragma unroll
      for (int i = 0; i < 16; i++) acc[j][i] = 0.f;
    for (int k = 0; k < 128; k++) {
      float w0 = WT[k * 512 + t];
      float w1 = WT[k * 512 + t + 256];
      float4 a0 = *reinterpret_cast<const float4*>(&sIn[k * 20]);
      float4 a1 = *reinterpret_cast<const float4*>(&sIn[k * 20 + 4]);
      float4 a2 = *reinterpret_cast<const float4*>(&sIn[k * 20 + 8]);
      float4 a3 = *reinterpret_cast<const float4*>(&sIn[k * 20 + 12]);
      float in[16] = {a0.x, a0.y, a0.z, a0.w, a1.x, a1.y, a1.z, a1.w,
                      a2.x, a2.y, a2.z, a2.w, a3.x, a3.y, a3.z, a3.w};
      #pragma unroll
      for (int i = 0; i < 16; i++) {
        acc[0][i] = fmaf(w0, in[i], acc[0][i]);
        acc[1][i] = fmaf(w1, in[i], acc[1][i]);
      }
    }
    int o0 = t, o1 = t + 256;
    float b0 = bias[o0], b1 = bias[o1];
    #pragma unroll
    for (int i = 0; i < 16; i++) {
      float v0 = sigmoidf_(acc[0][i] + b0);                       // i or f gate
      float v1raw = acc[1][i] + b1;
      float v1 = (o1 < 384) ? sigmoidf_(v1raw) : tanhf(v1raw);    // o gate or g
      sG[o0 * 21 + i] = v0;
      sG[o1 * 21 + i] = v1;
    }
  }
  __syncthreads();
  const float* cb = c + (size_t)b * 128 * PIX + p0;
  float* cnb = cnext + (size_t)b * 128 * PIX + p0;
  float* tb = tbuf + (size_t)b * 128 * PIX + p0;
  for (int idx = t; idx < 2048; idx += 256) {
    int ch = idx >> 4, px = idx & 15;
    float ig = sG[ch * 21 + px];
    float fg = sG[(128 + ch) * 21 + px];
    float og = sG[(256 + ch) * 21 + px];
    float gg = sG[(384 + ch) * 21 + px];
    float cv = cb[(size_t)ch * PIX + px];
    float cn = fg * cv + ig * gg;
    cnb[(size_t)ch * PIX + px] = cn;
    tb[(size_t)ch * PIX + px] = og * tanhf(cn);
  }
}

// ---------- K6: hnext = GN2(t) ----------
__global__ __launch_bounds__(256) void k_gnout(
    const float* __restrict__ tbuf, const float* __restrict__ statsB,
    const float* __restrict__ gn_g, const float* __restrict__ gn_b,
    float* __restrict__ hnext)
{
  size_t idx = ((size_t)blockIdx.x * 256 + threadIdx.x) * 4;
  if (idx >= (size_t)16777216) return;
  int chrow = (int)(idx >> 14);     // b*128 + ch
  int b = chrow >> 7, ch = chrow & 127;
  int g = ch >> 4;
  float mu = statsB[(b * 8 + g) * 2], rstd = statsB[(b * 8 + g) * 2 + 1];
  float gg = gn_g[ch] * rstd;
  float bb = gn_b[ch] - mu * gg;
  float4 v = *reinterpret_cast<const float4*>(&tbuf[idx]);
  float4 o;
  o.x = v.x * gg + bb; o.y = v.y * gg + bb;
  o.z = v.z * gg + bb; o.w = v.w * gg + bb;
  *reinterpret_cast<float4*>(&hnext[idx]) = o;
}

extern "C" void kernel_launch(void* const* d_in, const int* in_sizes, int n_in,
                              void* d_out, int out_size, void* d_ws, size_t ws_size,
                              hipStream_t stream) {
  (void)in_sizes; (void)n_in; (void)out_size; (void)ws_size;
  const float* x      = (const float*)d_in[0];
  const float* h      = (const float*)d_in[1];
  const float* c      = (const float*)d_in[2];
  const float* Wproj  = (const float*)d_in[3];
  const float* bproj  = (const float*)d_in[4];
  const float* ln_g   = (const float*)d_in[5];
  const float* ln_b   = (const float*)d_in[6];
  const float* Wqkv   = (const float*)d_in[7];
  const float* bqkv   = (const float*)d_in[8];
  const float* Wo     = (const float*)d_in[9];
  const float* bo     = (const float*)d_in[10];
  const float* Wgates = (const float*)d_in[11];
  const float* bgates = (const float*)d_in[12];
  const float* gn_g   = (const float*)d_in[13];
  const float* gn_b   = (const float*)d_in[14];

  float* out = (float*)d_out;
  float* hnext = out;
  float* cnext = out + 16777216;

  float* ws = (float*)d_ws;
  float* buf1 = ws;                     // proj, later t = o*tanh(cnext)
  float* buf2 = ws + 16777216;          // attn_map
  float* wtp  = ws + 33554432;          // [192][128]
  float* wtq  = wtp + 24576;            // [128][384]
  float* wto  = wtq + 49152;            // [128][128]
  float* wtg  = wto + 16384;            // [128][512]
  float* stA_raw = wtg + 65536;         // [64][2]
  float* stA     = stA_raw + 128;
  float* stB_raw = stA + 128;
  float* stB     = stB_raw + 128;

  hipMemsetAsync(stA_raw, 0, 512 * sizeof(float), stream);

  k_transpose<<<(24576 + 255) / 256, 256, 0, stream>>>(Wproj, wtp, 128, 192);
  k_transpose<<<(49152 + 255) / 256, 256, 0, stream>>>(Wqkv, wtq, 384, 128);
  k_transpose<<<(16384 + 255) / 256, 256, 0, stream>>>(Wo, wto, 128, 128);
  k_transpose<<<(65536 + 255) / 256, 256, 0, stream>>>(Wgates, wtg, 512, 128);

  dim3 g1(256, 8);
  k_proj<<<g1, 256, 0, stream>>>(x, h, wtp, bproj, buf1);
  k_attn<<<8192, 256, 0, stream>>>(buf1, ln_g, ln_b, wtq, bqkv, wto, bo, buf2);
  k_stats<<<256, 256, 0, stream>>>(buf2, stA_raw);
  k_stats_fin<<<1, 64, 0, stream>>>(stA_raw, stA);
  k_gates<<<8192, 256, 0, stream>>>(buf2, stA, gn_g, gn_b, wtg, bgates, c, cnext, buf1);
  k_stats<<<256, 256, 0, stream>>>(buf1, stB_raw);
  k_stats_fin<<<1, 64, 0, stream>>>(stB_raw, stB);
  k_gnout<<<16384, 256, 0, stream>>>(buf1, stB, gn_g, gn_b, hnext);
}

// Round 3
// 286.164 us; speedup vs baseline: 3.0035x; 3.0035x over previous
//
#include <hip/hip_runtime.h>
#include <math.h>

typedef unsigned int uint;
typedef unsigned short ushort;
typedef short s16x8 __attribute__((ext_vector_type(8)));
typedef float f32x4 __attribute__((ext_vector_type(4)));

#define PIX 16384
#define EPSF 1e-5f

__device__ __forceinline__ ushort f2bf(float f) {
  union { float f; uint u; } v; v.f = f;
  uint u = v.u;
  uint r = (u + 0x7FFFu + ((u >> 16) & 1u)) >> 16;
  return (ushort)r;
}
__device__ __forceinline__ float bf2f(ushort h) {
  union { uint u; float f; } v; v.u = ((uint)h) << 16;
  return v.f;
}
__device__ __forceinline__ uint pk2(float a, float b) {
  return (uint)f2bf(a) | ((uint)f2bf(b) << 16);
}
__device__ __forceinline__ float fsigmoid(float v) { return 1.f / (1.f + __expf(-v)); }
__device__ __forceinline__ float ftanh(float v) { return 1.f - 2.f / (__expf(2.f * v) + 1.f); }

union Frag { uint4 u4; uint u[4]; s16x8 s; };

// ---------------- weight fragment prep ----------------
// frag (mt, ks): lane l elem j = W[mt*16 + (l&15)][ks*32 + (l>>4)*8 + j]
__global__ void k_prepA(const float* __restrict__ W, ushort* __restrict__ F,
                        int MT, int KS, int ldw) {
  int idx = blockIdx.x * 256 + threadIdx.x;
  if (idx >= MT * KS * 64) return;
  int l = idx & 63, rest = idx >> 6;
  int ks = rest % KS, mt = rest / KS;
  const float* src = W + (size_t)(mt * 16 + (l & 15)) * ldw + ks * 32 + (l >> 4) * 8;
  uint4 v;
  v.x = pk2(src[0], src[1]);
  v.y = pk2(src[2], src[3]);
  v.z = pk2(src[4], src[5]);
  v.w = pk2(src[6], src[7]);
  *reinterpret_cast<uint4*>(F + (size_t)idx * 8) = v;
}

// ---------------- fused proj + LN + window MHSA + Wo (+GN stats) ----------------
__global__ __launch_bounds__(256) void k_attn(
    const float* __restrict__ x, const float* __restrict__ h,
    const ushort* __restrict__ FWp, const float* __restrict__ bproj,
    const float* __restrict__ ln_g, const float* __restrict__ ln_b,
    const ushort* __restrict__ FWq, const float* __restrict__ bqkv,
    const ushort* __restrict__ FWoT, const float* __restrict__ bo,
    ushort* __restrict__ attn_map, float* __restrict__ stA_raw)
{
  __shared__ __align__(16) char LM[75136];
  __shared__ float sStat[16];
  uint*   sInP  = (uint*)LM;                 // [96][65] dword pairs (phases 0-1)
  ushort* sXn   = (ushort*)LM;               // [4][16][136] (phases 2-3)
  ushort* sP    = (ushort*)LM;               // [4][4][16][32] (phases 4-5)
  ushort* sFin  = (ushort*)LM;               // [4][128][16] (phases 6-7)
  ushort* sProj = (ushort*)(LM + 24960);     // [4][16][136] (phases 1-2)
  ushort* sQK   = (ushort*)(LM + 24960);     // [4][16][264] (phases 3-4)
  ushort* sO    = (ushort*)(LM + 24960);     // [4][16][136] (phases 5-6)
  ushort* sV    = (ushort*)(LM + 58752);     // [4][128][16] (phases 3-5)

  const int t = threadIdx.x;
  const int bid = blockIdx.x;
  const int b = bid >> 8, wh = (bid >> 3) & 31, ww0 = bid & 7;
  const int w = t >> 6, l = t & 63, q = l >> 4, r16 = l & 15;

  if (t < 16) sStat[t] = 0.f;

  // ---- phase 0: stage concat(x,h) window-group -> sInP (bf16 dword pairs) ----
  const size_t xbase = (size_t)b * 64 * PIX;
  const size_t hbase = (size_t)b * 128 * PIX;
  #pragma unroll
  for (int it = 0; it < 24; it++) {
    int idx = it * 256 + t;            // [0, 6144)
    int pr = idx >> 6, p = idx & 63;
    int r = p >> 4, cc = p & 15;
    int gpix = (wh * 4 + r) * 128 + ww0 * 16 + cc;
    int i0 = pr * 2;
    float a, c2;
    if (i0 < 64) {
      a  = x[xbase + (size_t)i0 * PIX + gpix];
      c2 = x[xbase + (size_t)(i0 + 1) * PIX + gpix];
    } else {
      a  = h[hbase + (size_t)(i0 - 64) * PIX + gpix];
      c2 = h[hbase + (size_t)(i0 - 63) * PIX + gpix];
    }
    sInP[pr * 65 + p] = pk2(a, c2);
  }
  __syncthreads();

  // ---- phase 1: proj MFMA (M=128 chans, N=16 toks of this wave's window) ----
  {
    int p = (r16 >> 2) * 16 + w * 4 + (r16 & 3);   // block-px of tok=r16 in window w
    f32x4 acc[8];
    #pragma unroll
    for (int m = 0; m < 8; m++) acc[m] = (f32x4){0.f, 0.f, 0.f, 0.f};
    for (int ks = 0; ks < 6; ks++) {
      Frag bf;
      #pragma unroll
      for (int s = 0; s < 4; s++)
        bf.u[s] = sInP[(ks * 16 + q * 4 + s) * 65 + p];
      #pragma unroll
      for (int m = 0; m < 8; m++) {
        Frag af;
        af.u4 = *reinterpret_cast<const uint4*>(FWp + ((m * 6 + ks) * 64 + l) * 8);
        acc[m] = __builtin_amdgcn_mfma_f32_16x16x32_bf16(af.s, bf.s, acc[m], 0, 0, 0);
      }
    }
    ushort* dst = sProj + (w * 16 + r16) * 136;    // D col = tok = r16
    #pragma unroll
    for (int m = 0; m < 8; m++) {
      int o0 = m * 16 + q * 4;                     // D row = o0 + reg
      const float4 bv = *reinterpret_cast<const float4*>(bproj + o0);
      uint2 pk;
      pk.x = pk2(acc[m][0] + bv.x, acc[m][1] + bv.y);
      pk.y = pk2(acc[m][2] + bv.z, acc[m][3] + bv.w);
      *reinterpret_cast<uint2*>(dst + o0) = pk;
    }
  }
  __syncthreads();

  // ---- phase 2: LayerNorm sProj -> sXn ----
  {
    int tok = (t >> 2) & 15, g2 = t & 3;
    const ushort* row = sProj + (w * 16 + tok) * 136 + g2 * 32;
    float v[32];
    #pragma unroll
    for (int i = 0; i < 4; i++) {
      uint4 u = *reinterpret_cast<const uint4*>(row + i * 8);
      v[i*8+0] = bf2f((ushort)(u.x & 0xFFFFu)); v[i*8+1] = bf2f((ushort)(u.x >> 16));
      v[i*8+2] = bf2f((ushort)(u.y & 0xFFFFu)); v[i*8+3] = bf2f((ushort)(u.y >> 16));
      v[i*8+4] = bf2f((ushort)(u.z & 0xFFFFu)); v[i*8+5] = bf2f((ushort)(u.z >> 16));
      v[i*8+6] = bf2f((ushort)(u.w & 0xFFFFu)); v[i*8+7] = bf2f((ushort)(u.w >> 16));
    }
    float s = 0.f, s2 = 0.f;
    #pragma unroll
    for (int i = 0; i < 32; i++) { s += v[i]; s2 += v[i] * v[i]; }
    s  += __shfl_xor(s, 1);  s  += __shfl_xor(s, 2);
    s2 += __shfl_xor(s2, 1); s2 += __shfl_xor(s2, 2);
    float mu = s * 0.0078125f;
    float var = s2 * 0.0078125f - mu * mu;
    float rstd = rsqrtf(var + EPSF);
    ushort* orow = sXn + (w * 16 + tok) * 136 + g2 * 32;
    #pragma unroll
    for (int i = 0; i < 4; i++) {
      const float4 ga = *reinterpret_cast<const float4*>(ln_g + g2 * 32 + i * 8);
      const float4 gb = *reinterpret_cast<const float4*>(ln_g + g2 * 32 + i * 8 + 4);
      const float4 ba = *reinterpret_cast<const float4*>(ln_b + g2 * 32 + i * 8);
      const float4 bb = *reinterpret_cast<const float4*>(ln_b + g2 * 32 + i * 8 + 4);
      float n0 = (v[i*8+0] - mu) * rstd * ga.x + ba.x;
      float n1 = (v[i*8+1] - mu) * rstd * ga.y + ba.y;
      float n2 = (v[i*8+2] - mu) * rstd * ga.z + ba.z;
      float n3 = (v[i*8+3] - mu) * rstd * ga.w + ba.w;
      float n4 = (v[i*8+4] - mu) * rstd * gb.x + bb.x;
      float n5 = (v[i*8+5] - mu) * rstd * gb.y + bb.y;
      float n6 = (v[i*8+6] - mu) * rstd * gb.z + bb.z;
      float n7 = (v[i*8+7] - mu) * rstd * gb.w + bb.w;
      uint4 o;
      o.x = pk2(n0, n1); o.y = pk2(n2, n3); o.z = pk2(n4, n5); o.w = pk2(n6, n7);
      *reinterpret_cast<uint4*>(orow + i * 8) = o;
    }
  }
  __syncthreads();

  // ---- phase 3: QKV MFMA -> sQK (Q,K transposed) and sV ----
  {
    for (int chunk = 0; chunk < 4; chunk++) {
      f32x4 acc[6];
      #pragma unroll
      for (int i = 0; i < 6; i++) acc[i] = (f32x4){0.f, 0.f, 0.f, 0.f};
      for (int ks = 0; ks < 4; ks++) {
        Frag bf;
        bf.u4 = *reinterpret_cast<const uint4*>(sXn + (w * 16 + r16) * 136 + ks * 32 + q * 8);
        #pragma unroll
        for (int i = 0; i < 6; i++) {
          int mt = chunk * 6 + i;
          Frag af;
          af.u4 = *reinterpret_cast<const uint4*>(FWq + ((mt * 4 + ks) * 64 + l) * 8);
          acc[i] = __builtin_amdgcn_mfma_f32_16x16x32_bf16(af.s, bf.s, acc[i], 0, 0, 0);
        }
      }
      #pragma unroll
      for (int i = 0; i < 6; i++) {
        int mt = chunk * 6 + i;
        int oo = mt * 16 + q * 4;
        const float4 bv = *reinterpret_cast<const float4*>(bqkv + oo);
        float v0 = acc[i][0] + bv.x, v1 = acc[i][1] + bv.y;
        float v2 = acc[i][2] + bv.z, v3 = acc[i][3] + bv.w;
        if (mt < 16) {
          uint2 pk; pk.x = pk2(v0, v1); pk.y = pk2(v2, v3);
          *reinterpret_cast<uint2*>(sQK + (w * 16 + r16) * 264 + oo) = pk;
        } else {
          ushort* vd = sV + w * 2048 + (oo - 256) * 16 + r16;
          vd[0] = f2bf(v0); vd[16] = f2bf(v1); vd[32] = f2bf(v2); vd[48] = f2bf(v3);
        }
      }
    }
  }
  __syncthreads();

  // ---- phase 4: scores + softmax -> sP (zero-padded cols 16..31) ----
  {
    const float scale = 0.17677669529663687f;
    #pragma unroll
    for (int hd = 0; hd < 4; hd++) {
      if (l < 32) {
        int row = l >> 1, hz = l & 1;
        uint4 z = {0u, 0u, 0u, 0u};
        *reinterpret_cast<uint4*>(sP + w * 2048 + hd * 512 + row * 32 + 16 + hz * 8) = z;
      }
    }
    f32x4 sc[4];
    #pragma unroll
    for (int hd = 0; hd < 4; hd++) {
      Frag af, bf;
      af.u4 = *reinterpret_cast<const uint4*>(sQK + (w * 16 + r16) * 264 + hd * 32 + q * 8);
      bf.u4 = *reinterpret_cast<const uint4*>(sQK + (w * 16 + r16) * 264 + 128 + hd * 32 + q * 8);
      f32x4 z4 = (f32x4){0.f, 0.f, 0.f, 0.f};
      sc[hd] = __builtin_amdgcn_mfma_f32_16x16x32_bf16(af.s, bf.s, z4, 0, 0, 0);
    }
    #pragma unroll
    for (int hd = 0; hd < 4; hd++) {
      ushort* pd = sP + w * 2048 + hd * 512 + (q * 4) * 32 + r16;
      #pragma unroll
      for (int r = 0; r < 4; r++) {
        float sv = sc[hd][r] * scale;
        float mx = sv;
        mx = fmaxf(mx, __shfl_xor(mx, 1));
        mx = fmaxf(mx, __shfl_xor(mx, 2));
        mx = fmaxf(mx, __shfl_xor(mx, 4));
        mx = fmaxf(mx, __shfl_xor(mx, 8));
        float e = __expf(sv - mx);
        float sm = e;
        sm += __shfl_xor(sm, 1); sm += __shfl_xor(sm, 2);
        sm += __shfl_xor(sm, 4); sm += __shfl_xor(sm, 8);
        pd[r * 32] = f2bf(e / sm);
      }
    }
  }
  __syncthreads();

  // ---- phase 5: PV MFMA -> sO [tok][chan] ----
  {
    #pragma unroll
    for (int hd = 0; hd < 4; hd++) {
      Frag pa;
      pa.u4 = *reinterpret_cast<const uint4*>(sP + w * 2048 + hd * 512 + r16 * 32 + q * 8);
      #pragma unroll
      for (int nt = 0; nt < 2; nt++) {
        int ch = hd * 32 + nt * 16 + r16;
        int off = (q < 2) ? q * 8 : 0;   // q>=2 slots multiply zero P-cols
        Frag vf;
        vf.u4 = *reinterpret_cast<const uint4*>(sV + w * 2048 + ch * 16 + off);
        f32x4 z4 = (f32x4){0.f, 0.f, 0.f, 0.f};
        f32x4 o4 = __builtin_amdgcn_mfma_f32_16x16x32_bf16(pa.s, vf.s, z4, 0, 0, 0);
        ushort* od = sO + (w * 16 + q * 4) * 136 + ch;
        od[0] = f2bf(o4[0]); od[136] = f2bf(o4[1]);
        od[272] = f2bf(o4[2]); od[408] = f2bf(o4[3]);
      }
    }
  }
  __syncthreads();

  // ---- phase 6: Wo MFMA -> sFin [chan][tok] (ALL 8 channel tiles per window) ----
  {
    Frag a4[4];
    #pragma unroll
    for (int ks = 0; ks < 4; ks++)
      a4[ks].u4 = *reinterpret_cast<const uint4*>(sO + (w * 16 + r16) * 136 + ks * 32 + q * 8);
    #pragma unroll
    for (int ntg = 0; ntg < 8; ntg++) {
      f32x4 acc = (f32x4){0.f, 0.f, 0.f, 0.f};
      #pragma unroll
      for (int ks = 0; ks < 4; ks++) {
        Frag bf;
        bf.u4 = *reinterpret_cast<const uint4*>(FWoT + ((ntg * 4 + ks) * 64 + l) * 8);
        acc = __builtin_amdgcn_mfma_f32_16x16x32_bf16(a4[ks].s, bf.s, acc, 0, 0, 0);
      }
      int ch = ntg * 16 + r16;
      float bb = bo[ch];
      uint2 pk;
      pk.x = pk2(acc[0] + bb, acc[1] + bb);
      pk.y = pk2(acc[2] + bb, acc[3] + bb);
      *reinterpret_cast<uint2*>(sFin + (w * 128 + ch) * 16 + q * 4) = pk;
    }
  }
  __syncthreads();

  // ---- phase 7: coalesced writeout (2 windows per 16B) + GN partial stats ----
  {
    #pragma unroll
    for (int it = 0; it < 4; it++) {
      int seg = it * 256 + t;            // [0,1024)
      int ch = seg >> 3, r = (seg >> 1) & 3, half = seg & 1;
      uint2 a  = *reinterpret_cast<const uint2*>(sFin + (half * 2) * 2048 + ch * 16 + r * 4);
      uint2 c2 = *reinterpret_cast<const uint2*>(sFin + (half * 2 + 1) * 2048 + ch * 16 + r * 4);
      uint4 val = {a.x, a.y, c2.x, c2.y};
      *reinterpret_cast<uint4*>(attn_map + (size_t)(b * 128 + ch) * PIX
                                + (wh * 4 + r) * 128 + ww0 * 16 + half * 8) = val;
      float sv = 0.f, sv2 = 0.f;
      uint uu[4] = {val.x, val.y, val.z, val.w};
      #pragma unroll
      for (int k2 = 0; k2 < 4; k2++) {
        float f0 = bf2f((ushort)(uu[k2] & 0xFFFFu));
        float f1 = bf2f((ushort)(uu[k2] >> 16));
        sv += f0 + f1; sv2 += f0 * f0 + f1 * f1;
      }
      sv  += __shfl_xor(sv, 1);  sv  += __shfl_xor(sv, 2);  sv  += __shfl_xor(sv, 4);
      sv2 += __shfl_xor(sv2, 1); sv2 += __shfl_xor(sv2, 2); sv2 += __shfl_xor(sv2, 4);
      if ((t & 7) == 0) {
        int g = ch >> 4;
        atomicAdd(&sStat[g * 2], sv);
        atomicAdd(&sStat[g * 2 + 1], sv2);
      }
    }
  }
  __syncthreads();
  if (t < 16) atomicAdd(&stA_raw[b * 16 + t], sStat[t]);
}

// ---------------- stats finalize ----------------
__global__ void k_stats_fin(const float* __restrict__ raw, float* __restrict__ fin) {
  int i = threadIdx.x;
  if (i < 64) {
    const float invN = 1.f / 262144.f;
    float mu = raw[i * 2] * invN;
    float var = raw[i * 2 + 1] * invN - mu * mu;
    fin[i * 2] = mu;
    fin[i * 2 + 1] = rsqrtf(var + EPSF);
  }
}

// ---------------- GN + gates MFMA + LSTM update (+stats for GN2) ----------------
__global__ __launch_bounds__(256) void k_gates(
    const ushort* __restrict__ attn_map, const float* __restrict__ statsA,
    const float* __restrict__ gn_g, const float* __restrict__ gn_b,
    const ushort* __restrict__ FWg, const float* __restrict__ bgates,
    const float* __restrict__ c, float* __restrict__ cnext,
    ushort* __restrict__ tbuf, float* __restrict__ stB_raw)
{
  __shared__ uint sG[64 * 65];
  __shared__ float sA[128], sB[128];
  __shared__ float sStat[16];
  const int t = threadIdx.x, bid = blockIdx.x;
  const int b = bid >> 8, p0 = (bid & 255) * 64;
  const int w = t >> 6, l = t & 63, q = l >> 4, r16 = l & 15;
  if (t < 128) {
    int g = t >> 4;
    float mu = statsA[(b * 8 + g) * 2], rs = statsA[(b * 8 + g) * 2 + 1];
    float A = rs * gn_g[t];
    sA[t] = A; sB[t] = gn_b[t] - mu * A;
  }
  if (t >= 240) sStat[t - 240] = 0.f;
  __syncthreads();

  const size_t abase = (size_t)b * 128 * PIX + p0;
  #pragma unroll
  for (int it = 0; it < 16; it++) {
    int idx = it * 256 + t;
    int pr = idx >> 6, p = idx & 63;
    int c0 = pr * 2;
    float v0 = bf2f(attn_map[abase + (size_t)c0 * PIX + p]) * sA[c0] + sB[c0];
    float v1 = bf2f(attn_map[abase + (size_t)(c0 + 1) * PIX + p]) * sA[c0 + 1] + sB[c0 + 1];
    sG[pr * 65 + p] = pk2(v0, v1);
  }
  __syncthreads();

  f32x4 acc[8][4];
  #pragma unroll
  for (int mi = 0; mi < 8; mi++)
    #pragma unroll
    for (int nt = 0; nt < 4; nt++) acc[mi][nt] = (f32x4){0.f, 0.f, 0.f, 0.f};

  for (int ks = 0; ks < 4; ks++) {
    Frag bf[4];
    #pragma unroll
    for (int nt = 0; nt < 4; nt++)
      #pragma unroll
      for (int s = 0; s < 4; s++)
        bf[nt].u[s] = sG[(ks * 16 + q * 4 + s) * 65 + nt * 16 + r16];
    #pragma unroll
    for (int mi = 0; mi < 8; mi++) {
      int mt = w + mi * 4;
      Frag af;
      af.u4 = *reinterpret_cast<const uint4*>(FWg + ((mt * 4 + ks) * 64 + l) * 8);
      #pragma unroll
      for (int nt = 0; nt < 4; nt++)
        acc[mi][nt] = __builtin_amdgcn_mfma_f32_16x16x32_bf16(af.s, bf[nt].s, acc[mi][nt], 0, 0, 0);
    }
  }

  float gs[2] = {0.f, 0.f}, gs2[2] = {0.f, 0.f};
  #pragma unroll
  for (int mi2 = 0; mi2 < 2; mi2++) {
    int ch0 = (w + mi2 * 4) * 16 + q * 4;
    const float4 bi = *reinterpret_cast<const float4*>(bgates + ch0);
    const float4 bfg = *reinterpret_cast<const float4*>(bgates + 128 + ch0);
    const float4 bog = *reinterpret_cast<const float4*>(bgates + 256 + ch0);
    const float4 bgg = *reinterpret_cast<const float4*>(bgates + 384 + ch0);
    const float bis[4] = {bi.x, bi.y, bi.z, bi.w};
    const float bfs[4] = {bfg.x, bfg.y, bfg.z, bfg.w};
    const float bos[4] = {bog.x, bog.y, bog.z, bog.w};
    const float bgs[4] = {bgg.x, bgg.y, bgg.z, bgg.w};
    #pragma unroll
    for (int nt = 0; nt < 4; nt++) {
      int px = p0 + nt * 16 + r16;
      #pragma unroll
      for (int r = 0; r < 4; r++) {
        int ch = ch0 + r;
        float ig = fsigmoid(acc[mi2    ][nt][r] + bis[r]);
        float fg = fsigmoid(acc[mi2 + 2][nt][r] + bfs[r]);
        float og = fsigmoid(acc[mi2 + 4][nt][r] + bos[r]);
        float gg = ftanh   (acc[mi2 + 6][nt][r] + bgs[r]);
        size_t gidx = (size_t)(b * 128 + ch) * PIX + px;
        float cv = c[gidx];
        float cn = fg * cv + ig * gg;
        cnext[gidx] = cn;
        float tv = og * ftanh(cn);
        tbuf[gidx] = f2bf(tv);
        gs[mi2] += tv; gs2[mi2] += tv * tv;
      }
    }
  }
  #pragma unroll
  for (int mi2 = 0; mi2 < 2; mi2++) {
    float s = gs[mi2], s2 = gs2[mi2];
    s += __shfl_xor(s, 1); s += __shfl_xor(s, 2); s += __shfl_xor(s, 4);
    s += __shfl_xor(s, 8); s += __shfl_xor(s, 16); s += __shfl_xor(s, 32);
    s2 += __shfl_xor(s2, 1); s2 += __shfl_xor(s2, 2); s2 += __shfl_xor(s2, 4);
    s2 += __shfl_xor(s2, 8); s2 += __shfl_xor(s2, 16); s2 += __shfl_xor(s2, 32);
    if (l == 0) {
      int g = w + mi2 * 4;
      atomicAdd(&sStat[g * 2], s);
      atomicAdd(&sStat[g * 2 + 1], s2);
    }
  }
  __syncthreads();
  if (t < 16) atomicAdd(&stB_raw[b * 16 + t], sStat[t]);
}

// ---------------- hnext = GN2(tbuf) ----------------
__global__ __launch_bounds__(256) void k_gnout(
    const ushort* __restrict__ tbuf, const float* __restrict__ statsB,
    const float* __restrict__ gn_g, const float* __restrict__ gn_b,
    float* __restrict__ hnext)
{
  size_t idx = ((size_t)blockIdx.x * 256 + threadIdx.x) * 8;
  int chrow = (int)(idx >> 14);
  int b = chrow >> 7, ch = chrow & 127, g = ch >> 4;
  float mu = statsB[(b * 8 + g) * 2], rstd = statsB[(b * 8 + g) * 2 + 1];
  float A = gn_g[ch] * rstd, Bv = gn_b[ch] - mu * A;
  uint4 u = *reinterpret_cast<const uint4*>(tbuf + idx);
  float4 o0, o1;
  o0.x = bf2f((ushort)(u.x & 0xFFFFu)) * A + Bv;
  o0.y = bf2f((ushort)(u.x >> 16)) * A + Bv;
  o0.z = bf2f((ushort)(u.y & 0xFFFFu)) * A + Bv;
  o0.w = bf2f((ushort)(u.y >> 16)) * A + Bv;
  o1.x = bf2f((ushort)(u.z & 0xFFFFu)) * A + Bv;
  o1.y = bf2f((ushort)(u.z >> 16)) * A + Bv;
  o1.z = bf2f((ushort)(u.w & 0xFFFFu)) * A + Bv;
  o1.w = bf2f((ushort)(u.w >> 16)) * A + Bv;
  *reinterpret_cast<float4*>(hnext + idx) = o0;
  *reinterpret_cast<float4*>(hnext + idx + 4) = o1;
}

extern "C" void kernel_launch(void* const* d_in, const int* in_sizes, int n_in,
                              void* d_out, int out_size, void* d_ws, size_t ws_size,
                              hipStream_t stream) {
  (void)in_sizes; (void)n_in; (void)out_size; (void)ws_size;
  const float* x      = (const float*)d_in[0];
  const float* h      = (const float*)d_in[1];
  const float* c      = (const float*)d_in[2];
  const float* Wproj  = (const float*)d_in[3];
  const float* bproj  = (const float*)d_in[4];
  const float* ln_g   = (const float*)d_in[5];
  const float* ln_b   = (const float*)d_in[6];
  const float* Wqkv   = (const float*)d_in[7];
  const float* bqkv   = (const float*)d_in[8];
  const float* Wo     = (const float*)d_in[9];
  const float* bo     = (const float*)d_in[10];
  const float* Wgates = (const float*)d_in[11];
  const float* bgates = (const float*)d_in[12];
  const float* gn_g   = (const float*)d_in[13];
  const float* gn_b   = (const float*)d_in[14];

  float* out = (float*)d_out;
  float* hnext = out;
  float* cnext = out + 16777216;

  char* W = (char*)d_ws;
  ushort* attn = (ushort*)W;                          // 32 MB bf16
  ushort* tbuf = (ushort*)(W + 33554432);             // 32 MB bf16
  size_t off = 67108864;
  ushort* FWp = (ushort*)(W + off); off += 49152;     // 8*6*64*16B
  ushort* FWq = (ushort*)(W + off); off += 98304;     // 24*4*64*16B
  ushort* FWo = (ushort*)(W + off); off += 32768;     // 8*4*64*16B
  ushort* FWg = (ushort*)(W + off); off += 131072;    // 32*4*64*16B
  float* stA_raw = (float*)(W + off); off += 512;
  float* stB_raw = (float*)(W + off); off += 512;
  float* stA     = (float*)(W + off); off += 512;
  float* stB     = (float*)(W + off); off += 512;

  hipMemsetAsync(stA_raw, 0, 1024, stream);

  k_prepA<<<(3072 + 255) / 256, 256, 0, stream>>>(Wproj, FWp, 8, 6, 192);
  k_prepA<<<(6144 + 255) / 256, 256, 0, stream>>>(Wqkv, FWq, 24, 4, 128);
  k_prepA<<<(2048 + 255) / 256, 256, 0, stream>>>(Wo, FWo, 8, 4, 128);
  k_prepA<<<(8192 + 255) / 256, 256, 0, stream>>>(Wgates, FWg, 32, 4, 128);

  k_attn<<<2048, 256, 0, stream>>>(x, h, FWp, bproj, ln_g, ln_b,
                                   FWq, bqkv, FWo, bo, attn, stA_raw);
  k_stats_fin<<<1, 64, 0, stream>>>(stA_raw, stA);
  k_gates<<<2048, 256, 0, stream>>>(attn, stA, gn_g, gn_b, FWg, bgates,
                                    c, cnext, tbuf, stB_raw);
  k_stats_fin<<<1, 64, 0, stream>>>(stB_raw, stB);
  k_gnout<<<8192, 256, 0, stream>>>(tbuf, stB, gn_g, gn_b, hnext);
}

// Round 5
// 255.501 us; speedup vs baseline: 3.3640x; 1.1200x over previous
//
#include <hip/hip_runtime.h>
#include <math.h>

typedef unsigned int uint;
typedef unsigned short ushort;
typedef short s16x8 __attribute__((ext_vector_type(8)));
typedef float f32x4 __attribute__((ext_vector_type(4)));

#define PIX 16384
#define EPSF 1e-5f

__device__ __forceinline__ ushort f2bf(float f) {
  union { float f; uint u; } v; v.f = f;
  uint u = v.u;
  uint r = (u + 0x7FFFu + ((u >> 16) & 1u)) >> 16;
  return (ushort)r;
}
__device__ __forceinline__ float bf2f(ushort h) {
  union { uint u; float f; } v; v.u = ((uint)h) << 16;
  return v.f;
}
__device__ __forceinline__ uint pk2(float a, float b) {
  return (uint)f2bf(a) | ((uint)f2bf(b) << 16);
}
__device__ __forceinline__ float fsigmoid(float v) { return 1.f / (1.f + __expf(-v)); }
__device__ __forceinline__ float ftanh(float v) { return 1.f - 2.f / (__expf(2.f * v) + 1.f); }

union Frag { uint4 u4; uint u[4]; s16x8 s; };

// ---------------- merged weight fragment prep ----------------
// frag (mt, ks): lane l elem j = W[mt*16 + (l&15)][ks*32 + (l>>4)*8 + j]
__global__ void k_prep(const float* __restrict__ Wp, const float* __restrict__ Wq,
                       const float* __restrict__ Wo, const float* __restrict__ Wg,
                       ushort* __restrict__ FWp, ushort* __restrict__ FWq,
                       ushort* __restrict__ FWo, ushort* __restrict__ FWg) {
  int idx = blockIdx.x * 256 + threadIdx.x;   // [0, 19456)
  const float* W; ushort* F; int KS, ldw, rel;
  if (idx < 3072)       { W = Wp; F = FWp; KS = 6; ldw = 192; rel = idx; }
  else if (idx < 9216)  { W = Wq; F = FWq; KS = 4; ldw = 128; rel = idx - 3072; }
  else if (idx < 11264) { W = Wo; F = FWo; KS = 4; ldw = 128; rel = idx - 9216; }
  else                  { W = Wg; F = FWg; KS = 4; ldw = 128; rel = idx - 11264; }
  int l = rel & 63, rest = rel >> 6;
  int ks = rest % KS, mt = rest / KS;
  const float* src = W + (size_t)(mt * 16 + (l & 15)) * ldw + ks * 32 + (l >> 4) * 8;
  uint4 v;
  v.x = pk2(src[0], src[1]);
  v.y = pk2(src[2], src[3]);
  v.z = pk2(src[4], src[5]);
  v.w = pk2(src[6], src[7]);
  *reinterpret_cast<uint4*>(F + (size_t)rel * 8) = v;
}

// ---------------- fused proj + LN + window MHSA + Wo (+GN stats) ----------------
// Per-wave arena (12544 B), phases 2+ are barrier-free (per-wave ordering only):
//   [0    , 4352 ): aXn [16][136]   (ph2-3)  -> aP [4][16][32] (ph4-5, after hoisted QK reads)
//   [0    , 8448 ): aQK [16][264]   (ph3-4)  (overlays aXn after hoisted xn reads)
//   [4096 , 8448 ): aO  [16][136]   (ph5-6)
//   [8448 ,12544 ): aV  [128][16]   (ph3-5)  -> aFin [128][16] (ph6-7)
// Staging sInP [96][68] dwords (26112 B) lives at LM[0..) during ph0-1 only.
#define ARN 12544
__global__ __launch_bounds__(256, 3) void k_attn(
    const float* __restrict__ x, const float* __restrict__ h,
    const ushort* __restrict__ FWp, const float* __restrict__ bproj,
    const float* __restrict__ ln_g, const float* __restrict__ ln_b,
    const ushort* __restrict__ FWq, const float* __restrict__ bqkv,
    const ushort* __restrict__ FWoT, const float* __restrict__ bo,
    ushort* __restrict__ attn_map, float* __restrict__ stA_raw)
{
  __shared__ __align__(16) char LM[4 * ARN];
  __shared__ float sStat[16];

  const int t = threadIdx.x;
  const int bid = blockIdx.x;
  const int b = bid >> 8, wh = (bid >> 3) & 31, ww0 = bid & 7;
  const int w = t >> 6, l = t & 63, q = l >> 4, r16 = l & 15;

  uint* sInP = (uint*)LM;                       // [96][68] dwords, ph0-1
  char* AR = LM + w * ARN;
  ushort* aXn  = (ushort*)AR;
  ushort* aQK  = (ushort*)AR;
  ushort* aP   = (ushort*)AR;
  ushort* aO   = (ushort*)(AR + 4096);
  ushort* aV   = (ushort*)(AR + 8448);
  ushort* aFin = (ushort*)(AR + 8448);

  if (t < 16) sStat[t] = 0.f;

  // ---- phase 0: vectorized staging concat(x,h) -> sInP[chp][col], col = w*16 + tok ----
  {
    const float* xb = x + (size_t)b * 64 * PIX;
    const float* hb = h + (size_t)b * 128 * PIX;
    #pragma unroll
    for (int it = 0; it < 6; it++) {
      int item = it * 256 + t;                 // [0,1536)
      int wv = item & 3, r = (item >> 2) & 3, chp = item >> 4;   // chp in [0,96)
      int ch0 = chp * 2;
      int gpix = (wh * 4 + r) * 128 + ww0 * 16 + wv * 4;
      float4 a, c2;
      if (ch0 < 64) {
        a  = *reinterpret_cast<const float4*>(xb + (size_t)ch0 * PIX + gpix);
        c2 = *reinterpret_cast<const float4*>(xb + (size_t)(ch0 + 1) * PIX + gpix);
      } else {
        a  = *reinterpret_cast<const float4*>(hb + (size_t)(ch0 - 64) * PIX + gpix);
        c2 = *reinterpret_cast<const float4*>(hb + (size_t)(ch0 - 63) * PIX + gpix);
      }
      uint4 pkd;
      pkd.x = pk2(a.x, c2.x); pkd.y = pk2(a.y, c2.y);
      pkd.z = pk2(a.z, c2.z); pkd.w = pk2(a.w, c2.w);
      *reinterpret_cast<uint4*>(sInP + chp * 68 + wv * 16 + r * 4) = pkd;
    }
  }
  __syncthreads();   // B1: staging complete

  // ---- phase 1: proj MFMA, accumulators stay in registers across B2 ----
  f32x4 acc1[8];
  {
    int p = w * 16 + r16;                       // col = this wave's token r16
    #pragma unroll
    for (int m = 0; m < 8; m++) acc1[m] = (f32x4){0.f, 0.f, 0.f, 0.f};
    for (int ks = 0; ks < 6; ks++) {
      Frag bf;
      #pragma unroll
      for (int s = 0; s < 4; s++)
        bf.u[s] = sInP[(ks * 16 + q * 4 + s) * 68 + p];
      #pragma unroll
      for (int m = 0; m < 8; m++) {
        Frag af;
        af.u4 = *reinterpret_cast<const uint4*>(FWp + ((m * 6 + ks) * 64 + l) * 8);
        acc1[m] = __builtin_amdgcn_mfma_f32_16x16x32_bf16(af.s, bf.s, acc1[m], 0, 0, 0);
      }
    }
  }
  __syncthreads();   // B2: all sInP reads done; arenas may now overlay staging

  // ---- phase 1b: bias + pack -> aXn [tok][ch] (per-wave from here on, no barriers) ----
  {
    #pragma unroll
    for (int m = 0; m < 8; m++) {
      int o0 = m * 16 + q * 4;
      const float4 bv = *reinterpret_cast<const float4*>(bproj + o0);
      uint2 pk;
      pk.x = pk2(acc1[m][0] + bv.x, acc1[m][1] + bv.y);
      pk.y = pk2(acc1[m][2] + bv.z, acc1[m][3] + bv.w);
      *reinterpret_cast<uint2*>(aXn + r16 * 136 + o0) = pk;
    }
  }

  // ---- phase 2: LayerNorm aXn -> aXn (in place) ----
  {
    int tok = (t >> 2) & 15, g2 = t & 3;
    const ushort* row = aXn + tok * 136 + g2 * 32;
    float v[32];
    #pragma unroll
    for (int i = 0; i < 4; i++) {
      uint4 u = *reinterpret_cast<const uint4*>(row + i * 8);
      v[i*8+0] = bf2f((ushort)(u.x & 0xFFFFu)); v[i*8+1] = bf2f((ushort)(u.x >> 16));
      v[i*8+2] = bf2f((ushort)(u.y & 0xFFFFu)); v[i*8+3] = bf2f((ushort)(u.y >> 16));
      v[i*8+4] = bf2f((ushort)(u.z & 0xFFFFu)); v[i*8+5] = bf2f((ushort)(u.z >> 16));
      v[i*8+6] = bf2f((ushort)(u.w & 0xFFFFu)); v[i*8+7] = bf2f((ushort)(u.w >> 16));
    }
    float s = 0.f, s2 = 0.f;
    #pragma unroll
    for (int i = 0; i < 32; i++) { s += v[i]; s2 += v[i] * v[i]; }
    s  += __shfl_xor(s, 1);  s  += __shfl_xor(s, 2);
    s2 += __shfl_xor(s2, 1); s2 += __shfl_xor(s2, 2);
    float mu = s * 0.0078125f;
    float var = s2 * 0.0078125f - mu * mu;
    float rstd = rsqrtf(var + EPSF);
    ushort* orow = aXn + tok * 136 + g2 * 32;
    #pragma unroll
    for (int i = 0; i < 4; i++) {
      const float4 ga = *reinterpret_cast<const float4*>(ln_g + g2 * 32 + i * 8);
      const float4 gb = *reinterpret_cast<const float4*>(ln_g + g2 * 32 + i * 8 + 4);
      const float4 ba = *reinterpret_cast<const float4*>(ln_b + g2 * 32 + i * 8);
      const float4 bb = *reinterpret_cast<const float4*>(ln_b + g2 * 32 + i * 8 + 4);
      float n0 = (v[i*8+0] - mu) * rstd * ga.x + ba.x;
      float n1 = (v[i*8+1] - mu) * rstd * ga.y + ba.y;
      float n2 = (v[i*8+2] - mu) * rstd * ga.z + ba.z;
      float n3 = (v[i*8+3] - mu) * rstd * ga.w + ba.w;
      float n4 = (v[i*8+4] - mu) * rstd * gb.x + bb.x;
      float n5 = (v[i*8+5] - mu) * rstd * gb.y + bb.y;
      float n6 = (v[i*8+6] - mu) * rstd * gb.z + bb.z;
      float n7 = (v[i*8+7] - mu) * rstd * gb.w + bb.w;
      uint4 o;
      o.x = pk2(n0, n1); o.y = pk2(n2, n3); o.z = pk2(n4, n5); o.w = pk2(n6, n7);
      *reinterpret_cast<uint4*>(orow + i * 8) = o;
    }
  }

  // ---- phase 3: QKV MFMA -> aQK (Q,K) and aV; xn B-frags hoisted (aQK overlays aXn) ----
  {
    Frag bfh[4];
    #pragma unroll
    for (int ks = 0; ks < 4; ks++)
      bfh[ks].u4 = *reinterpret_cast<const uint4*>(aXn + r16 * 136 + ks * 32 + q * 8);
    for (int chunk = 0; chunk < 4; chunk++) {
      f32x4 acc[6];
      #pragma unroll
      for (int i = 0; i < 6; i++) acc[i] = (f32x4){0.f, 0.f, 0.f, 0.f};
      #pragma unroll
      for (int ks = 0; ks < 4; ks++) {
        #pragma unroll
        for (int i = 0; i < 6; i++) {
          int mt = chunk * 6 + i;
          Frag af;
          af.u4 = *reinterpret_cast<const uint4*>(FWq + ((mt * 4 + ks) * 64 + l) * 8);
          acc[i] = __builtin_amdgcn_mfma_f32_16x16x32_bf16(af.s, bfh[ks].s, acc[i], 0, 0, 0);
        }
      }
      #pragma unroll
      for (int i = 0; i < 6; i++) {
        int mt = chunk * 6 + i;
        int oo = mt * 16 + q * 4;
        const float4 bv = *reinterpret_cast<const float4*>(bqkv + oo);
        float v0 = acc[i][0] + bv.x, v1 = acc[i][1] + bv.y;
        float v2 = acc[i][2] + bv.z, v3 = acc[i][3] + bv.w;
        if (mt < 16) {
          uint2 pk; pk.x = pk2(v0, v1); pk.y = pk2(v2, v3);
          *reinterpret_cast<uint2*>(aQK + r16 * 264 + oo) = pk;
        } else {
          ushort* vd = aV + (oo - 256) * 16 + r16;
          vd[0] = f2bf(v0); vd[16] = f2bf(v1); vd[32] = f2bf(v2); vd[48] = f2bf(v3);
        }
      }
    }
  }

  // ---- phase 4: scores + softmax -> aP (QK frags hoisted; aP overlays aQK base) ----
  {
    const float scale = 0.17677669529663687f;
    Frag af4[4], bf4[4];
    #pragma unroll
    for (int hd = 0; hd < 4; hd++) {
      af4[hd].u4 = *reinterpret_cast<const uint4*>(aQK + r16 * 264 + hd * 32 + q * 8);
      bf4[hd].u4 = *reinterpret_cast<const uint4*>(aQK + r16 * 264 + 128 + hd * 32 + q * 8);
    }
    // zero-pad cols 16..31 (after hoisted reads; program order protects aQK)
    #pragma unroll
    for (int hd = 0; hd < 4; hd++) {
      if (l < 32) {
        int row = l >> 1, hz = l & 1;
        uint4 z = {0u, 0u, 0u, 0u};
        *reinterpret_cast<uint4*>(aP + hd * 512 + row * 32 + 16 + hz * 8) = z;
      }
    }
    f32x4 sc[4];
    #pragma unroll
    for (int hd = 0; hd < 4; hd++) {
      f32x4 z4 = (f32x4){0.f, 0.f, 0.f, 0.f};
      sc[hd] = __builtin_amdgcn_mfma_f32_16x16x32_bf16(af4[hd].s, bf4[hd].s, z4, 0, 0, 0);
    }
    #pragma unroll
    for (int hd = 0; hd < 4; hd++) {
      ushort* pd = aP + hd * 512 + (q * 4) * 32 + r16;
      #pragma unroll
      for (int r = 0; r < 4; r++) {
        float sv = sc[hd][r] * scale;
        float mx = sv;
        mx = fmaxf(mx, __shfl_xor(mx, 1));
        mx = fmaxf(mx, __shfl_xor(mx, 2));
        mx = fmaxf(mx, __shfl_xor(mx, 4));
        mx = fmaxf(mx, __shfl_xor(mx, 8));
        float e = __expf(sv - mx);
        float sm = e;
        sm += __shfl_xor(sm, 1); sm += __shfl_xor(sm, 2);
        sm += __shfl_xor(sm, 4); sm += __shfl_xor(sm, 8);
        pd[r * 32] = f2bf(e / sm);
      }
    }
  }

  // ---- phase 5: PV MFMA -> aO [tok][chan] (aP/aO/aV regions disjoint) ----
  {
    #pragma unroll
    for (int hd = 0; hd < 4; hd++) {
      Frag pa;
      pa.u4 = *reinterpret_cast<const uint4*>(aP + hd * 512 + r16 * 32 + q * 8);
      #pragma unroll
      for (int nt = 0; nt < 2; nt++) {
        int ch = hd * 32 + nt * 16 + r16;
        int off = (q < 2) ? q * 8 : 0;   // q>=2 slots multiply zero P-cols
        Frag vf;
        vf.u4 = *reinterpret_cast<const uint4*>(aV + ch * 16 + off);
        f32x4 z4 = (f32x4){0.f, 0.f, 0.f, 0.f};
        f32x4 o4 = __builtin_amdgcn_mfma_f32_16x16x32_bf16(pa.s, vf.s, z4, 0, 0, 0);
        ushort* od = aO + (q * 4) * 136 + ch;
        od[0] = f2bf(o4[0]); od[136] = f2bf(o4[1]);
        od[272] = f2bf(o4[2]); od[408] = f2bf(o4[3]);
      }
    }
  }

  // ---- phase 6: Wo MFMA -> aFin [chan][tok] (aFin overlays aV, dead after ph5) ----
  {
    Frag a4[4];
    #pragma unroll
    for (int ks = 0; ks < 4; ks++)
      a4[ks].u4 = *reinterpret_cast<const uint4*>(aO + r16 * 136 + ks * 32 + q * 8);
    #pragma unroll
    for (int ntg = 0; ntg < 8; ntg++) {
      f32x4 acc = (f32x4){0.f, 0.f, 0.f, 0.f};
      #pragma unroll
      for (int ks = 0; ks < 4; ks++) {
        Frag bf;
        bf.u4 = *reinterpret_cast<const uint4*>(FWoT + ((ntg * 4 + ks) * 64 + l) * 8);
        acc = __builtin_amdgcn_mfma_f32_16x16x32_bf16(a4[ks].s, bf.s, acc, 0, 0, 0);
      }
      int ch = ntg * 16 + r16;
      float bb = bo[ch];
      uint2 pk;
      pk.x = pk2(acc[0] + bb, acc[1] + bb);
      pk.y = pk2(acc[2] + bb, acc[3] + bb);
      *reinterpret_cast<uint2*>(aFin + ch * 16 + q * 4) = pk;
    }
  }
  __syncthreads();   // B3: cross-wave aFin reads below

  // ---- phase 7: coalesced writeout (2 windows per 16B) + GN partial stats ----
  {
    #pragma unroll
    for (int it = 0; it < 4; it++) {
      int seg = it * 256 + t;            // [0,1024)
      int ch = seg >> 3, r = (seg >> 1) & 3, half = seg & 1;
      const ushort* f0 = (const ushort*)(LM + (half * 2    ) * ARN + 8448);
      const ushort* f1 = (const ushort*)(LM + (half * 2 + 1) * ARN + 8448);
      uint2 a  = *reinterpret_cast<const uint2*>(f0 + ch * 16 + r * 4);
      uint2 c2 = *reinterpret_cast<const uint2*>(f1 + ch * 16 + r * 4);
      uint4 val = {a.x, a.y, c2.x, c2.y};
      *reinterpret_cast<uint4*>(attn_map + (size_t)(b * 128 + ch) * PIX
                                + (wh * 4 + r) * 128 + ww0 * 16 + half * 8) = val;
      float sv = 0.f, sv2 = 0.f;
      uint uu[4] = {val.x, val.y, val.z, val.w};
      #pragma unroll
      for (int k2 = 0; k2 < 4; k2++) {
        float fv0 = bf2f((ushort)(uu[k2] & 0xFFFFu));
        float fv1 = bf2f((ushort)(uu[k2] >> 16));
        sv += fv0 + fv1; sv2 += fv0 * fv0 + fv1 * fv1;
      }
      sv  += __shfl_xor(sv, 1);  sv  += __shfl_xor(sv, 2);  sv  += __shfl_xor(sv, 4);
      sv2 += __shfl_xor(sv2, 1); sv2 += __shfl_xor(sv2, 2); sv2 += __shfl_xor(sv2, 4);
      if ((t & 7) == 0) {
        int g = ch >> 4;
        atomicAdd(&sStat[g * 2], sv);
        atomicAdd(&sStat[g * 2 + 1], sv2);
      }
    }
  }
  __syncthreads();
  if (t < 16) atomicAdd(&stA_raw[b * 16 + t], sStat[t]);
}

// ---------------- stats finalize ----------------
__global__ void k_stats_fin(const float* __restrict__ raw, float* __restrict__ fin) {
  int i = threadIdx.x;
  if (i < 64) {
    const float invN = 1.f / 262144.f;
    float mu = raw[i * 2] * invN;
    float var = raw[i * 2 + 1] * invN - mu * mu;
    fin[i * 2] = mu;
    fin[i * 2 + 1] = rsqrtf(var + EPSF);
  }
}

// ---------------- GN + gates MFMA + LSTM update (+stats for GN2) ----------------
__global__ __launch_bounds__(256) void k_gates(
    const ushort* __restrict__ attn_map, const float* __restrict__ statsA,
    const float* __restrict__ gn_g, const float* __restrict__ gn_b,
    const ushort* __restrict__ FWg, const float* __restrict__ bgates,
    const float* __restrict__ c, float* __restrict__ cnext,
    ushort* __restrict__ tbuf, float* __restrict__ stB_raw)
{
  __shared__ uint sG[64 * 65];
  __shared__ float sA[128], sB[128];
  __shared__ float sStat[16];
  const int t = threadIdx.x, bid = blockIdx.x;
  const int b = bid >> 8, p0 = (bid & 255) * 64;
  const int w = t >> 6, l = t & 63, q = l >> 4, r16 = l & 15;
  if (t < 128) {
    int g = t >> 4;
    float mu = statsA[(b * 8 + g) * 2], rs = statsA[(b * 8 + g) * 2 + 1];
    float A = rs * gn_g[t];
    sA[t] = A; sB[t] = gn_b[t] - mu * A;
  }
  if (t >= 240) sStat[t - 240] = 0.f;
  __syncthreads();

  const size_t abase = (size_t)b * 128 * PIX + p0;
  #pragma unroll
  for (int it = 0; it < 16; it++) {
    int idx = it * 256 + t;
    int pr = idx >> 6, p = idx & 63;
    int c0 = pr * 2;
    float v0 = bf2f(attn_map[abase + (size_t)c0 * PIX + p]) * sA[c0] + sB[c0];
    float v1 = bf2f(attn_map[abase + (size_t)(c0 + 1) * PIX + p]) * sA[c0 + 1] + sB[c0 + 1];
    sG[pr * 65 + p] = pk2(v0, v1);
  }
  __syncthreads();

  f32x4 acc[8][4];
  #pragma unroll
  for (int mi = 0; mi < 8; mi++)
    #pragma unroll
    for (int nt = 0; nt < 4; nt++) acc[mi][nt] = (f32x4){0.f, 0.f, 0.f, 0.f};

  for (int ks = 0; ks < 4; ks++) {
    Frag bf[4];
    #pragma unroll
    for (int nt = 0; nt < 4; nt++)
      #pragma unroll
      for (int s = 0; s < 4; s++)
        bf[nt].u[s] = sG[(ks * 16 + q * 4 + s) * 65 + nt * 16 + r16];
    #pragma unroll
    for (int mi = 0; mi < 8; mi++) {
      int mt = w + mi * 4;
      Frag af;
      af.u4 = *reinterpret_cast<const uint4*>(FWg + ((mt * 4 + ks) * 64 + l) * 8);
      #pragma unroll
      for (int nt = 0; nt < 4; nt++)
        acc[mi][nt] = __builtin_amdgcn_mfma_f32_16x16x32_bf16(af.s, bf[nt].s, acc[mi][nt], 0, 0, 0);
    }
  }

  float gs[2] = {0.f, 0.f}, gs2[2] = {0.f, 0.f};
  #pragma unroll
  for (int mi2 = 0; mi2 < 2; mi2++) {
    int ch0 = (w + mi2 * 4) * 16 + q * 4;
    const float4 bi = *reinterpret_cast<const float4*>(bgates + ch0);
    const float4 bfg = *reinterpret_cast<const float4*>(bgates + 128 + ch0);
    const float4 bog = *reinterpret_cast<const float4*>(bgates + 256 + ch0);
    const float4 bgg = *reinterpret_cast<const float4*>(bgates + 384 + ch0);
    const float bis[4] = {bi.x, bi.y, bi.z, bi.w};
    const float bfs[4] = {bfg.x, bfg.y, bfg.z, bfg.w};
    const float bos[4] = {bog.x, bog.y, bog.z, bog.w};
    const float bgs[4] = {bgg.x, bgg.y, bgg.z, bgg.w};
    #pragma unroll
    for (int nt = 0; nt < 4; nt++) {
      int px = p0 + nt * 16 + r16;
      #pragma unroll
      for (int r = 0; r < 4; r++) {
        int ch = ch0 + r;
        float ig = fsigmoid(acc[mi2    ][nt][r] + bis[r]);
        float fg = fsigmoid(acc[mi2 + 2][nt][r] + bfs[r]);
        float og = fsigmoid(acc[mi2 + 4][nt][r] + bos[r]);
        float gg = ftanh   (acc[mi2 + 6][nt][r] + bgs[r]);
        size_t gidx = (size_t)(b * 128 + ch) * PIX + px;
        float cv = c[gidx];
        float cn = fg * cv + ig * gg;
        cnext[gidx] = cn;
        float tv = og * ftanh(cn);
        tbuf[gidx] = f2bf(tv);
        gs[mi2] += tv; gs2[mi2] += tv * tv;
      }
    }
  }
  #pragma unroll
  for (int mi2 = 0; mi2 < 2; mi2++) {
    float s = gs[mi2], s2 = gs2[mi2];
    s += __shfl_xor(s, 1); s += __shfl_xor(s, 2); s += __shfl_xor(s, 4);
    s += __shfl_xor(s, 8); s += __shfl_xor(s, 16); s += __shfl_xor(s, 32);
    s2 += __shfl_xor(s2, 1); s2 += __shfl_xor(s2, 2); s2 += __shfl_xor(s2, 4);
    s2 += __shfl_xor(s2, 8); s2 += __shfl_xor(s2, 16); s2 += __shfl_xor(s2, 32);
    if (l == 0) {
      int g = w + mi2 * 4;
      atomicAdd(&sStat[g * 2], s);
      atomicAdd(&sStat[g * 2 + 1], s2);
    }
  }
  __syncthreads();
  if (t < 16) atomicAdd(&stB_raw[b * 16 + t], sStat[t]);
}

// ---------------- hnext = GN2(tbuf) ----------------
__global__ __launch_bounds__(256) void k_gnout(
    const ushort* __restrict__ tbuf, const float* __restrict__ statsB,
    const float* __restrict__ gn_g, const float* __restrict__ gn_b,
    float* __restrict__ hnext)
{
  size_t idx = ((size_t)blockIdx.x * 256 + threadIdx.x) * 8;
  if (idx >= (size_t)16777216) return;
  int chrow = (int)(idx >> 14);
  int b = chrow >> 7, ch = chrow & 127, g = ch >> 4;
  float mu = statsB[(b * 8 + g) * 2], rstd = statsB[(b * 8 + g) * 2 + 1];
  float A = gn_g[ch] * rstd, Bv = gn_b[ch] - mu * A;
  uint4 u = *reinterpret_cast<const uint4*>(tbuf + idx);
  float4 o0, o1;
  o0.x = bf2f((ushort)(u.x & 0xFFFFu)) * A + Bv;
  o0.y = bf2f((ushort)(u.x >> 16)) * A + Bv;
  o0.z = bf2f((ushort)(u.y & 0xFFFFu)) * A + Bv;
  o0.w = bf2f((ushort)(u.y >> 16)) * A + Bv;
  o1.x = bf2f((ushort)(u.z & 0xFFFFu)) * A + Bv;
  o1.y = bf2f((ushort)(u.z >> 16)) * A + Bv;
  o1.z = bf2f((ushort)(u.w & 0xFFFFu)) * A + Bv;
  o1.w = bf2f((ushort)(u.w >> 16)) * A + Bv;
  *reinterpret_cast<float4*>(hnext + idx) = o0;
  *reinterpret_cast<float4*>(hnext + idx + 4) = o1;
}

extern "C" void kernel_launch(void* const* d_in, const int* in_sizes, int n_in,
                              void* d_out, int out_size, void* d_ws, size_t ws_size,
                              hipStream_t stream) {
  (void)in_sizes; (void)n_in; (void)out_size; (void)ws_size;
  const float* x      = (const float*)d_in[0];
  const float* h      = (const float*)d_in[1];
  const float* c      = (const float*)d_in[2];
  const float* Wproj  = (const float*)d_in[3];
  const float* bproj  = (const float*)d_in[4];
  const float* ln_g   = (const float*)d_in[5];
  const float* ln_b   = (const float*)d_in[6];
  const float* Wqkv   = (const float*)d_in[7];
  const float* bqkv   = (const float*)d_in[8];
  const float* Wo     = (const float*)d_in[9];
  const float* bo     = (const float*)d_in[10];
  const float* Wgates = (const float*)d_in[11];
  const float* bgates = (const float*)d_in[12];
  const float* gn_g   = (const float*)d_in[13];
  const float* gn_b   = (const float*)d_in[14];

  float* out = (float*)d_out;
  float* hnext = out;
  float* cnext = out + 16777216;

  char* W = (char*)d_ws;
  ushort* attn = (ushort*)W;                          // 32 MB bf16
  ushort* tbuf = (ushort*)(W + 33554432);             // 32 MB bf16
  size_t off = 67108864;
  ushort* FWp = (ushort*)(W + off); off += 49152;     // 8*6*64*16B
  ushort* FWq = (ushort*)(W + off); off += 98304;     // 24*4*64*16B
  ushort* FWo = (ushort*)(W + off); off += 32768;     // 8*4*64*16B
  ushort* FWg = (ushort*)(W + off); off += 131072;    // 32*4*64*16B
  float* stA_raw = (float*)(W + off); off += 512;
  float* stB_raw = (float*)(W + off); off += 512;
  float* stA     = (float*)(W + off); off += 512;
  float* stB     = (float*)(W + off); off += 512;

  hipMemsetAsync(stA_raw, 0, 1024, stream);

  k_prep<<<76, 256, 0, stream>>>(Wproj, Wqkv, Wo, Wgates, FWp, FWq, FWo, FWg);

  k_attn<<<2048, 256, 0, stream>>>(x, h, FWp, bproj, ln_g, ln_b,
                                   FWq, bqkv, FWo, bo, attn, stA_raw);
  k_stats_fin<<<1, 64, 0, stream>>>(stA_raw, stA);
  k_gates<<<2048, 256, 0, stream>>>(attn, stA, gn_g, gn_b, FWg, bgates,
                                    c, cnext, tbuf, stB_raw);
  k_stats_fin<<<1, 64, 0, stream>>>(stB_raw, stB);
  k_gnout<<<8192, 256, 0, stream>>>(tbuf, stB, gn_g, gn_b, hnext);
}

// Round 6
// 240.431 us; speedup vs baseline: 3.5748x; 1.0627x over previous
//
#include <hip/hip_runtime.h>
#include <math.h>

typedef unsigned int uint;
typedef unsigned short ushort;
typedef short s16x8 __attribute__((ext_vector_type(8)));
typedef float f32x4 __attribute__((ext_vector_type(4)));

#define PIX 16384
#define EPSF 1e-5f

__device__ __forceinline__ ushort f2bf(float f) {
  union { float f; uint u; } v; v.f = f;
  uint u = v.u;
  uint r = (u + 0x7FFFu + ((u >> 16) & 1u)) >> 16;
  return (ushort)r;
}
__device__ __forceinline__ float bf2f(ushort h) {
  union { uint u; float f; } v; v.u = ((uint)h) << 16;
  return v.f;
}
__device__ __forceinline__ uint pk2(float a, float b) {
  return (uint)f2bf(a) | ((uint)f2bf(b) << 16);
}
__device__ __forceinline__ float fsigmoid(float v) { return 1.f / (1.f + __expf(-v)); }
__device__ __forceinline__ float ftanh(float v) { return 1.f - 2.f / (__expf(2.f * v) + 1.f); }

union Frag { uint4 u4; uint u[4]; s16x8 s; };

// ---------------- merged weight fragment prep ----------------
// frag (mt, ks): lane l elem j = W[mt*16 + (l&15)][ks*32 + (l>>4)*8 + j]
__global__ void k_prep(const float* __restrict__ Wp, const float* __restrict__ Wq,
                       const float* __restrict__ Wo, const float* __restrict__ Wg,
                       ushort* __restrict__ FWp, ushort* __restrict__ FWq,
                       ushort* __restrict__ FWo, ushort* __restrict__ FWg) {
  int idx = blockIdx.x * 256 + threadIdx.x;   // [0, 19456)
  const float* W; ushort* F; int KS, ldw, rel;
  if (idx < 3072)       { W = Wp; F = FWp; KS = 6; ldw = 192; rel = idx; }
  else if (idx < 9216)  { W = Wq; F = FWq; KS = 4; ldw = 128; rel = idx - 3072; }
  else if (idx < 11264) { W = Wo; F = FWo; KS = 4; ldw = 128; rel = idx - 9216; }
  else                  { W = Wg; F = FWg; KS = 4; ldw = 128; rel = idx - 11264; }
  int l = rel & 63, rest = rel >> 6;
  int ks = rest % KS, mt = rest / KS;
  const float* src = W + (size_t)(mt * 16 + (l & 15)) * ldw + ks * 32 + (l >> 4) * 8;
  uint4 v;
  v.x = pk2(src[0], src[1]);
  v.y = pk2(src[2], src[3]);
  v.z = pk2(src[4], src[5]);
  v.w = pk2(src[6], src[7]);
  *reinterpret_cast<uint4*>(F + (size_t)rel * 8) = v;
}

// ---------------- fused proj + LN + window MHSA + Wo (+GN stats) ----------------
// (unchanged from round 5 — validated)
#define ARN 12544
__global__ __launch_bounds__(256, 3) void k_attn(
    const float* __restrict__ x, const float* __restrict__ h,
    const ushort* __restrict__ FWp, const float* __restrict__ bproj,
    const float* __restrict__ ln_g, const float* __restrict__ ln_b,
    const ushort* __restrict__ FWq, const float* __restrict__ bqkv,
    const ushort* __restrict__ FWoT, const float* __restrict__ bo,
    ushort* __restrict__ attn_map, float* __restrict__ stA_raw)
{
  __shared__ __align__(16) char LM[4 * ARN];
  __shared__ float sStat[16];

  const int t = threadIdx.x;
  const int bid = blockIdx.x;
  const int b = bid >> 8, wh = (bid >> 3) & 31, ww0 = bid & 7;
  const int w = t >> 6, l = t & 63, q = l >> 4, r16 = l & 15;

  uint* sInP = (uint*)LM;                       // [96][68] dwords, ph0-1
  char* AR = LM + w * ARN;
  ushort* aXn  = (ushort*)AR;
  ushort* aQK  = (ushort*)AR;
  ushort* aP   = (ushort*)AR;
  ushort* aO   = (ushort*)(AR + 4096);
  ushort* aV   = (ushort*)(AR + 8448);
  ushort* aFin = (ushort*)(AR + 8448);

  if (t < 16) sStat[t] = 0.f;

  // ---- phase 0: vectorized staging concat(x,h) -> sInP[chp][col] ----
  {
    const float* xb = x + (size_t)b * 64 * PIX;
    const float* hb = h + (size_t)b * 128 * PIX;
    #pragma unroll
    for (int it = 0; it < 6; it++) {
      int item = it * 256 + t;                 // [0,1536)
      int wv = item & 3, r = (item >> 2) & 3, chp = item >> 4;   // chp in [0,96)
      int ch0 = chp * 2;
      int gpix = (wh * 4 + r) * 128 + ww0 * 16 + wv * 4;
      float4 a, c2;
      if (ch0 < 64) {
        a  = *reinterpret_cast<const float4*>(xb + (size_t)ch0 * PIX + gpix);
        c2 = *reinterpret_cast<const float4*>(xb + (size_t)(ch0 + 1) * PIX + gpix);
      } else {
        a  = *reinterpret_cast<const float4*>(hb + (size_t)(ch0 - 64) * PIX + gpix);
        c2 = *reinterpret_cast<const float4*>(hb + (size_t)(ch0 - 63) * PIX + gpix);
      }
      uint4 pkd;
      pkd.x = pk2(a.x, c2.x); pkd.y = pk2(a.y, c2.y);
      pkd.z = pk2(a.z, c2.z); pkd.w = pk2(a.w, c2.w);
      *reinterpret_cast<uint4*>(sInP + chp * 68 + wv * 16 + r * 4) = pkd;
    }
  }
  __syncthreads();   // B1: staging complete

  // ---- phase 1: proj MFMA ----
  f32x4 acc1[8];
  {
    int p = w * 16 + r16;
    #pragma unroll
    for (int m = 0; m < 8; m++) acc1[m] = (f32x4){0.f, 0.f, 0.f, 0.f};
    for (int ks = 0; ks < 6; ks++) {
      Frag bf;
      #pragma unroll
      for (int s = 0; s < 4; s++)
        bf.u[s] = sInP[(ks * 16 + q * 4 + s) * 68 + p];
      #pragma unroll
      for (int m = 0; m < 8; m++) {
        Frag af;
        af.u4 = *reinterpret_cast<const uint4*>(FWp + ((m * 6 + ks) * 64 + l) * 8);
        acc1[m] = __builtin_amdgcn_mfma_f32_16x16x32_bf16(af.s, bf.s, acc1[m], 0, 0, 0);
      }
    }
  }
  __syncthreads();   // B2: arenas may overlay staging

  // ---- phase 1b: bias + pack -> aXn ----
  {
    #pragma unroll
    for (int m = 0; m < 8; m++) {
      int o0 = m * 16 + q * 4;
      const float4 bv = *reinterpret_cast<const float4*>(bproj + o0);
      uint2 pk;
      pk.x = pk2(acc1[m][0] + bv.x, acc1[m][1] + bv.y);
      pk.y = pk2(acc1[m][2] + bv.z, acc1[m][3] + bv.w);
      *reinterpret_cast<uint2*>(aXn + r16 * 136 + o0) = pk;
    }
  }

  // ---- phase 2: LayerNorm in place ----
  {
    int tok = (t >> 2) & 15, g2 = t & 3;
    const ushort* row = aXn + tok * 136 + g2 * 32;
    float v[32];
    #pragma unroll
    for (int i = 0; i < 4; i++) {
      uint4 u = *reinterpret_cast<const uint4*>(row + i * 8);
      v[i*8+0] = bf2f((ushort)(u.x & 0xFFFFu)); v[i*8+1] = bf2f((ushort)(u.x >> 16));
      v[i*8+2] = bf2f((ushort)(u.y & 0xFFFFu)); v[i*8+3] = bf2f((ushort)(u.y >> 16));
      v[i*8+4] = bf2f((ushort)(u.z & 0xFFFFu)); v[i*8+5] = bf2f((ushort)(u.z >> 16));
      v[i*8+6] = bf2f((ushort)(u.w & 0xFFFFu)); v[i*8+7] = bf2f((ushort)(u.w >> 16));
    }
    float s = 0.f, s2 = 0.f;
    #pragma unroll
    for (int i = 0; i < 32; i++) { s += v[i]; s2 += v[i] * v[i]; }
    s  += __shfl_xor(s, 1);  s  += __shfl_xor(s, 2);
    s2 += __shfl_xor(s2, 1); s2 += __shfl_xor(s2, 2);
    float mu = s * 0.0078125f;
    float var = s2 * 0.0078125f - mu * mu;
    float rstd = rsqrtf(var + EPSF);
    ushort* orow = aXn + tok * 136 + g2 * 32;
    #pragma unroll
    for (int i = 0; i < 4; i++) {
      const float4 ga = *reinterpret_cast<const float4*>(ln_g + g2 * 32 + i * 8);
      const float4 gb = *reinterpret_cast<const float4*>(ln_g + g2 * 32 + i * 8 + 4);
      const float4 ba = *reinterpret_cast<const float4*>(ln_b + g2 * 32 + i * 8);
      const float4 bb = *reinterpret_cast<const float4*>(ln_b + g2 * 32 + i * 8 + 4);
      float n0 = (v[i*8+0] - mu) * rstd * ga.x + ba.x;
      float n1 = (v[i*8+1] - mu) * rstd * ga.y + ba.y;
      float n2 = (v[i*8+2] - mu) * rstd * ga.z + ba.z;
      float n3 = (v[i*8+3] - mu) * rstd * ga.w + ba.w;
      float n4 = (v[i*8+4] - mu) * rstd * gb.x + bb.x;
      float n5 = (v[i*8+5] - mu) * rstd * gb.y + bb.y;
      float n6 = (v[i*8+6] - mu) * rstd * gb.z + bb.z;
      float n7 = (v[i*8+7] - mu) * rstd * gb.w + bb.w;
      uint4 o;
      o.x = pk2(n0, n1); o.y = pk2(n2, n3); o.z = pk2(n4, n5); o.w = pk2(n6, n7);
      *reinterpret_cast<uint4*>(orow + i * 8) = o;
    }
  }

  // ---- phase 3: QKV MFMA -> aQK, aV ----
  {
    Frag bfh[4];
    #pragma unroll
    for (int ks = 0; ks < 4; ks++)
      bfh[ks].u4 = *reinterpret_cast<const uint4*>(aXn + r16 * 136 + ks * 32 + q * 8);
    for (int chunk = 0; chunk < 4; chunk++) {
      f32x4 acc[6];
      #pragma unroll
      for (int i = 0; i < 6; i++) acc[i] = (f32x4){0.f, 0.f, 0.f, 0.f};
      #pragma unroll
      for (int ks = 0; ks < 4; ks++) {
        #pragma unroll
        for (int i = 0; i < 6; i++) {
          int mt = chunk * 6 + i;
          Frag af;
          af.u4 = *reinterpret_cast<const uint4*>(FWq + ((mt * 4 + ks) * 64 + l) * 8);
          acc[i] = __builtin_amdgcn_mfma_f32_16x16x32_bf16(af.s, bfh[ks].s, acc[i], 0, 0, 0);
        }
      }
      #pragma unroll
      for (int i = 0; i < 6; i++) {
        int mt = chunk * 6 + i;
        int oo = mt * 16 + q * 4;
        const float4 bv = *reinterpret_cast<const float4*>(bqkv + oo);
        float v0 = acc[i][0] + bv.x, v1 = acc[i][1] + bv.y;
        float v2 = acc[i][2] + bv.z, v3 = acc[i][3] + bv.w;
        if (mt < 16) {
          uint2 pk; pk.x = pk2(v0, v1); pk.y = pk2(v2, v3);
          *reinterpret_cast<uint2*>(aQK + r16 * 264 + oo) = pk;
        } else {
          ushort* vd = aV + (oo - 256) * 16 + r16;
          vd[0] = f2bf(v0); vd[16] = f2bf(v1); vd[32] = f2bf(v2); vd[48] = f2bf(v3);
        }
      }
    }
  }

  // ---- phase 4: scores + softmax -> aP ----
  {
    const float scale = 0.17677669529663687f;
    Frag af4[4], bf4[4];
    #pragma unroll
    for (int hd = 0; hd < 4; hd++) {
      af4[hd].u4 = *reinterpret_cast<const uint4*>(aQK + r16 * 264 + hd * 32 + q * 8);
      bf4[hd].u4 = *reinterpret_cast<const uint4*>(aQK + r16 * 264 + 128 + hd * 32 + q * 8);
    }
    #pragma unroll
    for (int hd = 0; hd < 4; hd++) {
      if (l < 32) {
        int row = l >> 1, hz = l & 1;
        uint4 z = {0u, 0u, 0u, 0u};
        *reinterpret_cast<uint4*>(aP + hd * 512 + row * 32 + 16 + hz * 8) = z;
      }
    }
    f32x4 sc[4];
    #pragma unroll
    for (int hd = 0; hd < 4; hd++) {
      f32x4 z4 = (f32x4){0.f, 0.f, 0.f, 0.f};
      sc[hd] = __builtin_amdgcn_mfma_f32_16x16x32_bf16(af4[hd].s, bf4[hd].s, z4, 0, 0, 0);
    }
    #pragma unroll
    for (int hd = 0; hd < 4; hd++) {
      ushort* pd = aP + hd * 512 + (q * 4) * 32 + r16;
      #pragma unroll
      for (int r = 0; r < 4; r++) {
        float sv = sc[hd][r] * scale;
        float mx = sv;
        mx = fmaxf(mx, __shfl_xor(mx, 1));
        mx = fmaxf(mx, __shfl_xor(mx, 2));
        mx = fmaxf(mx, __shfl_xor(mx, 4));
        mx = fmaxf(mx, __shfl_xor(mx, 8));
        float e = __expf(sv - mx);
        float sm = e;
        sm += __shfl_xor(sm, 1); sm += __shfl_xor(sm, 2);
        sm += __shfl_xor(sm, 4); sm += __shfl_xor(sm, 8);
        pd[r * 32] = f2bf(e / sm);
      }
    }
  }

  // ---- phase 5: PV MFMA -> aO ----
  {
    #pragma unroll
    for (int hd = 0; hd < 4; hd++) {
      Frag pa;
      pa.u4 = *reinterpret_cast<const uint4*>(aP + hd * 512 + r16 * 32 + q * 8);
      #pragma unroll
      for (int nt = 0; nt < 2; nt++) {
        int ch = hd * 32 + nt * 16 + r16;
        int off = (q < 2) ? q * 8 : 0;
        Frag vf;
        vf.u4 = *reinterpret_cast<const uint4*>(aV + ch * 16 + off);
        f32x4 z4 = (f32x4){0.f, 0.f, 0.f, 0.f};
        f32x4 o4 = __builtin_amdgcn_mfma_f32_16x16x32_bf16(pa.s, vf.s, z4, 0, 0, 0);
        ushort* od = aO + (q * 4) * 136 + ch;
        od[0] = f2bf(o4[0]); od[136] = f2bf(o4[1]);
        od[272] = f2bf(o4[2]); od[408] = f2bf(o4[3]);
      }
    }
  }

  // ---- phase 6: Wo MFMA -> aFin ----
  {
    Frag a4[4];
    #pragma unroll
    for (int ks = 0; ks < 4; ks++)
      a4[ks].u4 = *reinterpret_cast<const uint4*>(aO + r16 * 136 + ks * 32 + q * 8);
    #pragma unroll
    for (int ntg = 0; ntg < 8; ntg++) {
      f32x4 acc = (f32x4){0.f, 0.f, 0.f, 0.f};
      #pragma unroll
      for (int ks = 0; ks < 4; ks++) {
        Frag bf;
        bf.u4 = *reinterpret_cast<const uint4*>(FWoT + ((ntg * 4 + ks) * 64 + l) * 8);
        acc = __builtin_amdgcn_mfma_f32_16x16x32_bf16(a4[ks].s, bf.s, acc, 0, 0, 0);
      }
      int ch = ntg * 16 + r16;
      float bb = bo[ch];
      uint2 pk;
      pk.x = pk2(acc[0] + bb, acc[1] + bb);
      pk.y = pk2(acc[2] + bb, acc[3] + bb);
      *reinterpret_cast<uint2*>(aFin + ch * 16 + q * 4) = pk;
    }
  }
  __syncthreads();   // B3

  // ---- phase 7: coalesced writeout + GN partial stats ----
  {
    #pragma unroll
    for (int it = 0; it < 4; it++) {
      int seg = it * 256 + t;
      int ch = seg >> 3, r = (seg >> 1) & 3, half = seg & 1;
      const ushort* f0 = (const ushort*)(LM + (half * 2    ) * ARN + 8448);
      const ushort* f1 = (const ushort*)(LM + (half * 2 + 1) * ARN + 8448);
      uint2 a  = *reinterpret_cast<const uint2*>(f0 + ch * 16 + r * 4);
      uint2 c2 = *reinterpret_cast<const uint2*>(f1 + ch * 16 + r * 4);
      uint4 val = {a.x, a.y, c2.x, c2.y};
      *reinterpret_cast<uint4*>(attn_map + (size_t)(b * 128 + ch) * PIX
                                + (wh * 4 + r) * 128 + ww0 * 16 + half * 8) = val;
      float sv = 0.f, sv2 = 0.f;
      uint uu[4] = {val.x, val.y, val.z, val.w};
      #pragma unroll
      for (int k2 = 0; k2 < 4; k2++) {
        float fv0 = bf2f((ushort)(uu[k2] & 0xFFFFu));
        float fv1 = bf2f((ushort)(uu[k2] >> 16));
        sv += fv0 + fv1; sv2 += fv0 * fv0 + fv1 * fv1;
      }
      sv  += __shfl_xor(sv, 1);  sv  += __shfl_xor(sv, 2);  sv  += __shfl_xor(sv, 4);
      sv2 += __shfl_xor(sv2, 1); sv2 += __shfl_xor(sv2, 2); sv2 += __shfl_xor(sv2, 4);
      if ((t & 7) == 0) {
        int g = ch >> 4;
        atomicAdd(&sStat[g * 2], sv);
        atomicAdd(&sStat[g * 2 + 1], sv2);
      }
    }
  }
  __syncthreads();
  if (t < 16) atomicAdd(&stA_raw[b * 16 + t], sStat[t]);
}

// ---------------- GN + gates MFMA + LSTM update (+stats for GN2) ----------------
// v2: 32-px tiles, grid 4096, acc[8][2], vectorized staging, inline stats finalize.
__global__ __launch_bounds__(256, 4) void k_gates(
    const ushort* __restrict__ attn_map, const float* __restrict__ stA_raw,
    const float* __restrict__ gn_g, const float* __restrict__ gn_b,
    const ushort* __restrict__ FWg, const float* __restrict__ bgates,
    const float* __restrict__ c, float* __restrict__ cnext,
    ushort* __restrict__ tbuf, float* __restrict__ stB_raw)
{
  __shared__ uint sG[64 * 34];      // [pair-row][32 px + 2 pad] dwords
  __shared__ float sA[128], sB[128];
  __shared__ float sStat[16];
  const int t = threadIdx.x, bid = blockIdx.x;
  const int b = bid >> 9, p0 = (bid & 511) * 32;
  const int w = t >> 6, l = t & 63, q = l >> 4, r16 = l & 15;
  if (t < 128) {
    int g = t >> 4;
    const float invN = 1.f / 262144.f;
    float mu = stA_raw[b * 16 + g * 2] * invN;
    float var = stA_raw[b * 16 + g * 2 + 1] * invN - mu * mu;
    float rs = rsqrtf(var + EPSF);
    float A = rs * gn_g[t];
    sA[t] = A; sB[t] = gn_b[t] - mu * A;
  }
  if (t >= 240) sStat[t - 240] = 0.f;
  __syncthreads();

  // ---- vectorized staging: GN(attn) -> sG pairs ----
  {
    int pr = t >> 2, px0 = (t & 3) * 8;
    int c0 = pr * 2;
    const ushort* ab = attn_map + (size_t)(b * 128) * PIX + p0 + px0;
    uint4 a0 = *reinterpret_cast<const uint4*>(ab + (size_t)c0 * PIX);
    uint4 a1 = *reinterpret_cast<const uint4*>(ab + (size_t)(c0 + 1) * PIX);
    float A0 = sA[c0], B0 = sB[c0], A1 = sA[c0 + 1], B1 = sB[c0 + 1];
    uint u0[4] = {a0.x, a0.y, a0.z, a0.w};
    uint u1[4] = {a1.x, a1.y, a1.z, a1.w};
    uint d[8];
    #pragma unroll
    for (int j = 0; j < 4; j++) {
      float v0a = bf2f((ushort)(u0[j] & 0xFFFFu)) * A0 + B0;
      float v0b = bf2f((ushort)(u0[j] >> 16)) * A0 + B0;
      float v1a = bf2f((ushort)(u1[j] & 0xFFFFu)) * A1 + B1;
      float v1b = bf2f((ushort)(u1[j] >> 16)) * A1 + B1;
      d[j * 2]     = pk2(v0a, v1a);
      d[j * 2 + 1] = pk2(v0b, v1b);
    }
    uint4 w0 = {d[0], d[1], d[2], d[3]};
    uint4 w1 = {d[4], d[5], d[6], d[7]};
    *reinterpret_cast<uint4*>(&sG[pr * 34 + px0]) = w0;
    *reinterpret_cast<uint4*>(&sG[pr * 34 + px0 + 4]) = w1;
  }
  __syncthreads();

  f32x4 acc[8][2];
  #pragma unroll
  for (int mi = 0; mi < 8; mi++)
    #pragma unroll
    for (int nt = 0; nt < 2; nt++) acc[mi][nt] = (f32x4){0.f, 0.f, 0.f, 0.f};

  for (int ks = 0; ks < 4; ks++) {
    Frag bf[2];
    #pragma unroll
    for (int nt = 0; nt < 2; nt++)
      #pragma unroll
      for (int s = 0; s < 4; s++)
        bf[nt].u[s] = sG[(ks * 16 + q * 4 + s) * 34 + nt * 16 + r16];
    #pragma unroll
    for (int mi = 0; mi < 8; mi++) {
      int mt = w + mi * 4;
      Frag af;
      af.u4 = *reinterpret_cast<const uint4*>(FWg + ((mt * 4 + ks) * 64 + l) * 8);
      #pragma unroll
      for (int nt = 0; nt < 2; nt++)
        acc[mi][nt] = __builtin_amdgcn_mfma_f32_16x16x32_bf16(af.s, bf[nt].s, acc[mi][nt], 0, 0, 0);
    }
  }

  float gs[2] = {0.f, 0.f}, gs2[2] = {0.f, 0.f};
  #pragma unroll
  for (int mi2 = 0; mi2 < 2; mi2++) {
    int ch0 = (w + mi2 * 4) * 16 + q * 4;
    const float4 bi = *reinterpret_cast<const float4*>(bgates + ch0);
    const float4 bfg = *reinterpret_cast<const float4*>(bgates + 128 + ch0);
    const float4 bog = *reinterpret_cast<const float4*>(bgates + 256 + ch0);
    const float4 bgg = *reinterpret_cast<const float4*>(bgates + 384 + ch0);
    const float bis[4] = {bi.x, bi.y, bi.z, bi.w};
    const float bfs[4] = {bfg.x, bfg.y, bfg.z, bfg.w};
    const float bos[4] = {bog.x, bog.y, bog.z, bog.w};
    const float bgs[4] = {bgg.x, bgg.y, bgg.z, bgg.w};
    #pragma unroll
    for (int nt = 0; nt < 2; nt++) {
      int px = p0 + nt * 16 + r16;
      #pragma unroll
      for (int r = 0; r < 4; r++) {
        int ch = ch0 + r;
        float ig = fsigmoid(acc[mi2    ][nt][r] + bis[r]);
        float fg = fsigmoid(acc[mi2 + 2][nt][r] + bfs[r]);
        float og = fsigmoid(acc[mi2 + 4][nt][r] + bos[r]);
        float gg = ftanh   (acc[mi2 + 6][nt][r] + bgs[r]);
        size_t gidx = (size_t)(b * 128 + ch) * PIX + px;
        float cv = c[gidx];
        float cn = fg * cv + ig * gg;
        cnext[gidx] = cn;
        float tv = og * ftanh(cn);
        tbuf[gidx] = f2bf(tv);
        gs[mi2] += tv; gs2[mi2] += tv * tv;
      }
    }
  }
  #pragma unroll
  for (int mi2 = 0; mi2 < 2; mi2++) {
    float s = gs[mi2], s2 = gs2[mi2];
    s += __shfl_xor(s, 1); s += __shfl_xor(s, 2); s += __shfl_xor(s, 4);
    s += __shfl_xor(s, 8); s += __shfl_xor(s, 16); s += __shfl_xor(s, 32);
    s2 += __shfl_xor(s2, 1); s2 += __shfl_xor(s2, 2); s2 += __shfl_xor(s2, 4);
    s2 += __shfl_xor(s2, 8); s2 += __shfl_xor(s2, 16); s2 += __shfl_xor(s2, 32);
    if (l == 0) {
      int g = w + mi2 * 4;
      atomicAdd(&sStat[g * 2], s);
      atomicAdd(&sStat[g * 2 + 1], s2);
    }
  }
  __syncthreads();
  if (t < 16) atomicAdd(&stB_raw[b * 16 + t], sStat[t]);
}

// ---------------- hnext = GN2(tbuf), inline stats finalize ----------------
__global__ __launch_bounds__(256) void k_gnout(
    const ushort* __restrict__ tbuf, const float* __restrict__ stB_raw,
    const float* __restrict__ gn_g, const float* __restrict__ gn_b,
    float* __restrict__ hnext)
{
  size_t idx = ((size_t)blockIdx.x * 256 + threadIdx.x) * 8;
  if (idx >= (size_t)16777216) return;
  int chrow = (int)(idx >> 14);
  int b = chrow >> 7, ch = chrow & 127, g = ch >> 4;
  const float invN = 1.f / 262144.f;
  float mu = stB_raw[b * 16 + g * 2] * invN;
  float var = stB_raw[b * 16 + g * 2 + 1] * invN - mu * mu;
  float rstd = rsqrtf(var + EPSF);
  float A = gn_g[ch] * rstd, Bv = gn_b[ch] - mu * A;
  uint4 u = *reinterpret_cast<const uint4*>(tbuf + idx);
  float4 o0, o1;
  o0.x = bf2f((ushort)(u.x & 0xFFFFu)) * A + Bv;
  o0.y = bf2f((ushort)(u.x >> 16)) * A + Bv;
  o0.z = bf2f((ushort)(u.y & 0xFFFFu)) * A + Bv;
  o0.w = bf2f((ushort)(u.y >> 16)) * A + Bv;
  o1.x = bf2f((ushort)(u.z & 0xFFFFu)) * A + Bv;
  o1.y = bf2f((ushort)(u.z >> 16)) * A + Bv;
  o1.z = bf2f((ushort)(u.w & 0xFFFFu)) * A + Bv;
  o1.w = bf2f((ushort)(u.w >> 16)) * A + Bv;
  *reinterpret_cast<float4*>(hnext + idx) = o0;
  *reinterpret_cast<float4*>(hnext + idx + 4) = o1;
}

extern "C" void kernel_launch(void* const* d_in, const int* in_sizes, int n_in,
                              void* d_out, int out_size, void* d_ws, size_t ws_size,
                              hipStream_t stream) {
  (void)in_sizes; (void)n_in; (void)out_size; (void)ws_size;
  const float* x      = (const float*)d_in[0];
  const float* h      = (const float*)d_in[1];
  const float* c      = (const float*)d_in[2];
  const float* Wproj  = (const float*)d_in[3];
  const float* bproj  = (const float*)d_in[4];
  const float* ln_g   = (const float*)d_in[5];
  const float* ln_b   = (const float*)d_in[6];
  const float* Wqkv   = (const float*)d_in[7];
  const float* bqkv   = (const float*)d_in[8];
  const float* Wo     = (const float*)d_in[9];
  const float* bo     = (const float*)d_in[10];
  const float* Wgates = (const float*)d_in[11];
  const float* bgates = (const float*)d_in[12];
  const float* gn_g   = (const float*)d_in[13];
  const float* gn_b   = (const float*)d_in[14];

  float* out = (float*)d_out;
  float* hnext = out;
  float* cnext = out + 16777216;

  char* W = (char*)d_ws;
  ushort* attn = (ushort*)W;                          // 32 MB bf16
  ushort* tbuf = (ushort*)(W + 33554432);             // 32 MB bf16
  size_t off = 67108864;
  ushort* FWp = (ushort*)(W + off); off += 49152;
  ushort* FWq = (ushort*)(W + off); off += 98304;
  ushort* FWo = (ushort*)(W + off); off += 32768;
  ushort* FWg = (ushort*)(W + off); off += 131072;
  float* stA_raw = (float*)(W + off); off += 512;
  float* stB_raw = (float*)(W + off); off += 512;

  hipMemsetAsync(stA_raw, 0, 1024, stream);

  k_prep<<<76, 256, 0, stream>>>(Wproj, Wqkv, Wo, Wgates, FWp, FWq, FWo, FWg);

  k_attn<<<2048, 256, 0, stream>>>(x, h, FWp, bproj, ln_g, ln_b,
                                   FWq, bqkv, FWo, bo, attn, stA_raw);
  k_gates<<<4096, 256, 0, stream>>>(attn, stA_raw, gn_g, gn_b, FWg, bgates,
                                    c, cnext, tbuf, stB_raw);
  k_gnout<<<8192, 256, 0, stream>>>(tbuf, stB_raw, gn_g, gn_b, hnext);
}

// Round 8
// 236.265 us; speedup vs baseline: 3.6379x; 1.0176x over previous
//
#include <hip/hip_runtime.h>
#include <math.h>

typedef unsigned int uint;
typedef unsigned short ushort;
typedef short s16x8 __attribute__((ext_vector_type(8)));
typedef float f32x4 __attribute__((ext_vector_type(4)));

#define PIX 16384
#define EPSF 1e-5f

__device__ __forceinline__ ushort f2bf(float f) {
  union { float f; uint u; } v; v.f = f;
  uint u = v.u;
  uint r = (u + 0x7FFFu + ((u >> 16) & 1u)) >> 16;
  return (ushort)r;
}
__device__ __forceinline__ float bf2f(ushort h) {
  union { uint u; float f; } v; v.u = ((uint)h) << 16;
  return v.f;
}
__device__ __forceinline__ uint pk2(float a, float b) {
  return (uint)f2bf(a) | ((uint)f2bf(b) << 16);
}
__device__ __forceinline__ float fsigmoid(float v) { return 1.f / (1.f + __expf(-v)); }
__device__ __forceinline__ float ftanh(float v) { return 1.f - 2.f / (__expf(2.f * v) + 1.f); }

union Frag { uint4 u4; uint u[4]; s16x8 s; };

// ---------------- merged weight fragment prep ----------------
// frag (mt, ks): lane l elem j = W[mt*16 + (l&15)][ks*32 + (l>>4)*8 + j]
// FWq columns pre-scaled by ln_g (LN folded into QKV GEMM).
__global__ void k_prep(const float* __restrict__ Wp, const float* __restrict__ Wq,
                       const float* __restrict__ Wo, const float* __restrict__ Wg,
                       const float* __restrict__ ln_g,
                       ushort* __restrict__ FWp, ushort* __restrict__ FWq,
                       ushort* __restrict__ FWo, ushort* __restrict__ FWg) {
  int idx = blockIdx.x * 256 + threadIdx.x;   // [0, 19456)
  const float* W; ushort* F; int KS, ldw, rel; bool scale = false;
  if (idx < 3072)       { W = Wp; F = FWp; KS = 6; ldw = 192; rel = idx; }
  else if (idx < 9216)  { W = Wq; F = FWq; KS = 4; ldw = 128; rel = idx - 3072; scale = true; }
  else if (idx < 11264) { W = Wo; F = FWo; KS = 4; ldw = 128; rel = idx - 9216; }
  else                  { W = Wg; F = FWg; KS = 4; ldw = 128; rel = idx - 11264; }
  int l = rel & 63, rest = rel >> 6;
  int ks = rest % KS, mt = rest / KS;
  int col = ks * 32 + (l >> 4) * 8;
  const float* src = W + (size_t)(mt * 16 + (l & 15)) * ldw + col;
  float g[8] = {1.f, 1.f, 1.f, 1.f, 1.f, 1.f, 1.f, 1.f};
  if (scale) {
    #pragma unroll
    for (int j = 0; j < 8; j++) g[j] = ln_g[col + j];
  }
  uint4 v;
  v.x = pk2(src[0] * g[0], src[1] * g[1]);
  v.y = pk2(src[2] * g[2], src[3] * g[3]);
  v.z = pk2(src[4] * g[4], src[5] * g[5]);
  v.w = pk2(src[6] * g[6], src[7] * g[7]);
  *reinterpret_cast<uint4*>(F + (size_t)rel * 8) = v;
}

// S_o = sum_i Wqkv[o,i]*ln_g[i];  Tb_o = sum_i Wqkv[o,i]*ln_b[i] + bqkv[o]
__global__ void k_prep2(const float* __restrict__ Wq, const float* __restrict__ ln_g,
                        const float* __restrict__ ln_b, const float* __restrict__ bqkv,
                        float* __restrict__ Sarr, float* __restrict__ Tbarr) {
  int o = threadIdx.x;
  if (o >= 384) return;
  float S = 0.f, T = 0.f;
  const float* wr = Wq + (size_t)o * 128;
  for (int i = 0; i < 128; i++) {
    float wv = wr[i];
    S = fmaf(wv, ln_g[i], S);
    T = fmaf(wv, ln_b[i], T);
  }
  Sarr[o] = S;
  Tbarr[o] = T + bqkv[o];
}

// ---------------- fused proj + (folded LN) + window MHSA + Wo (+GN stats) ----------------
// Block = 4 windows (64 tokens). Waves split M (channel tiles) in GEMM phases; each
// A-frag feeds 4 MFMAs. Attention core stays per-wave = per-window.
// LDS (bytes): [0,26112)     sInP [96][68]dw   (ph0-1)
//              [0,17408)     sXn  [64][136]us  (ph1b-2)  -> sP [4 waves][4096B] (ph3)
//              [17408,51200) sQK  4 x 8448B slices (ph2-3); slice+[4096,8448) = sO (ph3-4)
//              [51200,67584) sV   [4][128][16]us (ph2-3) -> sFin [4][128][16]us (ph4-5)
__global__ __launch_bounds__(256, 2) void k_attn(
    const float* __restrict__ x, const float* __restrict__ h,
    const ushort* __restrict__ FWp, const float* __restrict__ bproj,
    const ushort* __restrict__ FWq, const float* __restrict__ Sarr,
    const float* __restrict__ Tbarr,
    const ushort* __restrict__ FWoT, const float* __restrict__ bo,
    ushort* __restrict__ attn_map, float* __restrict__ stA_raw)
{
  __shared__ __align__(16) char LM[67584];
  __shared__ float sSum[64], sSum2[64];
  __shared__ float sStat[16];

  const int t = threadIdx.x;
  const int bid = blockIdx.x;
  const int b = bid >> 8, wh = (bid >> 3) & 31, ww0 = bid & 7;
  const int w = t >> 6, l = t & 63, q = l >> 4, r16 = l & 15;

  uint* sInP = (uint*)LM;            // [96][68] dwords
  ushort* sXn = (ushort*)LM;         // [64][136]

  if (t < 64) { sSum[t] = 0.f; sSum2[t] = 0.f; }
  if (t < 16) sStat[t] = 0.f;

  // ---- phase 0: stage concat(x,h) -> sInP[chp][col], col = window*16 + token ----
  {
    const float* xb = x + (size_t)b * 64 * PIX;
    const float* hb = h + (size_t)b * 128 * PIX;
    #pragma unroll
    for (int it = 0; it < 6; it++) {
      int item = it * 256 + t;                 // [0,1536)
      int wv = item & 3, r = (item >> 2) & 3, chp = item >> 4;
      int ch0 = chp * 2;
      int gpix = (wh * 4 + r) * 128 + ww0 * 16 + wv * 4;
      float4 a, c2;
      if (ch0 < 64) {
        a  = *reinterpret_cast<const float4*>(xb + (size_t)ch0 * PIX + gpix);
        c2 = *reinterpret_cast<const float4*>(xb + (size_t)(ch0 + 1) * PIX + gpix);
      } else {
        a  = *reinterpret_cast<const float4*>(hb + (size_t)(ch0 - 64) * PIX + gpix);
        c2 = *reinterpret_cast<const float4*>(hb + (size_t)(ch0 - 63) * PIX + gpix);
      }
      uint4 pkd;
      pkd.x = pk2(a.x, c2.x); pkd.y = pk2(a.y, c2.y);
      pkd.z = pk2(a.z, c2.z); pkd.w = pk2(a.w, c2.w);
      *reinterpret_cast<uint4*>(sInP + chp * 68 + wv * 16 + r * 4) = pkd;
    }
  }
  __syncthreads();   // B1

  // ---- phase 1: proj MFMA. wave w owns mt in {w, w+4}; nt = window 0..3 ----
  f32x4 acc1[2][4];
  {
    #pragma unroll
    for (int mi = 0; mi < 2; mi++)
      #pragma unroll
      for (int nt = 0; nt < 4; nt++) acc1[mi][nt] = (f32x4){0.f, 0.f, 0.f, 0.f};
    for (int ks = 0; ks < 6; ks++) {
      Frag bf[4];
      #pragma unroll
      for (int nt = 0; nt < 4; nt++)
        #pragma unroll
        for (int s = 0; s < 4; s++)
          bf[nt].u[s] = sInP[(ks * 16 + q * 4 + s) * 68 + nt * 16 + r16];
      #pragma unroll
      for (int mi = 0; mi < 2; mi++) {
        Frag af;
        af.u4 = *reinterpret_cast<const uint4*>(FWp + (((w + mi * 4) * 6 + ks) * 64 + l) * 8);
        #pragma unroll
        for (int nt = 0; nt < 4; nt++)
          acc1[mi][nt] = __builtin_amdgcn_mfma_f32_16x16x32_bf16(af.s, bf[nt].s, acc1[mi][nt], 0, 0, 0);
      }
    }
  }
  __syncthreads();   // B2: all sInP reads done; sXn overlays

  // ---- phase 1b: bias, pack raw p -> sXn, per-token LN stats (fp32) ----
  {
    float pst[4] = {0.f, 0.f, 0.f, 0.f}, pst2[4] = {0.f, 0.f, 0.f, 0.f};
    #pragma unroll
    for (int mi = 0; mi < 2; mi++) {
      int o0 = (w + mi * 4) * 16 + q * 4;
      const float4 bv = *reinterpret_cast<const float4*>(bproj + o0);
      #pragma unroll
      for (int nt = 0; nt < 4; nt++) {
        float v0 = acc1[mi][nt][0] + bv.x, v1 = acc1[mi][nt][1] + bv.y;
        float v2 = acc1[mi][nt][2] + bv.z, v3 = acc1[mi][nt][3] + bv.w;
        uint2 pk; pk.x = pk2(v0, v1); pk.y = pk2(v2, v3);
        *reinterpret_cast<uint2*>(sXn + (nt * 16 + r16) * 136 + o0) = pk;
        pst[nt]  += v0 + v1 + v2 + v3;
        pst2[nt] += v0 * v0 + v1 * v1 + v2 * v2 + v3 * v3;
      }
    }
    #pragma unroll
    for (int nt = 0; nt < 4; nt++) {
      float s = pst[nt], s2 = pst2[nt];
      s  += __shfl_xor(s, 16);  s  += __shfl_xor(s, 32);
      s2 += __shfl_xor(s2, 16); s2 += __shfl_xor(s2, 32);
      if (q == 0) {
        atomicAdd(&sSum[nt * 16 + r16], s);
        atomicAdd(&sSum2[nt * 16 + r16], s2);
      }
    }
  }
  __syncthreads();   // B3: sXn + stats ready

  // ---- phase 2: QKV MFMA (wave w owns mt in {w,w+4,...,w+20}) + LN-affine epilogue ----
  {
    f32x4 acc2[6][4];
    #pragma unroll
    for (int mi = 0; mi < 6; mi++)
      #pragma unroll
      for (int nt = 0; nt < 4; nt++) acc2[mi][nt] = (f32x4){0.f, 0.f, 0.f, 0.f};
    for (int ks = 0; ks < 4; ks++) {
      Frag bf[4];
      #pragma unroll
      for (int nt = 0; nt < 4; nt++)
        bf[nt].u4 = *reinterpret_cast<const uint4*>(sXn + (nt * 16 + r16) * 136 + ks * 32 + q * 8);
      #pragma unroll
      for (int mi = 0; mi < 6; mi++) {
        Frag af;
        af.u4 = *reinterpret_cast<const uint4*>(FWq + (((w + mi * 4) * 4 + ks) * 64 + l) * 8);
        #pragma unroll
        for (int nt = 0; nt < 4; nt++)
          acc2[mi][nt] = __builtin_amdgcn_mfma_f32_16x16x32_bf16(af.s, bf[nt].s, acc2[mi][nt], 0, 0, 0);
      }
    }
    float rstd_[4], mr_[4];
    #pragma unroll
    for (int nt = 0; nt < 4; nt++) {
      int tok = nt * 16 + r16;
      float mu = sSum[tok] * 0.0078125f;
      float var = sSum2[tok] * 0.0078125f - mu * mu;
      rstd_[nt] = rsqrtf(var + EPSF);
      mr_[nt] = -mu * rstd_[nt];
    }
    ushort* sQKu = (ushort*)(LM + 17408);
    ushort* sVu  = (ushort*)(LM + 51200);
    #pragma unroll
    for (int mi = 0; mi < 6; mi++) {
      int mt = w + mi * 4;
      int oo = mt * 16 + q * 4;
      const float4 S4  = *reinterpret_cast<const float4*>(Sarr + oo);
      const float4 Tb4 = *reinterpret_cast<const float4*>(Tbarr + oo);
      #pragma unroll
      for (int nt = 0; nt < 4; nt++) {
        float v0 = fmaf(rstd_[nt], acc2[mi][nt][0], fmaf(mr_[nt], S4.x, Tb4.x));
        float v1 = fmaf(rstd_[nt], acc2[mi][nt][1], fmaf(mr_[nt], S4.y, Tb4.y));
        float v2 = fmaf(rstd_[nt], acc2[mi][nt][2], fmaf(mr_[nt], S4.z, Tb4.z));
        float v3 = fmaf(rstd_[nt], acc2[mi][nt][3], fmaf(mr_[nt], S4.w, Tb4.w));
        if (mi < 4) {        // mt < 16: Q or K
          uint2 pk; pk.x = pk2(v0, v1); pk.y = pk2(v2, v3);
          *reinterpret_cast<uint2*>(sQKu + nt * 4224 + r16 * 264 + oo) = pk;
        } else {             // V
          ushort* vd = sVu + nt * 2048 + (oo - 256) * 16 + r16;
          vd[0] = f2bf(v0); vd[16] = f2bf(v1); vd[32] = f2bf(v2); vd[48] = f2bf(v3);
        }
      }
    }
  }
  __syncthreads();   // B4: Q/K/V complete; sXn dead -> P arenas

  // ---- phase 3: scores + softmax + PV, wave = window w.
  //      P lives in dead sXn region [w*4096, w*4096+4096) — no Q/K overlay. ----
  {
    const float scale = 0.17677669529663687f;
    ushort* sQKw = (ushort*)(LM + 17408 + w * 8448);
    ushort* sPw  = (ushort*)(LM + w * 4096);
    Frag af4[4], bf4[4];
    #pragma unroll
    for (int hd = 0; hd < 4; hd++) {
      af4[hd].u4 = *reinterpret_cast<const uint4*>(sQKw + r16 * 264 + hd * 32 + q * 8);
      bf4[hd].u4 = *reinterpret_cast<const uint4*>(sQKw + r16 * 264 + 128 + hd * 32 + q * 8);
    }
    #pragma unroll
    for (int hd = 0; hd < 4; hd++) {
      if (l < 32) {
        int row = l >> 1, hz = l & 1;
        uint4 z = {0u, 0u, 0u, 0u};
        *reinterpret_cast<uint4*>(sPw + hd * 512 + row * 32 + 16 + hz * 8) = z;
      }
    }
    f32x4 sc[4];
    #pragma unroll
    for (int hd = 0; hd < 4; hd++) {
      f32x4 z4 = (f32x4){0.f, 0.f, 0.f, 0.f};
      sc[hd] = __builtin_amdgcn_mfma_f32_16x16x32_bf16(af4[hd].s, bf4[hd].s, z4, 0, 0, 0);
    }
    #pragma unroll
    for (int hd = 0; hd < 4; hd++) {
      ushort* pd = sPw + hd * 512 + (q * 4) * 32 + r16;
      #pragma unroll
      for (int r = 0; r < 4; r++) {
        float sv = sc[hd][r] * scale;
        float mx = sv;
        mx = fmaxf(mx, __shfl_xor(mx, 1));
        mx = fmaxf(mx, __shfl_xor(mx, 2));
        mx = fmaxf(mx, __shfl_xor(mx, 4));
        mx = fmaxf(mx, __shfl_xor(mx, 8));
        float e = __expf(sv - mx);
        float sm = e;
        sm += __shfl_xor(sm, 1); sm += __shfl_xor(sm, 2);
        sm += __shfl_xor(sm, 4); sm += __shfl_xor(sm, 8);
        pd[r * 32] = f2bf(e / sm);
      }
    }
    // PV -> sO (slice + [4096, 8448))
    ushort* sOw = (ushort*)(LM + 17408 + w * 8448 + 4096);
    ushort* sVw = (ushort*)(LM + 51200) + w * 2048;
    #pragma unroll
    for (int hd = 0; hd < 4; hd++) {
      Frag pa;
      pa.u4 = *reinterpret_cast<const uint4*>(sPw + hd * 512 + r16 * 32 + q * 8);
      #pragma unroll
      for (int nt2 = 0; nt2 < 2; nt2++) {
        int ch = hd * 32 + nt2 * 16 + r16;
        int off = (q < 2) ? q * 8 : 0;
        Frag vf;
        vf.u4 = *reinterpret_cast<const uint4*>(sVw + ch * 16 + off);
        f32x4 z4 = (f32x4){0.f, 0.f, 0.f, 0.f};
        f32x4 o4 = __builtin_amdgcn_mfma_f32_16x16x32_bf16(pa.s, vf.s, z4, 0, 0, 0);
        ushort* od = sOw + (q * 4) * 136 + ch;
        od[0] = f2bf(o4[0]); od[136] = f2bf(o4[1]);
        od[272] = f2bf(o4[2]); od[408] = f2bf(o4[3]);
      }
    }
  }
  __syncthreads();   // B5: all sO ready

  // ---- phase 4: Wo MFMA. wave w owns ntg in {w, w+4}; nt = window ----
  {
    ushort* sFinu = (ushort*)(LM + 51200);
    Frag a4[4][4];
    #pragma unroll
    for (int nt = 0; nt < 4; nt++) {
      ushort* sOnt = (ushort*)(LM + 17408 + nt * 8448 + 4096);
      #pragma unroll
      for (int ks = 0; ks < 4; ks++)
        a4[nt][ks].u4 = *reinterpret_cast<const uint4*>(sOnt + r16 * 136 + ks * 32 + q * 8);
    }
    #pragma unroll
    for (int mi2 = 0; mi2 < 2; mi2++) {
      int ntg = w + mi2 * 4;
      f32x4 acw[4];
      #pragma unroll
      for (int nt = 0; nt < 4; nt++) acw[nt] = (f32x4){0.f, 0.f, 0.f, 0.f};
      #pragma unroll
      for (int ks = 0; ks < 4; ks++) {
        Frag bfw;
        bfw.u4 = *reinterpret_cast<const uint4*>(FWoT + ((ntg * 4 + ks) * 64 + l) * 8);
        #pragma unroll
        for (int nt = 0; nt < 4; nt++)
          acw[nt] = __builtin_amdgcn_mfma_f32_16x16x32_bf16(a4[nt][ks].s, bfw.s, acw[nt], 0, 0, 0);
      }
      int ch = ntg * 16 + r16;
      float bb = bo[ch];
      #pragma unroll
      for (int nt = 0; nt < 4; nt++) {
        uint2 pk;
        pk.x = pk2(acw[nt][0] + bb, acw[nt][1] + bb);
        pk.y = pk2(acw[nt][2] + bb, acw[nt][3] + bb);
        *reinterpret_cast<uint2*>(sFinu + nt * 2048 + ch * 16 + q * 4) = pk;
      }
    }
  }
  __syncthreads();   // B6

  // ---- phase 5: coalesced writeout (2 windows per 16B) + GN partial stats ----
  {
    ushort* sFinu = (ushort*)(LM + 51200);
    #pragma unroll
    for (int it = 0; it < 4; it++) {
      int seg = it * 256 + t;            // [0,1024)
      int ch = seg >> 3, r = (seg >> 1) & 3, half = seg & 1;
      const ushort* f0 = sFinu + (half * 2    ) * 2048;
      const ushort* f1 = sFinu + (half * 2 + 1) * 2048;
      uint2 a  = *reinterpret_cast<const uint2*>(f0 + ch * 16 + r * 4);
      uint2 c2 = *reinterpret_cast<const uint2*>(f1 + ch * 16 + r * 4);
      uint4 val = {a.x, a.y, c2.x, c2.y};
      *reinterpret_cast<uint4*>(attn_map + (size_t)(b * 128 + ch) * PIX
                                + (wh * 4 + r) * 128 + ww0 * 16 + half * 8) = val;
      float sv = 0.f, sv2 = 0.f;
      uint uu[4] = {val.x, val.y, val.z, val.w};
      #pragma unroll
      for (int k2 = 0; k2 < 4; k2++) {
        float fv0 = bf2f((ushort)(uu[k2] & 0xFFFFu));
        float fv1 = bf2f((ushort)(uu[k2] >> 16));
        sv += fv0 + fv1; sv2 += fv0 * fv0 + fv1 * fv1;
      }
      sv  += __shfl_xor(sv, 1);  sv  += __shfl_xor(sv, 2);  sv  += __shfl_xor(sv, 4);
      sv2 += __shfl_xor(sv2, 1); sv2 += __shfl_xor(sv2, 2); sv2 += __shfl_xor(sv2, 4);
      if ((t & 7) == 0) {
        int g = ch >> 4;
        atomicAdd(&sStat[g * 2], sv);
        atomicAdd(&sStat[g * 2 + 1], sv2);
      }
    }
  }
  __syncthreads();
  if (t < 16) atomicAdd(&stA_raw[b * 16 + t], sStat[t]);
}

// ---------------- GN + gates MFMA + LSTM update (+stats for GN2) ----------------
__global__ __launch_bounds__(256, 4) void k_gates(
    const ushort* __restrict__ attn_map, const float* __restrict__ stA_raw,
    const float* __restrict__ gn_g, const float* __restrict__ gn_b,
    const ushort* __restrict__ FWg, const float* __restrict__ bgates,
    const float* __restrict__ c, float* __restrict__ cnext,
    ushort* __restrict__ tbuf, float* __restrict__ stB_raw)
{
  __shared__ uint sG[64 * 34];
  __shared__ float sA[128], sB[128];
  __shared__ float sStat[16];
  const int t = threadIdx.x, bid = blockIdx.x;
  const int b = bid >> 9, p0 = (bid & 511) * 32;
  const int w = t >> 6, l = t & 63, q = l >> 4, r16 = l & 15;
  if (t < 128) {
    int g = t >> 4;
    const float invN = 1.f / 262144.f;
    float mu = stA_raw[b * 16 + g * 2] * invN;
    float var = stA_raw[b * 16 + g * 2 + 1] * invN - mu * mu;
    float rs = rsqrtf(var + EPSF);
    float A = rs * gn_g[t];
    sA[t] = A; sB[t] = gn_b[t] - mu * A;
  }
  if (t >= 240) sStat[t - 240] = 0.f;
  __syncthreads();

  {
    int pr = t >> 2, px0 = (t & 3) * 8;
    int c0 = pr * 2;
    const ushort* ab = attn_map + (size_t)(b * 128) * PIX + p0 + px0;
    uint4 a0 = *reinterpret_cast<const uint4*>(ab + (size_t)c0 * PIX);
    uint4 a1 = *reinterpret_cast<const uint4*>(ab + (size_t)(c0 + 1) * PIX);
    float A0 = sA[c0], B0 = sB[c0], A1 = sA[c0 + 1], B1 = sB[c0 + 1];
    uint u0[4] = {a0.x, a0.y, a0.z, a0.w};
    uint u1[4] = {a1.x, a1.y, a1.z, a1.w};
    uint d[8];
    #pragma unroll
    for (int j = 0; j < 4; j++) {
      float v0a = bf2f((ushort)(u0[j] & 0xFFFFu)) * A0 + B0;
      float v0b = bf2f((ushort)(u0[j] >> 16)) * A0 + B0;
      float v1a = bf2f((ushort)(u1[j] & 0xFFFFu)) * A1 + B1;
      float v1b = bf2f((ushort)(u1[j] >> 16)) * A1 + B1;
      d[j * 2]     = pk2(v0a, v1a);
      d[j * 2 + 1] = pk2(v0b, v1b);
    }
    uint4 w0 = {d[0], d[1], d[2], d[3]};
    uint4 w1 = {d[4], d[5], d[6], d[7]};
    *reinterpret_cast<uint4*>(&sG[pr * 34 + px0]) = w0;
    *reinterpret_cast<uint4*>(&sG[pr * 34 + px0 + 4]) = w1;
  }
  __syncthreads();

  f32x4 acc[8][2];
  #pragma unroll
  for (int mi = 0; mi < 8; mi++)
    #pragma unroll
    for (int nt = 0; nt < 2; nt++) acc[mi][nt] = (f32x4){0.f, 0.f, 0.f, 0.f};

  for (int ks = 0; ks < 4; ks++) {
    Frag bf[2];
    #pragma unroll
    for (int nt = 0; nt < 2; nt++)
      #pragma unroll
      for (int s = 0; s < 4; s++)
        bf[nt].u[s] = sG[(ks * 16 + q * 4 + s) * 34 + nt * 16 + r16];
    #pragma unroll
    for (int mi = 0; mi < 8; mi++) {
      int mt = w + mi * 4;
      Frag af;
      af.u4 = *reinterpret_cast<const uint4*>(FWg + ((mt * 4 + ks) * 64 + l) * 8);
      #pragma unroll
      for (int nt = 0; nt < 2; nt++)
        acc[mi][nt] = __builtin_amdgcn_mfma_f32_16x16x32_bf16(af.s, bf[nt].s, acc[mi][nt], 0, 0, 0);
    }
  }

  float gs[2] = {0.f, 0.f}, gs2[2] = {0.f, 0.f};
  #pragma unroll
  for (int mi2 = 0; mi2 < 2; mi2++) {
    int ch0 = (w + mi2 * 4) * 16 + q * 4;
    const float4 bi = *reinterpret_cast<const float4*>(bgates + ch0);
    const float4 bfg = *reinterpret_cast<const float4*>(bgates + 128 + ch0);
    const float4 bog = *reinterpret_cast<const float4*>(bgates + 256 + ch0);
    const float4 bgg = *reinterpret_cast<const float4*>(bgates + 384 + ch0);
    const float bis[4] = {bi.x, bi.y, bi.z, bi.w};
    const float bfs[4] = {bfg.x, bfg.y, bfg.z, bfg.w};
    const float bos[4] = {bog.x, bog.y, bog.z, bog.w};
    const float bgs[4] = {bgg.x, bgg.y, bgg.z, bgg.w};
    #pragma unroll
    for (int nt = 0; nt < 2; nt++) {
      int px = p0 + nt * 16 + r16;
      #pragma unroll
      for (int r = 0; r < 4; r++) {
        int ch = ch0 + r;
        float ig = fsigmoid(acc[mi2    ][nt][r] + bis[r]);
        float fg = fsigmoid(acc[mi2 + 2][nt][r] + bfs[r]);
        float og = fsigmoid(acc[mi2 + 4][nt][r] + bos[r]);
        float gg = ftanh   (acc[mi2 + 6][nt][r] + bgs[r]);
        size_t gidx = (size_t)(b * 128 + ch) * PIX + px;
        float cv = c[gidx];
        float cn = fg * cv + ig * gg;
        cnext[gidx] = cn;
        float tv = og * ftanh(cn);
        tbuf[gidx] = f2bf(tv);
        gs[mi2] += tv; gs2[mi2] += tv * tv;
      }
    }
  }
  #pragma unroll
  for (int mi2 = 0; mi2 < 2; mi2++) {
    float s = gs[mi2], s2 = gs2[mi2];
    s += __shfl_xor(s, 1); s += __shfl_xor(s, 2); s += __shfl_xor(s, 4);
    s += __shfl_xor(s, 8); s += __shfl_xor(s, 16); s += __shfl_xor(s, 32);
    s2 += __shfl_xor(s2, 1); s2 += __shfl_xor(s2, 2); s2 += __shfl_xor(s2, 4);
    s2 += __shfl_xor(s2, 8); s2 += __shfl_xor(s2, 16); s2 += __shfl_xor(s2, 32);
    if (l == 0) {
      int g = w + mi2 * 4;
      atomicAdd(&sStat[g * 2], s);
      atomicAdd(&sStat[g * 2 + 1], s2);
    }
  }
  __syncthreads();
  if (t < 16) atomicAdd(&stB_raw[b * 16 + t], sStat[t]);
}

// ---------------- hnext = GN2(tbuf), inline stats finalize ----------------
__global__ __launch_bounds__(256) void k_gnout(
    const ushort* __restrict__ tbuf, const float* __restrict__ stB_raw,
    const float* __restrict__ gn_g, const float* __restrict__ gn_b,
    float* __restrict__ hnext)
{
  size_t idx = ((size_t)blockIdx.x * 256 + threadIdx.x) * 8;
  if (idx >= (size_t)16777216) return;
  int chrow = (int)(idx >> 14);
  int b = chrow >> 7, ch = chrow & 127, g = ch >> 4;
  const float invN = 1.f / 262144.f;
  float mu = stB_raw[b * 16 + g * 2] * invN;
  float var = stB_raw[b * 16 + g * 2 + 1] * invN - mu * mu;
  float rstd = rsqrtf(var + EPSF);
  float A = gn_g[ch] * rstd, Bv = gn_b[ch] - mu * A;
  uint4 u = *reinterpret_cast<const uint4*>(tbuf + idx);
  float4 o0, o1;
  o0.x = bf2f((ushort)(u.x & 0xFFFFu)) * A + Bv;
  o0.y = bf2f((ushort)(u.x >> 16)) * A + Bv;
  o0.z = bf2f((ushort)(u.y & 0xFFFFu)) * A + Bv;
  o0.w = bf2f((ushort)(u.y >> 16)) * A + Bv;
  o1.x = bf2f((ushort)(u.z & 0xFFFFu)) * A + Bv;
  o1.y = bf2f((ushort)(u.z >> 16)) * A + Bv;
  o1.z = bf2f((ushort)(u.w & 0xFFFFu)) * A + Bv;
  o1.w = bf2f((ushort)(u.w >> 16)) * A + Bv;
  *reinterpret_cast<float4*>(hnext + idx) = o0;
  *reinterpret_cast<float4*>(hnext + idx + 4) = o1;
}

extern "C" void kernel_launch(void* const* d_in, const int* in_sizes, int n_in,
                              void* d_out, int out_size, void* d_ws, size_t ws_size,
                              hipStream_t stream) {
  (void)in_sizes; (void)n_in; (void)out_size; (void)ws_size;
  const float* x      = (const float*)d_in[0];
  const float* h      = (const float*)d_in[1];
  const float* c      = (const float*)d_in[2];
  const float* Wproj  = (const float*)d_in[3];
  const float* bproj  = (const float*)d_in[4];
  const float* ln_g   = (const float*)d_in[5];
  const float* ln_b   = (const float*)d_in[6];
  const float* Wqkv   = (const float*)d_in[7];
  const float* bqkv   = (const float*)d_in[8];
  const float* Wo     = (const float*)d_in[9];
  const float* bo     = (const float*)d_in[10];
  const float* Wgates = (const float*)d_in[11];
  const float* bgates = (const float*)d_in[12];
  const float* gn_g   = (const float*)d_in[13];
  const float* gn_b   = (const float*)d_in[14];

  float* out = (float*)d_out;
  float* hnext = out;
  float* cnext = out + 16777216;

  char* W = (char*)d_ws;
  ushort* attn = (ushort*)W;                          // 32 MB bf16
  ushort* tbuf = (ushort*)(W + 33554432);             // 32 MB bf16
  size_t off = 67108864;
  ushort* FWp = (ushort*)(W + off); off += 49152;
  ushort* FWq = (ushort*)(W + off); off += 98304;
  ushort* FWo = (ushort*)(W + off); off += 32768;
  ushort* FWg = (ushort*)(W + off); off += 131072;
  float* stA_raw = (float*)(W + off); off += 512;
  float* stB_raw = (float*)(W + off); off += 512;
  float* Sarr    = (float*)(W + off); off += 1536;
  float* Tbarr   = (float*)(W + off); off += 1536;

  hipMemsetAsync(stA_raw, 0, 1024, stream);

  k_prep<<<76, 256, 0, stream>>>(Wproj, Wqkv, Wo, Wgates, ln_g, FWp, FWq, FWo, FWg);
  k_prep2<<<1, 384, 0, stream>>>(Wqkv, ln_g, ln_b, bqkv, Sarr, Tbarr);

  k_attn<<<2048, 256, 0, stream>>>(x, h, FWp, bproj, FWq, Sarr, Tbarr,
                                   FWo, bo, attn, stA_raw);
  k_gates<<<4096, 256, 0, stream>>>(attn, stA_raw, gn_g, gn_b, FWg, bgates,
                                    c, cnext, tbuf, stB_raw);
  k_gnout<<<8192, 256, 0, stream>>>(tbuf, stB_raw, gn_g, gn_b, hnext);
}

// Round 9
// 225.706 us; speedup vs baseline: 3.8080x; 1.0468x over previous
//
#include <hip/hip_runtime.h>
#include <math.h>

typedef unsigned int uint;
typedef unsigned short ushort;
typedef short s16x8 __attribute__((ext_vector_type(8)));
typedef float f32x4 __attribute__((ext_vector_type(4)));

#define PIX 16384
#define EPSF 1e-5f

__device__ __forceinline__ ushort f2bf(float f) {
  union { float f; uint u; } v; v.f = f;
  uint u = v.u;
  uint r = (u + 0x7FFFu + ((u >> 16) & 1u)) >> 16;
  return (ushort)r;
}
__device__ __forceinline__ float bf2f(ushort h) {
  union { uint u; float f; } v; v.u = ((uint)h) << 16;
  return v.f;
}
__device__ __forceinline__ uint pk2(float a, float b) {
  return (uint)f2bf(a) | ((uint)f2bf(b) << 16);
}
__device__ __forceinline__ float fsigmoid(float v) { return 1.f / (1.f + __expf(-v)); }
__device__ __forceinline__ float ftanh(float v) { return 1.f - 2.f / (__expf(2.f * v) + 1.f); }

union Frag { uint4 u4; uint u[4]; s16x8 s; };

// ---------------- merged weight fragment prep ----------------
// frag (mt, ks): lane l elem j = W[mt*16 + (l&15)][ks*32 + (l>>4)*8 + j]
// FWq columns pre-scaled by ln_g (LN folded into QKV GEMM).
__global__ void k_prep(const float* __restrict__ Wp, const float* __restrict__ Wq,
                       const float* __restrict__ Wo, const float* __restrict__ Wg,
                       const float* __restrict__ ln_g,
                       ushort* __restrict__ FWp, ushort* __restrict__ FWq,
                       ushort* __restrict__ FWo, ushort* __restrict__ FWg) {
  int idx = blockIdx.x * 256 + threadIdx.x;   // [0, 19456)
  const float* W; ushort* F; int KS, ldw, rel; bool scale = false;
  if (idx < 3072)       { W = Wp; F = FWp; KS = 6; ldw = 192; rel = idx; }
  else if (idx < 9216)  { W = Wq; F = FWq; KS = 4; ldw = 128; rel = idx - 3072; scale = true; }
  else if (idx < 11264) { W = Wo; F = FWo; KS = 4; ldw = 128; rel = idx - 9216; }
  else                  { W = Wg; F = FWg; KS = 4; ldw = 128; rel = idx - 11264; }
  int l = rel & 63, rest = rel >> 6;
  int ks = rest % KS, mt = rest / KS;
  int col = ks * 32 + (l >> 4) * 8;
  const float* src = W + (size_t)(mt * 16 + (l & 15)) * ldw + col;
  float g[8] = {1.f, 1.f, 1.f, 1.f, 1.f, 1.f, 1.f, 1.f};
  if (scale) {
    #pragma unroll
    for (int j = 0; j < 8; j++) g[j] = ln_g[col + j];
  }
  uint4 v;
  v.x = pk2(src[0] * g[0], src[1] * g[1]);
  v.y = pk2(src[2] * g[2], src[3] * g[3]);
  v.z = pk2(src[4] * g[4], src[5] * g[5]);
  v.w = pk2(src[6] * g[6], src[7] * g[7]);
  *reinterpret_cast<uint4*>(F + (size_t)rel * 8) = v;
}

// S_o = sum_i Wqkv[o,i]*ln_g[i];  Tb_o = sum_i Wqkv[o,i]*ln_b[i] + bqkv[o]
__global__ void k_prep2(const float* __restrict__ Wq, const float* __restrict__ ln_g,
                        const float* __restrict__ ln_b, const float* __restrict__ bqkv,
                        float* __restrict__ Sarr, float* __restrict__ Tbarr) {
  int o = threadIdx.x;
  if (o >= 384) return;
  float S = 0.f, T = 0.f;
  const float* wr = Wq + (size_t)o * 128;
  for (int i = 0; i < 128; i++) {
    float wv = wr[i];
    S = fmaf(wv, ln_g[i], S);
    T = fmaf(wv, ln_b[i], T);
  }
  Sarr[o] = S;
  Tbarr[o] = T + bqkv[o];
}

// ---------------- fused proj + (folded LN) + window MHSA + Wo (+GN stats) ----------------
// (unchanged from round 8 — validated)
__global__ __launch_bounds__(256, 2) void k_attn(
    const float* __restrict__ x, const float* __restrict__ h,
    const ushort* __restrict__ FWp, const float* __restrict__ bproj,
    const ushort* __restrict__ FWq, const float* __restrict__ Sarr,
    const float* __restrict__ Tbarr,
    const ushort* __restrict__ FWoT, const float* __restrict__ bo,
    ushort* __restrict__ attn_map, float* __restrict__ stA_raw)
{
  __shared__ __align__(16) char LM[67584];
  __shared__ float sSum[64], sSum2[64];
  __shared__ float sStat[16];

  const int t = threadIdx.x;
  const int bid = blockIdx.x;
  const int b = bid >> 8, wh = (bid >> 3) & 31, ww0 = bid & 7;
  const int w = t >> 6, l = t & 63, q = l >> 4, r16 = l & 15;

  uint* sInP = (uint*)LM;            // [96][68] dwords
  ushort* sXn = (ushort*)LM;         // [64][136]

  if (t < 64) { sSum[t] = 0.f; sSum2[t] = 0.f; }
  if (t < 16) sStat[t] = 0.f;

  // ---- phase 0: stage concat(x,h) -> sInP[chp][col], col = window*16 + token ----
  {
    const float* xb = x + (size_t)b * 64 * PIX;
    const float* hb = h + (size_t)b * 128 * PIX;
    #pragma unroll
    for (int it = 0; it < 6; it++) {
      int item = it * 256 + t;                 // [0,1536)
      int wv = item & 3, r = (item >> 2) & 3, chp = item >> 4;
      int ch0 = chp * 2;
      int gpix = (wh * 4 + r) * 128 + ww0 * 16 + wv * 4;
      float4 a, c2;
      if (ch0 < 64) {
        a  = *reinterpret_cast<const float4*>(xb + (size_t)ch0 * PIX + gpix);
        c2 = *reinterpret_cast<const float4*>(xb + (size_t)(ch0 + 1) * PIX + gpix);
      } else {
        a  = *reinterpret_cast<const float4*>(hb + (size_t)(ch0 - 64) * PIX + gpix);
        c2 = *reinterpret_cast<const float4*>(hb + (size_t)(ch0 - 63) * PIX + gpix);
      }
      uint4 pkd;
      pkd.x = pk2(a.x, c2.x); pkd.y = pk2(a.y, c2.y);
      pkd.z = pk2(a.z, c2.z); pkd.w = pk2(a.w, c2.w);
      *reinterpret_cast<uint4*>(sInP + chp * 68 + wv * 16 + r * 4) = pkd;
    }
  }
  __syncthreads();   // B1

  // ---- phase 1: proj MFMA. wave w owns mt in {w, w+4}; nt = window 0..3 ----
  f32x4 acc1[2][4];
  {
    #pragma unroll
    for (int mi = 0; mi < 2; mi++)
      #pragma unroll
      for (int nt = 0; nt < 4; nt++) acc1[mi][nt] = (f32x4){0.f, 0.f, 0.f, 0.f};
    for (int ks = 0; ks < 6; ks++) {
      Frag bf[4];
      #pragma unroll
      for (int nt = 0; nt < 4; nt++)
        #pragma unroll
        for (int s = 0; s < 4; s++)
          bf[nt].u[s] = sInP[(ks * 16 + q * 4 + s) * 68 + nt * 16 + r16];
      #pragma unroll
      for (int mi = 0; mi < 2; mi++) {
        Frag af;
        af.u4 = *reinterpret_cast<const uint4*>(FWp + (((w + mi * 4) * 6 + ks) * 64 + l) * 8);
        #pragma unroll
        for (int nt = 0; nt < 4; nt++)
          acc1[mi][nt] = __builtin_amdgcn_mfma_f32_16x16x32_bf16(af.s, bf[nt].s, acc1[mi][nt], 0, 0, 0);
      }
    }
  }
  __syncthreads();   // B2: all sInP reads done; sXn overlays

  // ---- phase 1b: bias, pack raw p -> sXn, per-token LN stats (fp32) ----
  {
    float pst[4] = {0.f, 0.f, 0.f, 0.f}, pst2[4] = {0.f, 0.f, 0.f, 0.f};
    #pragma unroll
    for (int mi = 0; mi < 2; mi++) {
      int o0 = (w + mi * 4) * 16 + q * 4;
      const float4 bv = *reinterpret_cast<const float4*>(bproj + o0);
      #pragma unroll
      for (int nt = 0; nt < 4; nt++) {
        float v0 = acc1[mi][nt][0] + bv.x, v1 = acc1[mi][nt][1] + bv.y;
        float v2 = acc1[mi][nt][2] + bv.z, v3 = acc1[mi][nt][3] + bv.w;
        uint2 pk; pk.x = pk2(v0, v1); pk.y = pk2(v2, v3);
        *reinterpret_cast<uint2*>(sXn + (nt * 16 + r16) * 136 + o0) = pk;
        pst[nt]  += v0 + v1 + v2 + v3;
        pst2[nt] += v0 * v0 + v1 * v1 + v2 * v2 + v3 * v3;
      }
    }
    #pragma unroll
    for (int nt = 0; nt < 4; nt++) {
      float s = pst[nt], s2 = pst2[nt];
      s  += __shfl_xor(s, 16);  s  += __shfl_xor(s, 32);
      s2 += __shfl_xor(s2, 16); s2 += __shfl_xor(s2, 32);
      if (q == 0) {
        atomicAdd(&sSum[nt * 16 + r16], s);
        atomicAdd(&sSum2[nt * 16 + r16], s2);
      }
    }
  }
  __syncthreads();   // B3: sXn + stats ready

  // ---- phase 2: QKV MFMA (wave w owns mt in {w,w+4,...,w+20}) + LN-affine epilogue ----
  {
    f32x4 acc2[6][4];
    #pragma unroll
    for (int mi = 0; mi < 6; mi++)
      #pragma unroll
      for (int nt = 0; nt < 4; nt++) acc2[mi][nt] = (f32x4){0.f, 0.f, 0.f, 0.f};
    for (int ks = 0; ks < 4; ks++) {
      Frag bf[4];
      #pragma unroll
      for (int nt = 0; nt < 4; nt++)
        bf[nt].u4 = *reinterpret_cast<const uint4*>(sXn + (nt * 16 + r16) * 136 + ks * 32 + q * 8);
      #pragma unroll
      for (int mi = 0; mi < 6; mi++) {
        Frag af;
        af.u4 = *reinterpret_cast<const uint4*>(FWq + (((w + mi * 4) * 4 + ks) * 64 + l) * 8);
        #pragma unroll
        for (int nt = 0; nt < 4; nt++)
          acc2[mi][nt] = __builtin_amdgcn_mfma_f32_16x16x32_bf16(af.s, bf[nt].s, acc2[mi][nt], 0, 0, 0);
      }
    }
    float rstd_[4], mr_[4];
    #pragma unroll
    for (int nt = 0; nt < 4; nt++) {
      int tok = nt * 16 + r16;
      float mu = sSum[tok] * 0.0078125f;
      float var = sSum2[tok] * 0.0078125f - mu * mu;
      rstd_[nt] = rsqrtf(var + EPSF);
      mr_[nt] = -mu * rstd_[nt];
    }
    ushort* sQKu = (ushort*)(LM + 17408);
    ushort* sVu  = (ushort*)(LM + 51200);
    #pragma unroll
    for (int mi = 0; mi < 6; mi++) {
      int mt = w + mi * 4;
      int oo = mt * 16 + q * 4;
      const float4 S4  = *reinterpret_cast<const float4*>(Sarr + oo);
      const float4 Tb4 = *reinterpret_cast<const float4*>(Tbarr + oo);
      #pragma unroll
      for (int nt = 0; nt < 4; nt++) {
        float v0 = fmaf(rstd_[nt], acc2[mi][nt][0], fmaf(mr_[nt], S4.x, Tb4.x));
        float v1 = fmaf(rstd_[nt], acc2[mi][nt][1], fmaf(mr_[nt], S4.y, Tb4.y));
        float v2 = fmaf(rstd_[nt], acc2[mi][nt][2], fmaf(mr_[nt], S4.z, Tb4.z));
        float v3 = fmaf(rstd_[nt], acc2[mi][nt][3], fmaf(mr_[nt], S4.w, Tb4.w));
        if (mi < 4) {        // mt < 16: Q or K
          uint2 pk; pk.x = pk2(v0, v1); pk.y = pk2(v2, v3);
          *reinterpret_cast<uint2*>(sQKu + nt * 4224 + r16 * 264 + oo) = pk;
        } else {             // V
          ushort* vd = sVu + nt * 2048 + (oo - 256) * 16 + r16;
          vd[0] = f2bf(v0); vd[16] = f2bf(v1); vd[32] = f2bf(v2); vd[48] = f2bf(v3);
        }
      }
    }
  }
  __syncthreads();   // B4: Q/K/V complete; sXn dead -> P arenas

  // ---- phase 3: scores + softmax + PV, wave = window w ----
  {
    const float scale = 0.17677669529663687f;
    ushort* sQKw = (ushort*)(LM + 17408 + w * 8448);
    ushort* sPw  = (ushort*)(LM + w * 4096);
    Frag af4[4], bf4[4];
    #pragma unroll
    for (int hd = 0; hd < 4; hd++) {
      af4[hd].u4 = *reinterpret_cast<const uint4*>(sQKw + r16 * 264 + hd * 32 + q * 8);
      bf4[hd].u4 = *reinterpret_cast<const uint4*>(sQKw + r16 * 264 + 128 + hd * 32 + q * 8);
    }
    #pragma unroll
    for (int hd = 0; hd < 4; hd++) {
      if (l < 32) {
        int row = l >> 1, hz = l & 1;
        uint4 z = {0u, 0u, 0u, 0u};
        *reinterpret_cast<uint4*>(sPw + hd * 512 + row * 32 + 16 + hz * 8) = z;
      }
    }
    f32x4 sc[4];
    #pragma unroll
    for (int hd = 0; hd < 4; hd++) {
      f32x4 z4 = (f32x4){0.f, 0.f, 0.f, 0.f};
      sc[hd] = __builtin_amdgcn_mfma_f32_16x16x32_bf16(af4[hd].s, bf4[hd].s, z4, 0, 0, 0);
    }
    #pragma unroll
    for (int hd = 0; hd < 4; hd++) {
      ushort* pd = sPw + hd * 512 + (q * 4) * 32 + r16;
      #pragma unroll
      for (int r = 0; r < 4; r++) {
        float sv = sc[hd][r] * scale;
        float mx = sv;
        mx = fmaxf(mx, __shfl_xor(mx, 1));
        mx = fmaxf(mx, __shfl_xor(mx, 2));
        mx = fmaxf(mx, __shfl_xor(mx, 4));
        mx = fmaxf(mx, __shfl_xor(mx, 8));
        float e = __expf(sv - mx);
        float sm = e;
        sm += __shfl_xor(sm, 1); sm += __shfl_xor(sm, 2);
        sm += __shfl_xor(sm, 4); sm += __shfl_xor(sm, 8);
        pd[r * 32] = f2bf(e / sm);
      }
    }
    // PV -> sO (slice + [4096, 8448))
    ushort* sOw = (ushort*)(LM + 17408 + w * 8448 + 4096);
    ushort* sVw = (ushort*)(LM + 51200) + w * 2048;
    #pragma unroll
    for (int hd = 0; hd < 4; hd++) {
      Frag pa;
      pa.u4 = *reinterpret_cast<const uint4*>(sPw + hd * 512 + r16 * 32 + q * 8);
      #pragma unroll
      for (int nt2 = 0; nt2 < 2; nt2++) {
        int ch = hd * 32 + nt2 * 16 + r16;
        int off = (q < 2) ? q * 8 : 0;
        Frag vf;
        vf.u4 = *reinterpret_cast<const uint4*>(sVw + ch * 16 + off);
        f32x4 z4 = (f32x4){0.f, 0.f, 0.f, 0.f};
        f32x4 o4 = __builtin_amdgcn_mfma_f32_16x16x32_bf16(pa.s, vf.s, z4, 0, 0, 0);
        ushort* od = sOw + (q * 4) * 136 + ch;
        od[0] = f2bf(o4[0]); od[136] = f2bf(o4[1]);
        od[272] = f2bf(o4[2]); od[408] = f2bf(o4[3]);
      }
    }
  }
  __syncthreads();   // B5: all sO ready

  // ---- phase 4: Wo MFMA. wave w owns ntg in {w, w+4}; nt = window ----
  {
    ushort* sFinu = (ushort*)(LM + 51200);
    Frag a4[4][4];
    #pragma unroll
    for (int nt = 0; nt < 4; nt++) {
      ushort* sOnt = (ushort*)(LM + 17408 + nt * 8448 + 4096);
      #pragma unroll
      for (int ks = 0; ks < 4; ks++)
        a4[nt][ks].u4 = *reinterpret_cast<const uint4*>(sOnt + r16 * 136 + ks * 32 + q * 8);
    }
    #pragma unroll
    for (int mi2 = 0; mi2 < 2; mi2++) {
      int ntg = w + mi2 * 4;
      f32x4 acw[4];
      #pragma unroll
      for (int nt = 0; nt < 4; nt++) acw[nt] = (f32x4){0.f, 0.f, 0.f, 0.f};
      #pragma unroll
      for (int ks = 0; ks < 4; ks++) {
        Frag bfw;
        bfw.u4 = *reinterpret_cast<const uint4*>(FWoT + ((ntg * 4 + ks) * 64 + l) * 8);
        #pragma unroll
        for (int nt = 0; nt < 4; nt++)
          acw[nt] = __builtin_amdgcn_mfma_f32_16x16x32_bf16(a4[nt][ks].s, bfw.s, acw[nt], 0, 0, 0);
      }
      int ch = ntg * 16 + r16;
      float bb = bo[ch];
      #pragma unroll
      for (int nt = 0; nt < 4; nt++) {
        uint2 pk;
        pk.x = pk2(acw[nt][0] + bb, acw[nt][1] + bb);
        pk.y = pk2(acw[nt][2] + bb, acw[nt][3] + bb);
        *reinterpret_cast<uint2*>(sFinu + nt * 2048 + ch * 16 + q * 4) = pk;
      }
    }
  }
  __syncthreads();   // B6

  // ---- phase 5: coalesced writeout (2 windows per 16B) + GN partial stats ----
  {
    ushort* sFinu = (ushort*)(LM + 51200);
    #pragma unroll
    for (int it = 0; it < 4; it++) {
      int seg = it * 256 + t;            // [0,1024)
      int ch = seg >> 3, r = (seg >> 1) & 3, half = seg & 1;
      const ushort* f0 = sFinu + (half * 2    ) * 2048;
      const ushort* f1 = sFinu + (half * 2 + 1) * 2048;
      uint2 a  = *reinterpret_cast<const uint2*>(f0 + ch * 16 + r * 4);
      uint2 c2 = *reinterpret_cast<const uint2*>(f1 + ch * 16 + r * 4);
      uint4 val = {a.x, a.y, c2.x, c2.y};
      *reinterpret_cast<uint4*>(attn_map + (size_t)(b * 128 + ch) * PIX
                                + (wh * 4 + r) * 128 + ww0 * 16 + half * 8) = val;
      float sv = 0.f, sv2 = 0.f;
      uint uu[4] = {val.x, val.y, val.z, val.w};
      #pragma unroll
      for (int k2 = 0; k2 < 4; k2++) {
        float fv0 = bf2f((ushort)(uu[k2] & 0xFFFFu));
        float fv1 = bf2f((ushort)(uu[k2] >> 16));
        sv += fv0 + fv1; sv2 += fv0 * fv0 + fv1 * fv1;
      }
      sv  += __shfl_xor(sv, 1);  sv  += __shfl_xor(sv, 2);  sv  += __shfl_xor(sv, 4);
      sv2 += __shfl_xor(sv2, 1); sv2 += __shfl_xor(sv2, 2); sv2 += __shfl_xor(sv2, 4);
      if ((t & 7) == 0) {
        int g = ch >> 4;
        atomicAdd(&sStat[g * 2], sv);
        atomicAdd(&sStat[g * 2 + 1], sv2);
      }
    }
  }
  __syncthreads();
  if (t < 16) atomicAdd(&stA_raw[b * 16 + t], sStat[t]);
}

// ---------------- GN + gates MFMA + LSTM update (+stats for GN2) ----------------
// v3: transposed GEMM D[px][ch] (A = activations, B = weight frag — same FWg table).
// Thread's 4 acc regs = 4 consecutive px of one channel -> float4 c/cnext, uint2 tbuf.
// LDS sG2[px][ch] (132-us rows); A-frags are single ds_read_b128. c prefetched.
__global__ __launch_bounds__(256, 4) void k_gates(
    const ushort* __restrict__ attn_map, const float* __restrict__ stA_raw,
    const float* __restrict__ gn_g, const float* __restrict__ gn_b,
    const ushort* __restrict__ FWg, const float* __restrict__ bgates,
    const float* __restrict__ c, float* __restrict__ cnext,
    ushort* __restrict__ tbuf, float* __restrict__ stB_raw)
{
  __shared__ uint sG2[32 * 66];     // [px][ch-pair dwords + 2 pad] = 8448 B
  __shared__ float sA[128], sB[128];
  __shared__ float sStat[16];
  const int t = threadIdx.x, bid = blockIdx.x;
  const int b = bid >> 9, p0 = (bid & 511) * 32;
  const int w = t >> 6, l = t & 63, q = l >> 4, r16 = l & 15;

  if (t < 128) {
    int g = t >> 4;
    const float invN = 1.f / 262144.f;
    float mu = stA_raw[b * 16 + g * 2] * invN;
    float var = stA_raw[b * 16 + g * 2 + 1] * invN - mu * mu;
    float rs = rsqrtf(var + EPSF);
    float A = rs * gn_g[t];
    sA[t] = A; sB[t] = gn_b[t] - mu * A;
  }
  if (t >= 240) sStat[t - 240] = 0.f;
  __syncthreads();

  // ---- staging: GN(attn) -> sG2[px][ch] (transposed) ----
  {
    int pr = t >> 2, px0 = (t & 3) * 8;
    int c0 = pr * 2;
    const ushort* ab = attn_map + (size_t)(b * 128) * PIX + p0 + px0;
    uint4 a0 = *reinterpret_cast<const uint4*>(ab + (size_t)c0 * PIX);
    uint4 a1 = *reinterpret_cast<const uint4*>(ab + (size_t)(c0 + 1) * PIX);
    float A0 = sA[c0], B0 = sB[c0], A1 = sA[c0 + 1], B1 = sB[c0 + 1];
    uint u0[4] = {a0.x, a0.y, a0.z, a0.w};
    uint u1[4] = {a1.x, a1.y, a1.z, a1.w};
    #pragma unroll
    for (int j = 0; j < 4; j++) {
      float v0lo = bf2f((ushort)(u0[j] & 0xFFFFu)) * A0 + B0;   // ch c0,   px0+2j
      float v0hi = bf2f((ushort)(u0[j] >> 16)) * A0 + B0;       // ch c0,   px0+2j+1
      float v1lo = bf2f((ushort)(u1[j] & 0xFFFFu)) * A1 + B1;   // ch c0+1, px0+2j
      float v1hi = bf2f((ushort)(u1[j] >> 16)) * A1 + B1;       // ch c0+1, px0+2j+1
      sG2[(px0 + 2 * j) * 66 + pr]     = pk2(v0lo, v1lo);
      sG2[(px0 + 2 * j + 1) * 66 + pr] = pk2(v0hi, v1hi);
    }
  }

  // ---- prefetch c (float4 per (j,pxt)); latency hides under barrier+MFMA ----
  float4 cv[2][2];
  #pragma unroll
  for (int j = 0; j < 2; j++) {
    int ch = (w + 4 * j) * 16 + r16;
    const float* cb = c + (size_t)(b * 128 + ch) * PIX + p0 + q * 4;
    cv[j][0] = *reinterpret_cast<const float4*>(cb);
    cv[j][1] = *reinterpret_cast<const float4*>(cb + 16);
  }
  __syncthreads();

  // ---- gates GEMM: D[px][ch]; acc[gate][j][pxt], ch tile = w + 4j + 8*gate ----
  f32x4 acc[4][2][2];
  #pragma unroll
  for (int g2 = 0; g2 < 4; g2++)
    #pragma unroll
    for (int j = 0; j < 2; j++)
      #pragma unroll
      for (int pxt = 0; pxt < 2; pxt++) acc[g2][j][pxt] = (f32x4){0.f, 0.f, 0.f, 0.f};

  const ushort* sGu = (const ushort*)sG2;
  for (int ks = 0; ks < 4; ks++) {
    Frag af[2];
    #pragma unroll
    for (int pxt = 0; pxt < 2; pxt++)
      af[pxt].u4 = *reinterpret_cast<const uint4*>(sGu + (pxt * 16 + r16) * 132 + ks * 32 + q * 8);
    #pragma unroll
    for (int g2 = 0; g2 < 4; g2++) {
      #pragma unroll
      for (int j = 0; j < 2; j++) {
        int ct = w + 4 * j + 8 * g2;
        Frag bfw;
        bfw.u4 = *reinterpret_cast<const uint4*>(FWg + ((ct * 4 + ks) * 64 + l) * 8);
        #pragma unroll
        for (int pxt = 0; pxt < 2; pxt++)
          acc[g2][j][pxt] = __builtin_amdgcn_mfma_f32_16x16x32_bf16(af[pxt].s, bfw.s, acc[g2][j][pxt], 0, 0, 0);
      }
    }
  }

  // ---- LSTM epilogue: vectorized c/cnext/tbuf ----
  float gs[2] = {0.f, 0.f}, gs2[2] = {0.f, 0.f};
  #pragma unroll
  for (int j = 0; j < 2; j++) {
    int ch = (w + 4 * j) * 16 + r16;
    float bi = bgates[ch], bff = bgates[128 + ch], bog = bgates[256 + ch], bgg = bgates[384 + ch];
    #pragma unroll
    for (int pxt = 0; pxt < 2; pxt++) {
      size_t gbase = (size_t)(b * 128 + ch) * PIX + p0 + pxt * 16 + q * 4;
      const float cc[4] = {cv[j][pxt].x, cv[j][pxt].y, cv[j][pxt].z, cv[j][pxt].w};
      float cn[4], tv[4];
      #pragma unroll
      for (int r = 0; r < 4; r++) {
        float ig = fsigmoid(acc[0][j][pxt][r] + bi);
        float fg = fsigmoid(acc[1][j][pxt][r] + bff);
        float og = fsigmoid(acc[2][j][pxt][r] + bog);
        float gg = ftanh   (acc[3][j][pxt][r] + bgg);
        cn[r] = fg * cc[r] + ig * gg;
        tv[r] = og * ftanh(cn[r]);
        gs[j] += tv[r]; gs2[j] += tv[r] * tv[r];
      }
      float4 cno = {cn[0], cn[1], cn[2], cn[3]};
      *reinterpret_cast<float4*>(cnext + gbase) = cno;
      uint2 tpk;
      tpk.x = pk2(tv[0], tv[1]); tpk.y = pk2(tv[2], tv[3]);
      *reinterpret_cast<uint2*>(tbuf + gbase) = tpk;
    }
  }
  #pragma unroll
  for (int j = 0; j < 2; j++) {
    float s = gs[j], s2 = gs2[j];
    s += __shfl_xor(s, 1); s += __shfl_xor(s, 2); s += __shfl_xor(s, 4);
    s += __shfl_xor(s, 8); s += __shfl_xor(s, 16); s += __shfl_xor(s, 32);
    s2 += __shfl_xor(s2, 1); s2 += __shfl_xor(s2, 2); s2 += __shfl_xor(s2, 4);
    s2 += __shfl_xor(s2, 8); s2 += __shfl_xor(s2, 16); s2 += __shfl_xor(s2, 32);
    if (l == 0) {
      int g = w + 4 * j;
      atomicAdd(&sStat[g * 2], s);
      atomicAdd(&sStat[g * 2 + 1], s2);
    }
  }
  __syncthreads();
  if (t < 16) atomicAdd(&stB_raw[b * 16 + t], sStat[t]);
}

// ---------------- hnext = GN2(tbuf), inline stats finalize ----------------
__global__ __launch_bounds__(256) void k_gnout(
    const ushort* __restrict__ tbuf, const float* __restrict__ stB_raw,
    const float* __restrict__ gn_g, const float* __restrict__ gn_b,
    float* __restrict__ hnext)
{
  size_t idx = ((size_t)blockIdx.x * 256 + threadIdx.x) * 8;
  if (idx >= (size_t)16777216) return;
  int chrow = (int)(idx >> 14);
  int b = chrow >> 7, ch = chrow & 127, g = ch >> 4;
  const float invN = 1.f / 262144.f;
  float mu = stB_raw[b * 16 + g * 2] * invN;
  float var = stB_raw[b * 16 + g * 2 + 1] * invN - mu * mu;
  float rstd = rsqrtf(var + EPSF);
  float A = gn_g[ch] * rstd, Bv = gn_b[ch] - mu * A;
  uint4 u = *reinterpret_cast<const uint4*>(tbuf + idx);
  float4 o0, o1;
  o0.x = bf2f((ushort)(u.x & 0xFFFFu)) * A + Bv;
  o0.y = bf2f((ushort)(u.x >> 16)) * A + Bv;
  o0.z = bf2f((ushort)(u.y & 0xFFFFu)) * A + Bv;
  o0.w = bf2f((ushort)(u.y >> 16)) * A + Bv;
  o1.x = bf2f((ushort)(u.z & 0xFFFFu)) * A + Bv;
  o1.y = bf2f((ushort)(u.z >> 16)) * A + Bv;
  o1.z = bf2f((ushort)(u.w & 0xFFFFu)) * A + Bv;
  o1.w = bf2f((ushort)(u.w >> 16)) * A + Bv;
  *reinterpret_cast<float4*>(hnext + idx) = o0;
  *reinterpret_cast<float4*>(hnext + idx + 4) = o1;
}

extern "C" void kernel_launch(void* const* d_in, const int* in_sizes, int n_in,
                              void* d_out, int out_size, void* d_ws, size_t ws_size,
                              hipStream_t stream) {
  (void)in_sizes; (void)n_in; (void)out_size; (void)ws_size;
  const float* x      = (const float*)d_in[0];
  const float* h      = (const float*)d_in[1];
  const float* c      = (const float*)d_in[2];
  const float* Wproj  = (const float*)d_in[3];
  const float* bproj  = (const float*)d_in[4];
  const float* ln_g   = (const float*)d_in[5];
  const float* ln_b   = (const float*)d_in[6];
  const float* Wqkv   = (const float*)d_in[7];
  const float* bqkv   = (const float*)d_in[8];
  const float* Wo     = (const float*)d_in[9];
  const float* bo     = (const float*)d_in[10];
  const float* Wgates = (const float*)d_in[11];
  const float* bgates = (const float*)d_in[12];
  const float* gn_g   = (const float*)d_in[13];
  const float* gn_b   = (const float*)d_in[14];

  float* out = (float*)d_out;
  float* hnext = out;
  float* cnext = out + 16777216;

  char* W = (char*)d_ws;
  ushort* attn = (ushort*)W;                          // 32 MB bf16
  ushort* tbuf = (ushort*)(W + 33554432);             // 32 MB bf16
  size_t off = 67108864;
  ushort* FWp = (ushort*)(W + off); off += 49152;
  ushort* FWq = (ushort*)(W + off); off += 98304;
  ushort* FWo = (ushort*)(W + off); off += 32768;
  ushort* FWg = (ushort*)(W + off); off += 131072;
  float* stA_raw = (float*)(W + off); off += 512;
  float* stB_raw = (float*)(W + off); off += 512;
  float* Sarr    = (float*)(W + off); off += 1536;
  float* Tbarr   = (float*)(W + off); off += 1536;

  hipMemsetAsync(stA_raw, 0, 1024, stream);

  k_prep<<<76, 256, 0, stream>>>(Wproj, Wqkv, Wo, Wgates, ln_g, FWp, FWq, FWo, FWg);
  k_prep2<<<1, 384, 0, stream>>>(Wqkv, ln_g, ln_b, bqkv, Sarr, Tbarr);

  k_attn<<<2048, 256, 0, stream>>>(x, h, FWp, bproj, FWq, Sarr, Tbarr,
                                   FWo, bo, attn, stA_raw);
  k_gates<<<4096, 256, 0, stream>>>(attn, stA_raw, gn_g, gn_b, FWg, bgates,
                                    c, cnext, tbuf, stB_raw);
  k_gnout<<<8192, 256, 0, stream>>>(tbuf, stB_raw, gn_g, gn_b, hnext);
}

// Round 10
// 215.252 us; speedup vs baseline: 3.9930x; 1.0486x over previous
//
#include <hip/hip_runtime.h>
#include <math.h>

typedef unsigned int uint;
typedef unsigned short ushort;
typedef short s16x8 __attribute__((ext_vector_type(8)));
typedef float f32x4 __attribute__((ext_vector_type(4)));

#define PIX 16384
#define EPSF 1e-5f

__device__ __forceinline__ ushort f2bf(float f) {
  union { float f; uint u; } v; v.f = f;
  uint u = v.u;
  uint r = (u + 0x7FFFu + ((u >> 16) & 1u)) >> 16;
  return (ushort)r;
}
__device__ __forceinline__ float bf2f(ushort h) {
  union { uint u; float f; } v; v.u = ((uint)h) << 16;
  return v.f;
}
__device__ __forceinline__ uint pk2(float a, float b) {
  return (uint)f2bf(a) | ((uint)f2bf(b) << 16);
}
__device__ __forceinline__ float fsigmoid(float v) { return 1.f / (1.f + __expf(-v)); }
__device__ __forceinline__ float ftanh(float v) { return 1.f - 2.f / (__expf(2.f * v) + 1.f); }

union Frag { uint4 u4; uint u[4]; s16x8 s; };

// ---------------- merged weight fragment prep ----------------
// frag (mt, ks): lane l elem j = W[mt*16 + (l&15)][ks*32 + (l>>4)*8 + j]
// FWq columns pre-scaled by ln_g (LN folded into QKV GEMM).
__global__ void k_prep(const float* __restrict__ Wp, const float* __restrict__ Wq,
                       const float* __restrict__ Wo, const float* __restrict__ Wg,
                       const float* __restrict__ ln_g,
                       ushort* __restrict__ FWp, ushort* __restrict__ FWq,
                       ushort* __restrict__ FWo, ushort* __restrict__ FWg) {
  int idx = blockIdx.x * 256 + threadIdx.x;   // [0, 19456)
  const float* W; ushort* F; int KS, ldw, rel; bool scale = false;
  if (idx < 3072)       { W = Wp; F = FWp; KS = 6; ldw = 192; rel = idx; }
  else if (idx < 9216)  { W = Wq; F = FWq; KS = 4; ldw = 128; rel = idx - 3072; scale = true; }
  else if (idx < 11264) { W = Wo; F = FWo; KS = 4; ldw = 128; rel = idx - 9216; }
  else                  { W = Wg; F = FWg; KS = 4; ldw = 128; rel = idx - 11264; }
  int l = rel & 63, rest = rel >> 6;
  int ks = rest % KS, mt = rest / KS;
  int col = ks * 32 + (l >> 4) * 8;
  const float* src = W + (size_t)(mt * 16 + (l & 15)) * ldw + col;
  float g[8] = {1.f, 1.f, 1.f, 1.f, 1.f, 1.f, 1.f, 1.f};
  if (scale) {
    #pragma unroll
    for (int j = 0; j < 8; j++) g[j] = ln_g[col + j];
  }
  uint4 v;
  v.x = pk2(src[0] * g[0], src[1] * g[1]);
  v.y = pk2(src[2] * g[2], src[3] * g[3]);
  v.z = pk2(src[4] * g[4], src[5] * g[5]);
  v.w = pk2(src[6] * g[6], src[7] * g[7]);
  *reinterpret_cast<uint4*>(F + (size_t)rel * 8) = v;
}

// S_o = sum_i Wqkv[o,i]*ln_g[i];  Tb_o = sum_i Wqkv[o,i]*ln_b[i] + bqkv[o]
__global__ void k_prep2(const float* __restrict__ Wq, const float* __restrict__ ln_g,
                        const float* __restrict__ ln_b, const float* __restrict__ bqkv,
                        float* __restrict__ Sarr, float* __restrict__ Tbarr) {
  int o = threadIdx.x;
  if (o >= 384) return;
  float S = 0.f, T = 0.f;
  const float* wr = Wq + (size_t)o * 128;
  for (int i = 0; i < 128; i++) {
    float wv = wr[i];
    S = fmaf(wv, ln_g[i], S);
    T = fmaf(wv, ln_b[i], T);
  }
  Sarr[o] = S;
  Tbarr[o] = T + bqkv[o];
}

// ---------------- fused proj + (folded LN) + window MHSA + Wo (+GN stats) ----------------
// v2: 51200-B LDS (3 blocks/CU). Region map:
//   R0 [0,17408):     sInP part (ph0-1) -> sXn (ph1b-2) -> V [4][2048]us (ph2b-3) -> sFin (ph4-5)
//   R1 [17408,51200): sInP part (ph0-1) -> 4x 8448B window slices:
//        ph2a: [16][264]us Q(cols 0-127), K(cols 128-255)
//        ph3:  P at slice[0,4096) (over dead Q, per-wave order), sO at slice[4096,8448)
// Phase 2 split: hoist 16 xn frags -> QK GEMM (writes slices) -> V GEMM (acc in regs)
//   -> B4 (sXn reads drained) -> V epilogue writes R0 -> B4b (V visible) -> attention.
__global__ __launch_bounds__(256, 3) void k_attn(
    const float* __restrict__ x, const float* __restrict__ h,
    const ushort* __restrict__ FWp, const float* __restrict__ bproj,
    const ushort* __restrict__ FWq, const float* __restrict__ Sarr,
    const float* __restrict__ Tbarr,
    const ushort* __restrict__ FWoT, const float* __restrict__ bo,
    ushort* __restrict__ attn_map, float* __restrict__ stA_raw)
{
  __shared__ __align__(16) char LM[51200];
  __shared__ float sSum[64], sSum2[64];
  __shared__ float sStat[16];

  const int t = threadIdx.x;
  const int bid = blockIdx.x;
  const int b = bid >> 8, wh = (bid >> 3) & 31, ww0 = bid & 7;
  const int w = t >> 6, l = t & 63, q = l >> 4, r16 = l & 15;

  uint* sInP = (uint*)LM;            // [96][68] dwords (26112 B)
  ushort* sXn = (ushort*)LM;         // [64][136]

  if (t < 64) { sSum[t] = 0.f; sSum2[t] = 0.f; }
  if (t < 16) sStat[t] = 0.f;

  // ---- phase 0: stage concat(x,h) -> sInP[chp][col], col = window*16 + token ----
  {
    const float* xb = x + (size_t)b * 64 * PIX;
    const float* hb = h + (size_t)b * 128 * PIX;
    #pragma unroll
    for (int it = 0; it < 6; it++) {
      int item = it * 256 + t;                 // [0,1536)
      int wv = item & 3, r = (item >> 2) & 3, chp = item >> 4;
      int ch0 = chp * 2;
      int gpix = (wh * 4 + r) * 128 + ww0 * 16 + wv * 4;
      float4 a, c2;
      if (ch0 < 64) {
        a  = *reinterpret_cast<const float4*>(xb + (size_t)ch0 * PIX + gpix);
        c2 = *reinterpret_cast<const float4*>(xb + (size_t)(ch0 + 1) * PIX + gpix);
      } else {
        a  = *reinterpret_cast<const float4*>(hb + (size_t)(ch0 - 64) * PIX + gpix);
        c2 = *reinterpret_cast<const float4*>(hb + (size_t)(ch0 - 63) * PIX + gpix);
      }
      uint4 pkd;
      pkd.x = pk2(a.x, c2.x); pkd.y = pk2(a.y, c2.y);
      pkd.z = pk2(a.z, c2.z); pkd.w = pk2(a.w, c2.w);
      *reinterpret_cast<uint4*>(sInP + chp * 68 + wv * 16 + r * 4) = pkd;
    }
  }
  __syncthreads();   // B1

  // ---- phase 1: proj MFMA. wave w owns mt in {w, w+4}; nt = window 0..3 ----
  f32x4 acc1[2][4];
  {
    #pragma unroll
    for (int mi = 0; mi < 2; mi++)
      #pragma unroll
      for (int nt = 0; nt < 4; nt++) acc1[mi][nt] = (f32x4){0.f, 0.f, 0.f, 0.f};
    for (int ks = 0; ks < 6; ks++) {
      Frag bf[4];
      #pragma unroll
      for (int nt = 0; nt < 4; nt++)
        #pragma unroll
        for (int s = 0; s < 4; s++)
          bf[nt].u[s] = sInP[(ks * 16 + q * 4 + s) * 68 + nt * 16 + r16];
      #pragma unroll
      for (int mi = 0; mi < 2; mi++) {
        Frag af;
        af.u4 = *reinterpret_cast<const uint4*>(FWp + (((w + mi * 4) * 6 + ks) * 64 + l) * 8);
        #pragma unroll
        for (int nt = 0; nt < 4; nt++)
          acc1[mi][nt] = __builtin_amdgcn_mfma_f32_16x16x32_bf16(af.s, bf[nt].s, acc1[mi][nt], 0, 0, 0);
      }
    }
  }
  __syncthreads();   // B2: all sInP reads done; sXn overlays

  // ---- phase 1b: bias, pack raw p -> sXn, per-token LN stats (fp32) ----
  {
    float pst[4] = {0.f, 0.f, 0.f, 0.f}, pst2[4] = {0.f, 0.f, 0.f, 0.f};
    #pragma unroll
    for (int mi = 0; mi < 2; mi++) {
      int o0 = (w + mi * 4) * 16 + q * 4;
      const float4 bv = *reinterpret_cast<const float4*>(bproj + o0);
      #pragma unroll
      for (int nt = 0; nt < 4; nt++) {
        float v0 = acc1[mi][nt][0] + bv.x, v1 = acc1[mi][nt][1] + bv.y;
        float v2 = acc1[mi][nt][2] + bv.z, v3 = acc1[mi][nt][3] + bv.w;
        uint2 pk; pk.x = pk2(v0, v1); pk.y = pk2(v2, v3);
        *reinterpret_cast<uint2*>(sXn + (nt * 16 + r16) * 136 + o0) = pk;
        pst[nt]  += v0 + v1 + v2 + v3;
        pst2[nt] += v0 * v0 + v1 * v1 + v2 * v2 + v3 * v3;
      }
    }
    #pragma unroll
    for (int nt = 0; nt < 4; nt++) {
      float s = pst[nt], s2 = pst2[nt];
      s  += __shfl_xor(s, 16);  s  += __shfl_xor(s, 32);
      s2 += __shfl_xor(s2, 16); s2 += __shfl_xor(s2, 32);
      if (q == 0) {
        atomicAdd(&sSum[nt * 16 + r16], s);
        atomicAdd(&sSum2[nt * 16 + r16], s2);
      }
    }
  }
  __syncthreads();   // B3: sXn + stats ready

  // ---- phase 2: hoist xn frags; QK GEMM -> slices; V GEMM held in regs ----
  float rstd_[4], mr_[4];
  f32x4 accV[2][4];
  {
    Frag bfh[4][4];   // [ks][nt] — all sXn reads happen here
    #pragma unroll
    for (int ks = 0; ks < 4; ks++)
      #pragma unroll
      for (int nt = 0; nt < 4; nt++)
        bfh[ks][nt].u4 = *reinterpret_cast<const uint4*>(sXn + (nt * 16 + r16) * 136 + ks * 32 + q * 8);

    #pragma unroll
    for (int nt = 0; nt < 4; nt++) {
      int tok = nt * 16 + r16;
      float mu = sSum[tok] * 0.0078125f;
      float var = sSum2[tok] * 0.0078125f - mu * mu;
      rstd_[nt] = rsqrtf(var + EPSF);
      mr_[nt] = -mu * rstd_[nt];
    }

    ushort* sQKu = (ushort*)(LM + 17408);
    #pragma unroll
    for (int mi = 0; mi < 4; mi++) {        // Q,K tiles: mt = w + mi*4 < 16
      int mt = w + mi * 4;
      f32x4 accq[4];
      #pragma unroll
      for (int nt = 0; nt < 4; nt++) accq[nt] = (f32x4){0.f, 0.f, 0.f, 0.f};
      #pragma unroll
      for (int ks = 0; ks < 4; ks++) {
        Frag af;
        af.u4 = *reinterpret_cast<const uint4*>(FWq + ((mt * 4 + ks) * 64 + l) * 8);
        #pragma unroll
        for (int nt = 0; nt < 4; nt++)
          accq[nt] = __builtin_amdgcn_mfma_f32_16x16x32_bf16(af.s, bfh[ks][nt].s, accq[nt], 0, 0, 0);
      }
      int oo = mt * 16 + q * 4;
      const float4 S4  = *reinterpret_cast<const float4*>(Sarr + oo);
      const float4 Tb4 = *reinterpret_cast<const float4*>(Tbarr + oo);
      #pragma unroll
      for (int nt = 0; nt < 4; nt++) {
        float v0 = fmaf(rstd_[nt], accq[nt][0], fmaf(mr_[nt], S4.x, Tb4.x));
        float v1 = fmaf(rstd_[nt], accq[nt][1], fmaf(mr_[nt], S4.y, Tb4.y));
        float v2 = fmaf(rstd_[nt], accq[nt][2], fmaf(mr_[nt], S4.z, Tb4.z));
        float v3 = fmaf(rstd_[nt], accq[nt][3], fmaf(mr_[nt], S4.w, Tb4.w));
        uint2 pk; pk.x = pk2(v0, v1); pk.y = pk2(v2, v3);
        *reinterpret_cast<uint2*>(sQKu + nt * 4224 + r16 * 264 + oo) = pk;
      }
    }
    #pragma unroll
    for (int mi = 0; mi < 2; mi++) {        // V tiles: mt = w+16, w+20
      int mt = w + 16 + mi * 4;
      #pragma unroll
      for (int nt = 0; nt < 4; nt++) accV[mi][nt] = (f32x4){0.f, 0.f, 0.f, 0.f};
      #pragma unroll
      for (int ks = 0; ks < 4; ks++) {
        Frag af;
        af.u4 = *reinterpret_cast<const uint4*>(FWq + ((mt * 4 + ks) * 64 + l) * 8);
        #pragma unroll
        for (int nt = 0; nt < 4; nt++)
          accV[mi][nt] = __builtin_amdgcn_mfma_f32_16x16x32_bf16(af.s, bfh[ks][nt].s, accV[mi][nt], 0, 0, 0);
      }
    }
  }
  __syncthreads();   // B4: all waves' sXn reads drained; R0 free for V

  // ---- phase 2b: V epilogue -> R0 [0,16384) ----
  {
    ushort* sVu = (ushort*)LM;
    #pragma unroll
    for (int mi = 0; mi < 2; mi++) {
      int mt = w + 16 + mi * 4;
      int oo = mt * 16 + q * 4;
      const float4 S4  = *reinterpret_cast<const float4*>(Sarr + oo);
      const float4 Tb4 = *reinterpret_cast<const float4*>(Tbarr + oo);
      #pragma unroll
      for (int nt = 0; nt < 4; nt++) {
        float v0 = fmaf(rstd_[nt], accV[mi][nt][0], fmaf(mr_[nt], S4.x, Tb4.x));
        float v1 = fmaf(rstd_[nt], accV[mi][nt][1], fmaf(mr_[nt], S4.y, Tb4.y));
        float v2 = fmaf(rstd_[nt], accV[mi][nt][2], fmaf(mr_[nt], S4.z, Tb4.z));
        float v3 = fmaf(rstd_[nt], accV[mi][nt][3], fmaf(mr_[nt], S4.w, Tb4.w));
        ushort* vd = sVu + nt * 2048 + (oo - 256) * 16 + r16;
        vd[0] = f2bf(v0); vd[16] = f2bf(v1); vd[32] = f2bf(v2); vd[48] = f2bf(v3);
      }
    }
  }
  __syncthreads();   // B4b: V visible to all waves

  // ---- phase 3: scores + softmax + PV, wave = window w.
  //      P overlays dead Q at slice[0,4096) (per-wave program order). ----
  {
    const float scale = 0.17677669529663687f;
    ushort* sQKw = (ushort*)(LM + 17408 + w * 8448);
    ushort* sPw  = sQKw;
    Frag af4[4], bf4[4];
    #pragma unroll
    for (int hd = 0; hd < 4; hd++) {
      af4[hd].u4 = *reinterpret_cast<const uint4*>(sQKw + r16 * 264 + hd * 32 + q * 8);
      bf4[hd].u4 = *reinterpret_cast<const uint4*>(sQKw + r16 * 264 + 128 + hd * 32 + q * 8);
    }
    #pragma unroll
    for (int hd = 0; hd < 4; hd++) {
      if (l < 32) {
        int row = l >> 1, hz = l & 1;
        uint4 z = {0u, 0u, 0u, 0u};
        *reinterpret_cast<uint4*>(sPw + hd * 512 + row * 32 + 16 + hz * 8) = z;
      }
    }
    f32x4 sc[4];
    #pragma unroll
    for (int hd = 0; hd < 4; hd++) {
      f32x4 z4 = (f32x4){0.f, 0.f, 0.f, 0.f};
      sc[hd] = __builtin_amdgcn_mfma_f32_16x16x32_bf16(af4[hd].s, bf4[hd].s, z4, 0, 0, 0);
    }
    #pragma unroll
    for (int hd = 0; hd < 4; hd++) {
      ushort* pd = sPw + hd * 512 + (q * 4) * 32 + r16;
      #pragma unroll
      for (int r = 0; r < 4; r++) {
        float sv = sc[hd][r] * scale;
        float mx = sv;
        mx = fmaxf(mx, __shfl_xor(mx, 1));
        mx = fmaxf(mx, __shfl_xor(mx, 2));
        mx = fmaxf(mx, __shfl_xor(mx, 4));
        mx = fmaxf(mx, __shfl_xor(mx, 8));
        float e = __expf(sv - mx);
        float sm = e;
        sm += __shfl_xor(sm, 1); sm += __shfl_xor(sm, 2);
        sm += __shfl_xor(sm, 4); sm += __shfl_xor(sm, 8);
        pd[r * 32] = f2bf(e / sm);
      }
    }
    // PV -> sO at slice[4096,8448); V from R0
    ushort* sOw = sQKw + 2048;               // +4096 B
    ushort* sVw = (ushort*)LM + w * 2048;    // window w's V (4096 B)
    #pragma unroll
    for (int hd = 0; hd < 4; hd++) {
      Frag pa;
      pa.u4 = *reinterpret_cast<const uint4*>(sPw + hd * 512 + r16 * 32 + q * 8);
      #pragma unroll
      for (int nt2 = 0; nt2 < 2; nt2++) {
        int ch = hd * 32 + nt2 * 16 + r16;
        int off = (q < 2) ? q * 8 : 0;
        Frag vf;
        vf.u4 = *reinterpret_cast<const uint4*>(sVw + ch * 16 + off);
        f32x4 z4 = (f32x4){0.f, 0.f, 0.f, 0.f};
        f32x4 o4 = __builtin_amdgcn_mfma_f32_16x16x32_bf16(pa.s, vf.s, z4, 0, 0, 0);
        ushort* od = sOw + (q * 4) * 136 + ch;
        od[0] = f2bf(o4[0]); od[136] = f2bf(o4[1]);
        od[272] = f2bf(o4[2]); od[408] = f2bf(o4[3]);
      }
    }
  }
  __syncthreads();   // B5: all sO ready; R0 (V) dead -> sFin

  // ---- phase 4: Wo MFMA. wave w owns ntg in {w, w+4}; nt = window ----
  {
    ushort* sFinu = (ushort*)LM;
    Frag a4[4][4];
    #pragma unroll
    for (int nt = 0; nt < 4; nt++) {
      ushort* sOnt = (ushort*)(LM + 17408 + nt * 8448 + 4096);
      #pragma unroll
      for (int ks = 0; ks < 4; ks++)
        a4[nt][ks].u4 = *reinterpret_cast<const uint4*>(sOnt + r16 * 136 + ks * 32 + q * 8);
    }
    #pragma unroll
    for (int mi2 = 0; mi2 < 2; mi2++) {
      int ntg = w + mi2 * 4;
      f32x4 acw[4];
      #pragma unroll
      for (int nt = 0; nt < 4; nt++) acw[nt] = (f32x4){0.f, 0.f, 0.f, 0.f};
      #pragma unroll
      for (int ks = 0; ks < 4; ks++) {
        Frag bfw;
        bfw.u4 = *reinterpret_cast<const uint4*>(FWoT + ((ntg * 4 + ks) * 64 + l) * 8);
        #pragma unroll
        for (int nt = 0; nt < 4; nt++)
          acw[nt] = __builtin_amdgcn_mfma_f32_16x16x32_bf16(a4[nt][ks].s, bfw.s, acw[nt], 0, 0, 0);
      }
      int ch = ntg * 16 + r16;
      float bb = bo[ch];
      #pragma unroll
      for (int nt = 0; nt < 4; nt++) {
        uint2 pk;
        pk.x = pk2(acw[nt][0] + bb, acw[nt][1] + bb);
        pk.y = pk2(acw[nt][2] + bb, acw[nt][3] + bb);
        *reinterpret_cast<uint2*>(sFinu + nt * 2048 + ch * 16 + q * 4) = pk;
      }
    }
  }
  __syncthreads();   // B6

  // ---- phase 5: coalesced writeout (2 windows per 16B) + GN partial stats ----
  {
    ushort* sFinu = (ushort*)LM;
    #pragma unroll
    for (int it = 0; it < 4; it++) {
      int seg = it * 256 + t;            // [0,1024)
      int ch = seg >> 3, r = (seg >> 1) & 3, half = seg & 1;
      const ushort* f0 = sFinu + (half * 2    ) * 2048;
      const ushort* f1 = sFinu + (half * 2 + 1) * 2048;
      uint2 a  = *reinterpret_cast<const uint2*>(f0 + ch * 16 + r * 4);
      uint2 c2 = *reinterpret_cast<const uint2*>(f1 + ch * 16 + r * 4);
      uint4 val = {a.x, a.y, c2.x, c2.y};
      *reinterpret_cast<uint4*>(attn_map + (size_t)(b * 128 + ch) * PIX
                                + (wh * 4 + r) * 128 + ww0 * 16 + half * 8) = val;
      float sv = 0.f, sv2 = 0.f;
      uint uu[4] = {val.x, val.y, val.z, val.w};
      #pragma unroll
      for (int k2 = 0; k2 < 4; k2++) {
        float fv0 = bf2f((ushort)(uu[k2] & 0xFFFFu));
        float fv1 = bf2f((ushort)(uu[k2] >> 16));
        sv += fv0 + fv1; sv2 += fv0 * fv0 + fv1 * fv1;
      }
      sv  += __shfl_xor(sv, 1);  sv  += __shfl_xor(sv, 2);  sv  += __shfl_xor(sv, 4);
      sv2 += __shfl_xor(sv2, 1); sv2 += __shfl_xor(sv2, 2); sv2 += __shfl_xor(sv2, 4);
      if ((t & 7) == 0) {
        int g = ch >> 4;
        atomicAdd(&sStat[g * 2], sv);
        atomicAdd(&sStat[g * 2 + 1], sv2);
      }
    }
  }
  __syncthreads();
  if (t < 16) atomicAdd(&stA_raw[b * 16 + t], sStat[t]);
}

// ---------------- GN + gates MFMA + LSTM update (+stats for GN2) ----------------
// (unchanged from round 9 — validated)
__global__ __launch_bounds__(256, 4) void k_gates(
    const ushort* __restrict__ attn_map, const float* __restrict__ stA_raw,
    const float* __restrict__ gn_g, const float* __restrict__ gn_b,
    const ushort* __restrict__ FWg, const float* __restrict__ bgates,
    const float* __restrict__ c, float* __restrict__ cnext,
    ushort* __restrict__ tbuf, float* __restrict__ stB_raw)
{
  __shared__ uint sG2[32 * 66];     // [px][ch-pair dwords + 2 pad] = 8448 B
  __shared__ float sA[128], sB[128];
  __shared__ float sStat[16];
  const int t = threadIdx.x, bid = blockIdx.x;
  const int b = bid >> 9, p0 = (bid & 511) * 32;
  const int w = t >> 6, l = t & 63, q = l >> 4, r16 = l & 15;

  if (t < 128) {
    int g = t >> 4;
    const float invN = 1.f / 262144.f;
    float mu = stA_raw[b * 16 + g * 2] * invN;
    float var = stA_raw[b * 16 + g * 2 + 1] * invN - mu * mu;
    float rs = rsqrtf(var + EPSF);
    float A = rs * gn_g[t];
    sA[t] = A; sB[t] = gn_b[t] - mu * A;
  }
  if (t >= 240) sStat[t - 240] = 0.f;
  __syncthreads();

  // ---- staging: GN(attn) -> sG2[px][ch] (transposed) ----
  {
    int pr = t >> 2, px0 = (t & 3) * 8;
    int c0 = pr * 2;
    const ushort* ab = attn_map + (size_t)(b * 128) * PIX + p0 + px0;
    uint4 a0 = *reinterpret_cast<const uint4*>(ab + (size_t)c0 * PIX);
    uint4 a1 = *reinterpret_cast<const uint4*>(ab + (size_t)(c0 + 1) * PIX);
    float A0 = sA[c0], B0 = sB[c0], A1 = sA[c0 + 1], B1 = sB[c0 + 1];
    uint u0[4] = {a0.x, a0.y, a0.z, a0.w};
    uint u1[4] = {a1.x, a1.y, a1.z, a1.w};
    #pragma unroll
    for (int j = 0; j < 4; j++) {
      float v0lo = bf2f((ushort)(u0[j] & 0xFFFFu)) * A0 + B0;
      float v0hi = bf2f((ushort)(u0[j] >> 16)) * A0 + B0;
      float v1lo = bf2f((ushort)(u1[j] & 0xFFFFu)) * A1 + B1;
      float v1hi = bf2f((ushort)(u1[j] >> 16)) * A1 + B1;
      sG2[(px0 + 2 * j) * 66 + pr]     = pk2(v0lo, v1lo);
      sG2[(px0 + 2 * j + 1) * 66 + pr] = pk2(v0hi, v1hi);
    }
  }

  // ---- prefetch c ----
  float4 cv[2][2];
  #pragma unroll
  for (int j = 0; j < 2; j++) {
    int ch = (w + 4 * j) * 16 + r16;
    const float* cb = c + (size_t)(b * 128 + ch) * PIX + p0 + q * 4;
    cv[j][0] = *reinterpret_cast<const float4*>(cb);
    cv[j][1] = *reinterpret_cast<const float4*>(cb + 16);
  }
  __syncthreads();

  // ---- gates GEMM: D[px][ch]; acc[gate][j][pxt], ch tile = w + 4j + 8*gate ----
  f32x4 acc[4][2][2];
  #pragma unroll
  for (int g2 = 0; g2 < 4; g2++)
    #pragma unroll
    for (int j = 0; j < 2; j++)
      #pragma unroll
      for (int pxt = 0; pxt < 2; pxt++) acc[g2][j][pxt] = (f32x4){0.f, 0.f, 0.f, 0.f};

  const ushort* sGu = (const ushort*)sG2;
  for (int ks = 0; ks < 4; ks++) {
    Frag af[2];
    #pragma unroll
    for (int pxt = 0; pxt < 2; pxt++)
      af[pxt].u4 = *reinterpret_cast<const uint4*>(sGu + (pxt * 16 + r16) * 132 + ks * 32 + q * 8);
    #pragma unroll
    for (int g2 = 0; g2 < 4; g2++) {
      #pragma unroll
      for (int j = 0; j < 2; j++) {
        int ct = w + 4 * j + 8 * g2;
        Frag bfw;
        bfw.u4 = *reinterpret_cast<const uint4*>(FWg + ((ct * 4 + ks) * 64 + l) * 8);
        #pragma unroll
        for (int pxt = 0; pxt < 2; pxt++)
          acc[g2][j][pxt] = __builtin_amdgcn_mfma_f32_16x16x32_bf16(af[pxt].s, bfw.s, acc[g2][j][pxt], 0, 0, 0);
      }
    }
  }

  // ---- LSTM epilogue: vectorized c/cnext/tbuf ----
  float gs[2] = {0.f, 0.f}, gs2[2] = {0.f, 0.f};
  #pragma unroll
  for (int j = 0; j < 2; j++) {
    int ch = (w + 4 * j) * 16 + r16;
    float bi = bgates[ch], bff = bgates[128 + ch], bog = bgates[256 + ch], bgg = bgates[384 + ch];
    #pragma unroll
    for (int pxt = 0; pxt < 2; pxt++) {
      size_t gbase = (size_t)(b * 128 + ch) * PIX + p0 + pxt * 16 + q * 4;
      const float cc[4] = {cv[j][pxt].x, cv[j][pxt].y, cv[j][pxt].z, cv[j][pxt].w};
      float cn[4], tv[4];
      #pragma unroll
      for (int r = 0; r < 4; r++) {
        float ig = fsigmoid(acc[0][j][pxt][r] + bi);
        float fg = fsigmoid(acc[1][j][pxt][r] + bff);
        float og = fsigmoid(acc[2][j][pxt][r] + bog);
        float gg = ftanh   (acc[3][j][pxt][r] + bgg);
        cn[r] = fg * cc[r] + ig * gg;
        tv[r] = og * ftanh(cn[r]);
        gs[j] += tv[r]; gs2[j] += tv[r] * tv[r];
      }
      float4 cno = {cn[0], cn[1], cn[2], cn[3]};
      *reinterpret_cast<float4*>(cnext + gbase) = cno;
      uint2 tpk;
      tpk.x = pk2(tv[0], tv[1]); tpk.y = pk2(tv[2], tv[3]);
      *reinterpret_cast<uint2*>(tbuf + gbase) = tpk;
    }
  }
  #pragma unroll
  for (int j = 0; j < 2; j++) {
    float s = gs[j], s2 = gs2[j];
    s += __shfl_xor(s, 1); s += __shfl_xor(s, 2); s += __shfl_xor(s, 4);
    s += __shfl_xor(s, 8); s += __shfl_xor(s, 16); s += __shfl_xor(s, 32);
    s2 += __shfl_xor(s2, 1); s2 += __shfl_xor(s2, 2); s2 += __shfl_xor(s2, 4);
    s2 += __shfl_xor(s2, 8); s2 += __shfl_xor(s2, 16); s2 += __shfl_xor(s2, 32);
    if (l == 0) {
      int g = w + 4 * j;
      atomicAdd(&sStat[g * 2], s);
      atomicAdd(&sStat[g * 2 + 1], s2);
    }
  }
  __syncthreads();
  if (t < 16) atomicAdd(&stB_raw[b * 16 + t], sStat[t]);
}

// ---------------- hnext = GN2(tbuf), inline stats finalize ----------------
__global__ __launch_bounds__(256) void k_gnout(
    const ushort* __restrict__ tbuf, const float* __restrict__ stB_raw,
    const float* __restrict__ gn_g, const float* __restrict__ gn_b,
    float* __restrict__ hnext)
{
  size_t idx = ((size_t)blockIdx.x * 256 + threadIdx.x) * 8;
  if (idx >= (size_t)16777216) return;
  int chrow = (int)(idx >> 14);
  int b = chrow >> 7, ch = chrow & 127, g = ch >> 4;
  const float invN = 1.f / 262144.f;
  float mu = stB_raw[b * 16 + g * 2] * invN;
  float var = stB_raw[b * 16 + g * 2 + 1] * invN - mu * mu;
  float rstd = rsqrtf(var + EPSF);
  float A = gn_g[ch] * rstd, Bv = gn_b[ch] - mu * A;
  uint4 u = *reinterpret_cast<const uint4*>(tbuf + idx);
  float4 o0, o1;
  o0.x = bf2f((ushort)(u.x & 0xFFFFu)) * A + Bv;
  o0.y = bf2f((ushort)(u.x >> 16)) * A + Bv;
  o0.z = bf2f((ushort)(u.y & 0xFFFFu)) * A + Bv;
  o0.w = bf2f((ushort)(u.y >> 16)) * A + Bv;
  o1.x = bf2f((ushort)(u.z & 0xFFFFu)) * A + Bv;
  o1.y = bf2f((ushort)(u.z >> 16)) * A + Bv;
  o1.z = bf2f((ushort)(u.w & 0xFFFFu)) * A + Bv;
  o1.w = bf2f((ushort)(u.w >> 16)) * A + Bv;
  *reinterpret_cast<float4*>(hnext + idx) = o0;
  *reinterpret_cast<float4*>(hnext + idx + 4) = o1;
}

extern "C" void kernel_launch(void* const* d_in, const int* in_sizes, int n_in,
                              void* d_out, int out_size, void* d_ws, size_t ws_size,
                              hipStream_t stream) {
  (void)in_sizes; (void)n_in; (void)out_size; (void)ws_size;
  const float* x      = (const float*)d_in[0];
  const float* h      = (const float*)d_in[1];
  const float* c      = (const float*)d_in[2];
  const float* Wproj  = (const float*)d_in[3];
  const float* bproj  = (const float*)d_in[4];
  const float* ln_g   = (const float*)d_in[5];
  const float* ln_b   = (const float*)d_in[6];
  const float* Wqkv   = (const float*)d_in[7];
  const float* bqkv   = (const float*)d_in[8];
  const float* Wo     = (const float*)d_in[9];
  const float* bo     = (const float*)d_in[10];
  const float* Wgates = (const float*)d_in[11];
  const float* bgates = (const float*)d_in[12];
  const float* gn_g   = (const float*)d_in[13];
  const float* gn_b   = (const float*)d_in[14];

  float* out = (float*)d_out;
  float* hnext = out;
  float* cnext = out + 16777216;

  char* W = (char*)d_ws;
  ushort* attn = (ushort*)W;                          // 32 MB bf16
  ushort* tbuf = (ushort*)(W + 33554432);             // 32 MB bf16
  size_t off = 67108864;
  ushort* FWp = (ushort*)(W + off); off += 49152;
  ushort* FWq = (ushort*)(W + off); off += 98304;
  ushort* FWo = (ushort*)(W + off); off += 32768;
  ushort* FWg = (ushort*)(W + off); off += 131072;
  float* stA_raw = (float*)(W + off); off += 512;
  float* stB_raw = (float*)(W + off); off += 512;
  float* Sarr    = (float*)(W + off); off += 1536;
  float* Tbarr   = (float*)(W + off); off += 1536;

  hipMemsetAsync(stA_raw, 0, 1024, stream);

  k_prep<<<76, 256, 0, stream>>>(Wproj, Wqkv, Wo, Wgates, ln_g, FWp, FWq, FWo, FWg);
  k_prep2<<<1, 384, 0, stream>>>(Wqkv, ln_g, ln_b, bqkv, Sarr, Tbarr);

  k_attn<<<2048, 256, 0, stream>>>(x, h, FWp, bproj, FWq, Sarr, Tbarr,
                                   FWo, bo, attn, stA_raw);
  k_gates<<<4096, 256, 0, stream>>>(attn, stA_raw, gn_g, gn_b, FWg, bgates,
                                    c, cnext, tbuf, stB_raw);
  k_gnout<<<8192, 256, 0, stream>>>(tbuf, stB_raw, gn_g, gn_b, hnext);
}